// Round 2
// baseline (3155.698 us; speedup 1.0000x reference)
//
#include <hip/hip_runtime.h>

// GCN: 3x GCNConv(relu) + global_mean_pool + FC, fp32.
// Factorization: g = (x @ W^T) * dinv ; agg[i] = g[i] + sum_{e: dst=i} g[src_e]
//                next_x[i] = relu(dinv[i]*agg[i] + b)
// deg/dinv computed once from edge structure (self-loop = +1).
// NOTE: harness materializes integer inputs as int32 (NOT int64) — cast to const int*.

static constexpr int TPB = 256;

__global__ void deg_kernel(const int* __restrict__ dst, int* __restrict__ deg, int E) {
  int e = blockIdx.x * blockDim.x + threadIdx.x;
  if (e < E) atomicAdd(&deg[dst[e]], 1);
}

__global__ void dinv_kernel(const int* __restrict__ deg, float* __restrict__ dinv, int n) {
  int i = blockIdx.x * blockDim.x + threadIdx.x;
  if (i < n) dinv[i] = rsqrtf((float)deg[i] + 1.0f);  // +1 self-loop
}

// Layer 1: in=2, out=32. One thread per (node, f).
__global__ void transform1_kernel(const float* __restrict__ x, const float* __restrict__ W1,
                                  const float* __restrict__ dinv,
                                  float* __restrict__ g, float* __restrict__ agg, int n) {
  int tid = blockIdx.x * blockDim.x + threadIdx.x;
  int i = tid >> 5, f = tid & 31;
  if (i >= n) return;
  float di = dinv[i];
  float gv = (x[i * 2 + 0] * W1[f * 2 + 0] + x[i * 2 + 1] * W1[f * 2 + 1]) * di;
  g[i * 32 + f] = gv;
  agg[i * 32 + f] = gv;  // self-loop init
}

// Generic mid transform: reads prev agg, applies relu(dinv*agg+b_prev), matmul W, scales by dinv.
// Writes g and agg-init. Block = 256 threads = NPB nodes x OUT features.
template <int IN, int OUT, int NPB>
__global__ void transform_mid_kernel(const float* __restrict__ agg_prev,
                                     const float* __restrict__ b_prev,
                                     const float* __restrict__ W,     // [OUT][IN] row-major
                                     const float* __restrict__ dinv,
                                     float* __restrict__ g, float* __restrict__ agg_init, int n) {
  __shared__ float Wl[IN * OUT];     // transposed: Wl[j*OUT+f]
  __shared__ float al[NPB][IN];
  int t = threadIdx.x;
  for (int idx = t; idx < IN * OUT; idx += TPB) {
    int f = idx / IN, j = idx % IN;
    Wl[j * OUT + f] = W[idx];
  }
  int base = blockIdx.x * NPB;
  for (int idx = t; idx < NPB * IN; idx += TPB) {
    int nl = idx / IN, j = idx % IN;
    int node = base + nl;
    float a = 0.f;
    if (node < n) a = fmaxf(dinv[node] * agg_prev[node * IN + j] + b_prev[j], 0.f);
    al[nl][j] = a;
  }
  __syncthreads();
  int nl = t / OUT, f = t % OUT;
  int node = base + nl;
  if (node >= n) return;
  float s = 0.f;
#pragma unroll
  for (int j = 0; j < IN; ++j) s += al[nl][j] * Wl[j * OUT + f];
  float gv = dinv[node] * s;
  g[node * OUT + f] = gv;
  agg_init[node * OUT + f] = gv;
}

// Scatter: each edge's row (OUT floats = 2^LOGQ float4s) handled by 2^LOGQ lanes.
template <int LOGQ>
__global__ void scatter_kernel(const int* __restrict__ src, const int* __restrict__ dst,
                               const float4* __restrict__ g4, float* __restrict__ agg, int E) {
  int tid = blockIdx.x * blockDim.x + threadIdx.x;
  int e = tid >> LOGQ;
  if (e >= E) return;
  int q = tid & ((1 << LOGQ) - 1);
  int s = src[e], d = dst[e];
  float4 v = g4[((long long)s << LOGQ) + q];
  float* p = agg + ((long long)d << (LOGQ + 2)) + q * 4;
  unsafeAtomicAdd(p + 0, v.x);
  unsafeAtomicAdd(p + 1, v.y);
  unsafeAtomicAdd(p + 2, v.z);
  unsafeAtomicAdd(p + 3, v.w);
}

// Final layer epilogue + pooling sums. One thread per (node, f).
__global__ void pool_kernel(const float* __restrict__ agg3, const float* __restrict__ b3,
                            const float* __restrict__ dinv, const int* __restrict__ batch,
                            float* __restrict__ pooled, float* __restrict__ cnt, int n) {
  int tid = blockIdx.x * blockDim.x + threadIdx.x;
  int i = tid >> 5, f = tid & 31;
  if (i >= n) return;
  float v = fmaxf(dinv[i] * agg3[i * 32 + f] + b3[f], 0.f);
  int gid = batch[i];
  unsafeAtomicAdd(&pooled[gid * 32 + f], v);
  if (f == 0) unsafeAtomicAdd(&cnt[gid], 1.0f);
}

__global__ void fc_kernel(const float* __restrict__ pooled, const float* __restrict__ cnt,
                          const float* __restrict__ Wfc, const float* __restrict__ bfc,
                          float* __restrict__ out, int G) {
  int g = blockIdx.x * blockDim.x + threadIdx.x;
  if (g >= G) return;
  float s = 0.f;
#pragma unroll
  for (int f = 0; f < 32; ++f) s += pooled[g * 32 + f] * Wfc[f];
  out[g] = s / fmaxf(cnt[g], 1.0f) + bfc[0];
}

extern "C" void kernel_launch(void* const* d_in, const int* in_sizes, int n_in,
                              void* d_out, int out_size, void* d_ws, size_t ws_size,
                              hipStream_t stream) {
  const float* x     = (const float*)d_in[0];
  const int*   ei    = (const int*)d_in[1];     // int32 on device
  const int*   batch = (const int*)d_in[2];     // int32 on device
  const float* W1    = (const float*)d_in[3];
  const float* b1    = (const float*)d_in[4];
  const float* W2    = (const float*)d_in[5];
  const float* b2    = (const float*)d_in[6];
  const float* W3    = (const float*)d_in[7];
  const float* b3    = (const float*)d_in[8];
  const float* Wfc   = (const float*)d_in[9];
  const float* bfc   = (const float*)d_in[10];
  float* out = (float*)d_out;

  const int N = in_sizes[0] / 2;
  const int E = in_sizes[1] / 2;
  const int G = out_size;  // 512
  const int* src = ei;
  const int* dst = ei + E;

  // Workspace carve-up (poisoned 0xAA each call; zero what needs zeroing).
  char* ws = (char*)d_ws;
  size_t off = 0;
  auto alloc = [&](size_t bytes) -> char* {
    char* p = ws + off;
    off += (bytes + 255) & ~(size_t)255;
    return p;
  };
  int*   deg    = (int*)alloc((size_t)N * 4);
  float* dinv   = (float*)alloc((size_t)N * 4);
  float* g      = (float*)alloc((size_t)N * 64 * 4);   // reused each layer
  float* aggA   = (float*)alloc((size_t)N * 32 * 4);   // agg1, then agg3
  float* aggB   = (float*)alloc((size_t)N * 64 * 4);   // agg2
  float* pooled = (float*)alloc((size_t)G * 32 * 4);
  float* cnt    = (float*)alloc((size_t)G * 4);

  hipMemsetAsync(deg, 0, (size_t)N * 4, stream);
  hipMemsetAsync(pooled, 0, (size_t)G * 32 * 4, stream);
  hipMemsetAsync(cnt, 0, (size_t)G * 4, stream);

  // Structure (once per call)
  deg_kernel<<<(E + TPB - 1) / TPB, TPB, 0, stream>>>(dst, deg, E);
  dinv_kernel<<<(N + TPB - 1) / TPB, TPB, 0, stream>>>(deg, dinv, N);

  // Layer 1: 2 -> 32
  transform1_kernel<<<((size_t)N * 32 + TPB - 1) / TPB, TPB, 0, stream>>>(x, W1, dinv, g, aggA, N);
  scatter_kernel<3><<<((size_t)E * 8 + TPB - 1) / TPB, TPB, 0, stream>>>(src, dst, (const float4*)g, aggA, E);

  // Layer 2: 32 -> 64 (relu+b1 fused into transform)
  transform_mid_kernel<32, 64, 4><<<(N + 3) / 4, TPB, 0, stream>>>(aggA, b1, W2, dinv, g, aggB, N);
  scatter_kernel<4><<<((size_t)E * 16 + TPB - 1) / TPB, TPB, 0, stream>>>(src, dst, (const float4*)g, aggB, E);

  // Layer 3: 64 -> 32 (relu+b2 fused); agg3 reuses aggA
  transform_mid_kernel<64, 32, 8><<<(N + 7) / 8, TPB, 0, stream>>>(aggB, b2, W3, dinv, g, aggA, N);
  scatter_kernel<3><<<((size_t)E * 8 + TPB - 1) / TPB, TPB, 0, stream>>>(src, dst, (const float4*)g, aggA, E);

  // relu+b3 fused into pooling; then FC
  pool_kernel<<<((size_t)N * 32 + TPB - 1) / TPB, TPB, 0, stream>>>(aggA, b3, dinv, batch, pooled, cnt, N);
  fc_kernel<<<(G + TPB - 1) / TPB, TPB, 0, stream>>>(pooled, cnt, Wfc, bfc, out, G);
}

// Round 3
// 876.822 us; speedup vs baseline: 3.5990x; 3.5990x over previous
//
#include <hip/hip_runtime.h>

// GCN: 3x GCNConv(relu) + global_mean_pool + FC, fp32.
// R3: atomic-free aggregation. The R2 counters showed each fp32-atomic scatter
// wrote 1.6 GB through L2 (32 B per 4 B atomic RMW) at ~1.35 TB/s — the wall.
// Now: counting-sort edges by dst into CSR (int atomics only), then GATHER:
//   g = (h @ W^T) * dinv                      (transform kernels)
//   h' = relu(dinv*(g[i] + sum_{src in N(i)} g[src]) + b)   (gather kernels)
// Pool uses sorted `batch`: per-graph node ranges, block-per-graph LDS reduce,
// fused with the FC. Zero fp32 atomics anywhere.
// NOTE: integer inputs are int32 on device (NOT int64).

static constexpr int TPB = 256;

__global__ void deg_kernel(const int* __restrict__ dst, int* __restrict__ deg, int E) {
  int e = blockIdx.x * blockDim.x + threadIdx.x;
  if (e < E) atomicAdd(&deg[dst[e]], 1);
}

// Single-workgroup exclusive scan of deg -> rowptr & cursor; also dinv = rsqrt(deg+1).
__global__ __launch_bounds__(1024) void scan_kernel(const int* __restrict__ deg,
                                                    int* __restrict__ rowptr,
                                                    int* __restrict__ cursor,
                                                    float* __restrict__ dinv, int n, int E) {
  const int T = 1024;
  int t = threadIdx.x;
  int chunk = (n + T - 1) / T;
  int lo = t * chunk, hi = min(lo + chunk, n);
  int s = 0;
  for (int i = lo; i < hi; ++i) s += deg[i];
  __shared__ int cs[T];
  cs[t] = s;
  __syncthreads();
  for (int off = 1; off < T; off <<= 1) {  // Hillis-Steele inclusive scan
    int v = (t >= off) ? cs[t - off] : 0;
    __syncthreads();
    cs[t] += v;
    __syncthreads();
  }
  int run = (t == 0) ? 0 : cs[t - 1];
  for (int i = lo; i < hi; ++i) {
    rowptr[i] = run;
    cursor[i] = run;
    dinv[i] = rsqrtf((float)deg[i] + 1.0f);  // +1 self-loop
    run += deg[i];
  }
  if (t == 0) rowptr[n] = E;
}

__global__ void fill_kernel(const int* __restrict__ src, const int* __restrict__ dst,
                            int* __restrict__ cursor, int* __restrict__ esrc, int E) {
  int e = blockIdx.x * blockDim.x + threadIdx.x;
  if (e >= E) return;
  int pos = atomicAdd(&cursor[dst[e]], 1);
  esrc[pos] = src[e];
}

// Graph ranges from sorted batch: gstart[g] = first i with batch[i] >= g.
__global__ void gptr_kernel(const int* __restrict__ batch, int* __restrict__ gstart, int n, int G) {
  int i = blockIdx.x * blockDim.x + threadIdx.x;
  if (i >= n) return;
  int b = batch[i];
  int bp = (i == 0) ? -1 : batch[i - 1];
  for (int g = bp + 1; g <= b; ++g) gstart[g] = i;
  if (i == n - 1)
    for (int g = b + 1; g <= G; ++g) gstart[g] = n;
}

// Layer 1 transform: in=2, out=32. One thread per (node, f).
__global__ void transform1_kernel(const float* __restrict__ x, const float* __restrict__ W1,
                                  const float* __restrict__ dinv, float* __restrict__ g, int n) {
  int tid = blockIdx.x * blockDim.x + threadIdx.x;
  int i = tid >> 5, f = tid & 31;
  if (i >= n) return;
  g[(size_t)i * 32 + f] =
      (x[i * 2 + 0] * W1[f * 2 + 0] + x[i * 2 + 1] * W1[f * 2 + 1]) * dinv[i];
}

// Mid transform: g = (h @ W^T) * dinv. h is already activated. NPB nodes x OUT feats per block.
template <int IN, int OUT, int NPB>
__global__ void transform_mid_kernel(const float* __restrict__ h, const float* __restrict__ W,
                                     const float* __restrict__ dinv, float* __restrict__ g, int n) {
  __shared__ float Wl[IN * OUT];  // transposed: Wl[j*OUT+f]
  __shared__ float al[NPB][IN];
  int t = threadIdx.x;
  for (int idx = t; idx < IN * OUT; idx += TPB) {
    int f = idx / IN, j = idx % IN;
    Wl[j * OUT + f] = W[idx];
  }
  int base = blockIdx.x * NPB;
  for (int idx = t; idx < NPB * IN; idx += TPB) {
    int nl = idx / IN, j = idx % IN;
    int node = base + nl;
    al[nl][j] = (node < n) ? h[(size_t)node * IN + j] : 0.f;
  }
  __syncthreads();
  int nl = t / OUT, f = t % OUT;
  int node = base + nl;
  if (node >= n) return;
  float s = 0.f;
#pragma unroll
  for (int j = 0; j < IN; ++j) s += al[nl][j] * Wl[j * OUT + f];
  g[(size_t)node * OUT + f] = dinv[node] * s;
}

// Gather + epilogue: h[i] = relu(dinv[i]*(g[i] + sum g[src]) + b). Q = F/4 float4 lanes/node.
template <int LOGQ>
__global__ void gather_kernel(const float4* __restrict__ g4, const int* __restrict__ rowptr,
                              const int* __restrict__ esrc, const float* __restrict__ dinv,
                              const float* __restrict__ b, float4* __restrict__ h4, int n) {
  constexpr int Q = 1 << LOGQ;
  int tid = blockIdx.x * blockDim.x + threadIdx.x;
  int i = tid >> LOGQ, q = tid & (Q - 1);
  if (i >= n) return;
  int r0 = rowptr[i], r1 = rowptr[i + 1];
  float4 acc = g4[(size_t)i * Q + q];  // self-loop
  for (int e = r0; e < r1; ++e) {
    int s = esrc[e];
    float4 v = g4[(size_t)s * Q + q];
    acc.x += v.x; acc.y += v.y; acc.z += v.z; acc.w += v.w;
  }
  float di = dinv[i];
  const float4 bv = ((const float4*)b)[q];
  float4 o;
  o.x = fmaxf(di * acc.x + bv.x, 0.f);
  o.y = fmaxf(di * acc.y + bv.y, 0.f);
  o.z = fmaxf(di * acc.z + bv.z, 0.f);
  o.w = fmaxf(di * acc.w + bv.w, 0.f);
  h4[(size_t)i * Q + q] = o;
}

// Block per graph: mean-pool h3 over the graph's node range, then FC. No atomics.
__global__ void poolfc_kernel(const float* __restrict__ h3, const int* __restrict__ gstart,
                              const float* __restrict__ Wfc, const float* __restrict__ bfc,
                              float* __restrict__ out) {
  int gi = blockIdx.x;
  int s = gstart[gi], e = gstart[gi + 1];
  int t = threadIdx.x;
  int nl = t >> 5, f = t & 31;
  float acc = 0.f;
  for (int i = s + nl; i < e; i += 8) acc += h3[(size_t)i * 32 + f];
  __shared__ float red[256];
  red[t] = acc;
  __syncthreads();
  for (int st = 128; st >= 32; st >>= 1) {
    if (t < st) red[t] += red[t + st];
    __syncthreads();
  }
  if (t < 32) {
    float cnt = (float)(e - s);
    float v = (red[t] / fmaxf(cnt, 1.f)) * Wfc[t];
    for (int o = 16; o; o >>= 1) v += __shfl_down(v, o, 32);
    if (t == 0) out[gi] = v + bfc[0];
  }
}

extern "C" void kernel_launch(void* const* d_in, const int* in_sizes, int n_in,
                              void* d_out, int out_size, void* d_ws, size_t ws_size,
                              hipStream_t stream) {
  const float* x     = (const float*)d_in[0];
  const int*   ei    = (const int*)d_in[1];  // int32 on device
  const int*   batch = (const int*)d_in[2];
  const float* W1    = (const float*)d_in[3];
  const float* b1    = (const float*)d_in[4];
  const float* W2    = (const float*)d_in[5];
  const float* b2    = (const float*)d_in[6];
  const float* W3    = (const float*)d_in[7];
  const float* b3    = (const float*)d_in[8];
  const float* Wfc   = (const float*)d_in[9];
  const float* bfc   = (const float*)d_in[10];
  float* out = (float*)d_out;

  const int N = in_sizes[0] / 2;
  const int E = in_sizes[1] / 2;
  const int G = out_size;  // 512
  const int* src = ei;
  const int* dst = ei + E;

  char* ws = (char*)d_ws;
  size_t off = 0;
  auto alloc = [&](size_t bytes) -> char* {
    char* p = ws + off;
    off += (bytes + 255) & ~(size_t)255;
    return p;
  };
  int*   deg    = (int*)alloc((size_t)N * 4);
  float* dinv   = (float*)alloc((size_t)N * 4);
  int*   rowptr = (int*)alloc((size_t)(N + 1) * 4);
  int*   cursor = (int*)alloc((size_t)N * 4);
  int*   esrc   = (int*)alloc((size_t)E * 4);
  int*   gstart = (int*)alloc((size_t)(G + 1) * 4);
  float* g      = (float*)alloc((size_t)N * 64 * 4);  // transform output, reused per layer
  float* hA     = (float*)alloc((size_t)N * 32 * 4);  // h1, then h3
  float* hB     = (float*)alloc((size_t)N * 64 * 4);  // h2

  hipMemsetAsync(deg, 0, (size_t)N * 4, stream);

  // --- structure (per call; ws is re-poisoned every launch) ---
  deg_kernel<<<(E + TPB - 1) / TPB, TPB, 0, stream>>>(dst, deg, E);
  scan_kernel<<<1, 1024, 0, stream>>>(deg, rowptr, cursor, dinv, N, E);
  fill_kernel<<<(E + TPB - 1) / TPB, TPB, 0, stream>>>(src, dst, cursor, esrc, E);
  gptr_kernel<<<(N + TPB - 1) / TPB, TPB, 0, stream>>>(batch, gstart, N, G);

  // --- layer 1: 2 -> 32 ---
  transform1_kernel<<<((size_t)N * 32 + TPB - 1) / TPB, TPB, 0, stream>>>(x, W1, dinv, g, N);
  gather_kernel<3><<<((size_t)N * 8 + TPB - 1) / TPB, TPB, 0, stream>>>(
      (const float4*)g, rowptr, esrc, dinv, b1, (float4*)hA, N);

  // --- layer 2: 32 -> 64 ---
  transform_mid_kernel<32, 64, 4><<<(N + 3) / 4, TPB, 0, stream>>>(hA, W2, dinv, g, N);
  gather_kernel<4><<<((size_t)N * 16 + TPB - 1) / TPB, TPB, 0, stream>>>(
      (const float4*)g, rowptr, esrc, dinv, b2, (float4*)hB, N);

  // --- layer 3: 64 -> 32 ---
  transform_mid_kernel<64, 32, 8><<<(N + 7) / 8, TPB, 0, stream>>>(hB, W3, dinv, g, N);
  gather_kernel<3><<<((size_t)N * 8 + TPB - 1) / TPB, TPB, 0, stream>>>(
      (const float4*)g, rowptr, esrc, dinv, b3, (float4*)hA, N);

  // --- pool + fc ---
  poolfc_kernel<<<G, 256, 0, stream>>>(hA, gstart, Wfc, bfc, out);
}

// Round 4
// 610.505 us; speedup vs baseline: 5.1690x; 1.4362x over previous
//
#include <hip/hip_runtime.h>

// GCN: 3x GCNConv(relu) + global_mean_pool + FC, fp32.
// R4: replace the single-block scan (280 us, 1 CU, uncoalesced) with a
// two-level multi-block scan (partial sums -> scan sums -> emit). Everything
// else unchanged from R3 (atomic-free CSR gather aggregation).
// NOTE: integer inputs are int32 on device (NOT int64).

static constexpr int TPB = 256;
static constexpr int NB_SCAN = 256;  // scan blocks

__global__ void deg_kernel(const int* __restrict__ dst, int* __restrict__ deg, int E) {
  int e = blockIdx.x * blockDim.x + threadIdx.x;
  if (e < E) atomicAdd(&deg[dst[e]], 1);
}

// --- two-level exclusive scan of deg over N elements ---
// Level 1: per-segment sums. Segment b = [b*seg, min((b+1)*seg, n)).
__global__ void scan_partial_kernel(const int* __restrict__ deg, int* __restrict__ blocksum,
                                    int n, int seg) {
  int b = blockIdx.x, t = threadIdx.x;
  int lo = b * seg, hi = min(lo + seg, n);
  int acc = 0;
  for (int i = lo + t; i < hi; i += TPB) acc += deg[i];
  __shared__ int red[TPB];
  red[t] = acc;
  __syncthreads();
  for (int st = TPB / 2; st > 0; st >>= 1) {
    if (t < st) red[t] += red[t + st];
    __syncthreads();
  }
  if (t == 0) blocksum[b] = red[0];
}

// Level 2: exclusive scan of the NB_SCAN block sums (one tiny block).
__global__ void scan_blocks_kernel(int* __restrict__ blocksum) {
  __shared__ int cs[NB_SCAN];
  int t = threadIdx.x;
  int v = blocksum[t];
  cs[t] = v;
  __syncthreads();
  for (int off = 1; off < NB_SCAN; off <<= 1) {  // Hillis-Steele inclusive
    int u = (t >= off) ? cs[t - off] : 0;
    __syncthreads();
    cs[t] += u;
    __syncthreads();
  }
  blocksum[t] = cs[t] - v;  // exclusive
}

// Level 3: emit rowptr/cursor/dinv, tile-by-tile coalesced.
__global__ void scan_emit_kernel(const int* __restrict__ deg, const int* __restrict__ blocksum,
                                 int* __restrict__ rowptr, int* __restrict__ cursor,
                                 float* __restrict__ dinv, int n, int seg, int E) {
  int b = blockIdx.x, t = threadIdx.x;
  int lo = b * seg, hi = min(lo + seg, n);
  __shared__ int cs[TPB];
  __shared__ int s_run;
  if (t == 0) s_run = blocksum[b];
  __syncthreads();
  for (int base = lo; base < hi; base += TPB) {
    int i = base + t;
    int v = (i < hi) ? deg[i] : 0;
    cs[t] = v;
    __syncthreads();
    for (int off = 1; off < TPB; off <<= 1) {  // inclusive scan of tile
      int u = (t >= off) ? cs[t - off] : 0;
      __syncthreads();
      cs[t] += u;
      __syncthreads();
    }
    if (i < hi) {
      int excl = s_run + cs[t] - v;
      rowptr[i] = excl;
      cursor[i] = excl;
      dinv[i] = rsqrtf((float)v + 1.0f);  // +1 self-loop
    }
    __syncthreads();
    if (t == 0) s_run += cs[TPB - 1];
    __syncthreads();
  }
  if (b == 0 && t == 0) rowptr[n] = E;
}

__global__ void fill_kernel(const int* __restrict__ src, const int* __restrict__ dst,
                            int* __restrict__ cursor, int* __restrict__ esrc, int E) {
  int e = blockIdx.x * blockDim.x + threadIdx.x;
  if (e >= E) return;
  int pos = atomicAdd(&cursor[dst[e]], 1);
  esrc[pos] = src[e];
}

// Graph ranges from sorted batch: gstart[g] = first i with batch[i] >= g.
__global__ void gptr_kernel(const int* __restrict__ batch, int* __restrict__ gstart, int n, int G) {
  int i = blockIdx.x * blockDim.x + threadIdx.x;
  if (i >= n) return;
  int b = batch[i];
  int bp = (i == 0) ? -1 : batch[i - 1];
  for (int g = bp + 1; g <= b; ++g) gstart[g] = i;
  if (i == n - 1)
    for (int g = b + 1; g <= G; ++g) gstart[g] = n;
}

// Layer 1 transform: in=2, out=32. One thread per (node, f).
__global__ void transform1_kernel(const float* __restrict__ x, const float* __restrict__ W1,
                                  const float* __restrict__ dinv, float* __restrict__ g, int n) {
  int tid = blockIdx.x * blockDim.x + threadIdx.x;
  int i = tid >> 5, f = tid & 31;
  if (i >= n) return;
  g[(size_t)i * 32 + f] =
      (x[i * 2 + 0] * W1[f * 2 + 0] + x[i * 2 + 1] * W1[f * 2 + 1]) * dinv[i];
}

// Mid transform: g = (h @ W^T) * dinv. h is already activated. NPB nodes x OUT feats per block.
template <int IN, int OUT, int NPB>
__global__ void transform_mid_kernel(const float* __restrict__ h, const float* __restrict__ W,
                                     const float* __restrict__ dinv, float* __restrict__ g, int n) {
  __shared__ float Wl[IN * OUT];  // transposed: Wl[j*OUT+f]
  __shared__ float al[NPB][IN];
  int t = threadIdx.x;
  for (int idx = t; idx < IN * OUT; idx += TPB) {
    int f = idx / IN, j = idx % IN;
    Wl[j * OUT + f] = W[idx];
  }
  int base = blockIdx.x * NPB;
  for (int idx = t; idx < NPB * IN; idx += TPB) {
    int nl = idx / IN, j = idx % IN;
    int node = base + nl;
    al[nl][j] = (node < n) ? h[(size_t)node * IN + j] : 0.f;
  }
  __syncthreads();
  int nl = t / OUT, f = t % OUT;
  int node = base + nl;
  if (node >= n) return;
  float s = 0.f;
#pragma unroll
  for (int j = 0; j < IN; ++j) s += al[nl][j] * Wl[j * OUT + f];
  g[(size_t)node * OUT + f] = dinv[node] * s;
}

// Gather + epilogue: h[i] = relu(dinv[i]*(g[i] + sum g[src]) + b). Q = F/4 float4 lanes/node.
template <int LOGQ>
__global__ void gather_kernel(const float4* __restrict__ g4, const int* __restrict__ rowptr,
                              const int* __restrict__ esrc, const float* __restrict__ dinv,
                              const float* __restrict__ b, float4* __restrict__ h4, int n) {
  constexpr int Q = 1 << LOGQ;
  int tid = blockIdx.x * blockDim.x + threadIdx.x;
  int i = tid >> LOGQ, q = tid & (Q - 1);
  if (i >= n) return;
  int r0 = rowptr[i], r1 = rowptr[i + 1];
  float4 acc = g4[(size_t)i * Q + q];  // self-loop
  for (int e = r0; e < r1; ++e) {
    int s = esrc[e];
    float4 v = g4[(size_t)s * Q + q];
    acc.x += v.x; acc.y += v.y; acc.z += v.z; acc.w += v.w;
  }
  float di = dinv[i];
  const float4 bv = ((const float4*)b)[q];
  float4 o;
  o.x = fmaxf(di * acc.x + bv.x, 0.f);
  o.y = fmaxf(di * acc.y + bv.y, 0.f);
  o.z = fmaxf(di * acc.z + bv.z, 0.f);
  o.w = fmaxf(di * acc.w + bv.w, 0.f);
  h4[(size_t)i * Q + q] = o;
}

// Block per graph: mean-pool h3 over the graph's node range, then FC. No atomics.
__global__ void poolfc_kernel(const float* __restrict__ h3, const int* __restrict__ gstart,
                              const float* __restrict__ Wfc, const float* __restrict__ bfc,
                              float* __restrict__ out) {
  int gi = blockIdx.x;
  int s = gstart[gi], e = gstart[gi + 1];
  int t = threadIdx.x;
  int nl = t >> 5, f = t & 31;
  float acc = 0.f;
  for (int i = s + nl; i < e; i += 8) acc += h3[(size_t)i * 32 + f];
  __shared__ float red[256];
  red[t] = acc;
  __syncthreads();
  for (int st = 128; st >= 32; st >>= 1) {
    if (t < st) red[t] += red[t + st];
    __syncthreads();
  }
  if (t < 32) {
    float cnt = (float)(e - s);
    float v = (red[t] / fmaxf(cnt, 1.f)) * Wfc[t];
    for (int o = 16; o; o >>= 1) v += __shfl_down(v, o, 32);
    if (t == 0) out[gi] = v + bfc[0];
  }
}

extern "C" void kernel_launch(void* const* d_in, const int* in_sizes, int n_in,
                              void* d_out, int out_size, void* d_ws, size_t ws_size,
                              hipStream_t stream) {
  const float* x     = (const float*)d_in[0];
  const int*   ei    = (const int*)d_in[1];  // int32 on device
  const int*   batch = (const int*)d_in[2];
  const float* W1    = (const float*)d_in[3];
  const float* b1    = (const float*)d_in[4];
  const float* W2    = (const float*)d_in[5];
  const float* b2    = (const float*)d_in[6];
  const float* W3    = (const float*)d_in[7];
  const float* b3    = (const float*)d_in[8];
  const float* Wfc   = (const float*)d_in[9];
  const float* bfc   = (const float*)d_in[10];
  float* out = (float*)d_out;

  const int N = in_sizes[0] / 2;
  const int E = in_sizes[1] / 2;
  const int G = out_size;  // 512
  const int* src = ei;
  const int* dst = ei + E;

  char* ws = (char*)d_ws;
  size_t off = 0;
  auto alloc = [&](size_t bytes) -> char* {
    char* p = ws + off;
    off += (bytes + 255) & ~(size_t)255;
    return p;
  };
  int*   deg      = (int*)alloc((size_t)N * 4);
  float* dinv     = (float*)alloc((size_t)N * 4);
  int*   rowptr   = (int*)alloc((size_t)(N + 1) * 4);
  int*   cursor   = (int*)alloc((size_t)N * 4);
  int*   esrc     = (int*)alloc((size_t)E * 4);
  int*   gstart   = (int*)alloc((size_t)(G + 1) * 4);
  int*   blocksum = (int*)alloc((size_t)NB_SCAN * 4);
  float* g        = (float*)alloc((size_t)N * 64 * 4);  // transform output, reused per layer
  float* hA       = (float*)alloc((size_t)N * 32 * 4);  // h1, then h3
  float* hB       = (float*)alloc((size_t)N * 64 * 4);  // h2

  hipMemsetAsync(deg, 0, (size_t)N * 4, stream);

  // --- structure (per call; ws is re-poisoned every launch) ---
  deg_kernel<<<(E + TPB - 1) / TPB, TPB, 0, stream>>>(dst, deg, E);
  const int seg = (N + NB_SCAN - 1) / NB_SCAN;
  scan_partial_kernel<<<NB_SCAN, TPB, 0, stream>>>(deg, blocksum, N, seg);
  scan_blocks_kernel<<<1, NB_SCAN, 0, stream>>>(blocksum);
  scan_emit_kernel<<<NB_SCAN, TPB, 0, stream>>>(deg, blocksum, rowptr, cursor, dinv, N, seg, E);
  fill_kernel<<<(E + TPB - 1) / TPB, TPB, 0, stream>>>(src, dst, cursor, esrc, E);
  gptr_kernel<<<(N + TPB - 1) / TPB, TPB, 0, stream>>>(batch, gstart, N, G);

  // --- layer 1: 2 -> 32 ---
  transform1_kernel<<<((size_t)N * 32 + TPB - 1) / TPB, TPB, 0, stream>>>(x, W1, dinv, g, N);
  gather_kernel<3><<<((size_t)N * 8 + TPB - 1) / TPB, TPB, 0, stream>>>(
      (const float4*)g, rowptr, esrc, dinv, b1, (float4*)hA, N);

  // --- layer 2: 32 -> 64 ---
  transform_mid_kernel<32, 64, 4><<<(N + 3) / 4, TPB, 0, stream>>>(hA, W2, dinv, g, N);
  gather_kernel<4><<<((size_t)N * 16 + TPB - 1) / TPB, TPB, 0, stream>>>(
      (const float4*)g, rowptr, esrc, dinv, b2, (float4*)hB, N);

  // --- layer 3: 64 -> 32 ---
  transform_mid_kernel<64, 32, 8><<<(N + 7) / 8, TPB, 0, stream>>>(hB, W3, dinv, g, N);
  gather_kernel<3><<<((size_t)N * 8 + TPB - 1) / TPB, TPB, 0, stream>>>(
      (const float4*)g, rowptr, esrc, dinv, b3, (float4*)hA, N);

  // --- pool + fc ---
  poolfc_kernel<<<G, 256, 0, stream>>>(hA, gstart, Wfc, bfc, out);
}

// Round 5
// 471.684 us; speedup vs baseline: 6.6903x; 1.2943x over previous
//
#include <hip/hip_runtime.h>

// GCN: 3x GCNConv(relu) + global_mean_pool + FC, fp32.
// R5: replace deg(random global atomics)+fill(random 4B scatter, 105MB line
// writebacks, 130us) with a bucketed counting sort whose random access lives
// entirely in LDS:
//   P1: LDS histogram into B buckets (128 node-ids each) -> generic scan of
//       the (bucket,block) table -> scatter (src,dst) pairs bucket-contiguous
//       (runs of ~8 edges = 64B coalesced writes).
//   P2: block-per-bucket: LDS count -> LDS scan -> rowptr/dinv emit, then
//       LDS-staged sort and fully-coalesced esrc writeback. No global atomics.
// Aggregation/transform/pool unchanged from R4 (atomic-free CSR gather).
// NOTE: integer inputs are int32 on device (NOT int64).

static constexpr int TPB = 256;
static constexpr int NB1 = 256;      // phase-1 blocks
static constexpr int NB_SCAN = 256;  // scan blocks
static constexpr int P2CAP = 6144;   // per-bucket LDS staging (ints); avg bucket ~2046

// ---------- phase 1a: per-(bucket,block) histogram ----------
__global__ void p1_hist_kernel(const int* __restrict__ dst, int* __restrict__ hist,
                               int E, int chunk, int shift, int B) {
  __shared__ int h[1024];  // B <= 1024 by construction
  int b = blockIdx.x, t = threadIdx.x;
  for (int i = t; i < B; i += TPB) h[i] = 0;
  __syncthreads();
  int lo = b * chunk, hi = min(lo + chunk, E);
  for (int e = lo + t; e < hi; e += TPB) atomicAdd(&h[dst[e] >> shift], 1);
  __syncthreads();
  for (int i = t; i < B; i += TPB) hist[i * NB1 + b] = h[i];
}

// ---------- generic two-level exclusive scan (in place) ----------
__global__ void scan_partial_kernel(const int* __restrict__ a, int* __restrict__ bsum,
                                    int n, int seg) {
  int b = blockIdx.x, t = threadIdx.x;
  int lo = b * seg, hi = min(lo + seg, n);
  int acc = 0;
  for (int i = lo + t; i < hi; i += TPB) acc += a[i];
  __shared__ int red[TPB];
  red[t] = acc;
  __syncthreads();
  for (int st = TPB / 2; st > 0; st >>= 1) {
    if (t < st) red[t] += red[t + st];
    __syncthreads();
  }
  if (t == 0) bsum[b] = red[0];
}

__global__ void scan_blocks_kernel(int* __restrict__ bsum) {
  __shared__ int cs[NB_SCAN];
  int t = threadIdx.x;
  int v = bsum[t];
  cs[t] = v;
  __syncthreads();
  for (int off = 1; off < NB_SCAN; off <<= 1) {
    int u = (t >= off) ? cs[t - off] : 0;
    __syncthreads();
    cs[t] += u;
    __syncthreads();
  }
  bsum[t] = cs[t] - v;  // exclusive
}

__global__ void scan_emit_kernel(int* __restrict__ a, const int* __restrict__ bsum,
                                 int n, int seg) {
  int b = blockIdx.x, t = threadIdx.x;
  int lo = b * seg, hi = min(lo + seg, n);
  __shared__ int cs[TPB];
  __shared__ int s_run;
  if (t == 0) s_run = bsum[b];
  __syncthreads();
  for (int base = lo; base < hi; base += TPB) {
    int i = base + t;
    int v = (i < hi) ? a[i] : 0;
    cs[t] = v;
    __syncthreads();
    for (int off = 1; off < TPB; off <<= 1) {
      int u = (t >= off) ? cs[t - off] : 0;
      __syncthreads();
      cs[t] += u;
      __syncthreads();
    }
    if (i < hi) a[i] = s_run + cs[t] - v;  // exclusive
    __syncthreads();
    if (t == 0) s_run += cs[TPB - 1];
    __syncthreads();
  }
}

// ---------- phase 1b: scatter edges into bucket-contiguous epair ----------
__global__ void p1_scatter_kernel(const int* __restrict__ src, const int* __restrict__ dst,
                                  const int* __restrict__ hist, int2* __restrict__ epair,
                                  int E, int chunk, int shift, int B) {
  __shared__ int cur[1024];
  int b = blockIdx.x, t = threadIdx.x;
  for (int i = t; i < B; i += TPB) cur[i] = hist[i * NB1 + b];
  __syncthreads();
  int lo = b * chunk, hi = min(lo + chunk, E);
  for (int e = lo + t; e < hi; e += TPB) {
    int d = dst[e];
    int pos = atomicAdd(&cur[d >> shift], 1);
    epair[pos] = make_int2(src[e], d);
  }
}

// ---------- phase 2: per-bucket counting sort + rowptr/dinv emit ----------
__global__ __launch_bounds__(TPB) void p2_sort_kernel(
    const int2* __restrict__ epair, const int* __restrict__ hist,
    int* __restrict__ rowptr, float* __restrict__ dinv, int* __restrict__ esrc,
    int N, int E, int shift, int B) {
  int bkt = blockIdx.x, t = threadIdx.x;
  int span = 1 << shift;  // <= 256
  int nb = bkt << shift;
  int bstart = hist[bkt * NB1];
  int bend = (bkt + 1 < B) ? hist[(bkt + 1) * NB1] : E;
  int bsize = bend - bstart;
  __shared__ int cnt[256];
  __shared__ int ex[256];
  __shared__ int lsrc[P2CAP];
  if (t < span) cnt[t] = 0;
  __syncthreads();
  for (int e = bstart + t; e < bend; e += TPB) atomicAdd(&cnt[epair[e].y - nb], 1);
  __syncthreads();
  int v = (t < span) ? cnt[t] : 0;
  ex[t] = v;
  __syncthreads();
  for (int off = 1; off < 256; off <<= 1) {  // Hillis-Steele inclusive
    int u = (t >= off) ? ex[t - off] : 0;
    __syncthreads();
    ex[t] += u;
    __syncthreads();
  }
  int excl = ex[t] - v;  // exclusive scan value
  int node = nb + t;
  if (t < span && node < N) {
    rowptr[node] = bstart + excl;
    dinv[node] = rsqrtf((float)v + 1.0f);  // +1 self-loop
  }
  if (bkt == 0 && t == 0) rowptr[N] = E;
  __syncthreads();
  bool stage = (bsize <= P2CAP);  // fallback keeps any input correct
  if (t < span) cnt[t] = stage ? excl : bstart + excl;  // reuse cnt as cursor
  __syncthreads();
  for (int e = bstart + t; e < bend; e += TPB) {
    int2 p = epair[e];
    int pos = atomicAdd(&cnt[p.y - nb], 1);
    if (stage) lsrc[pos] = p.x;
    else esrc[pos] = p.x;
  }
  __syncthreads();
  if (stage)
    for (int i = t; i < bsize; i += TPB) esrc[bstart + i] = lsrc[i];  // coalesced
}

// Graph ranges from sorted batch: gstart[g] = first i with batch[i] >= g.
__global__ void gptr_kernel(const int* __restrict__ batch, int* __restrict__ gstart, int n, int G) {
  int i = blockIdx.x * blockDim.x + threadIdx.x;
  if (i >= n) return;
  int b = batch[i];
  int bp = (i == 0) ? -1 : batch[i - 1];
  for (int g = bp + 1; g <= b; ++g) gstart[g] = i;
  if (i == n - 1)
    for (int g = b + 1; g <= G; ++g) gstart[g] = n;
}

// Layer 1 transform: in=2, out=32. One thread per (node, f).
__global__ void transform1_kernel(const float* __restrict__ x, const float* __restrict__ W1,
                                  const float* __restrict__ dinv, float* __restrict__ g, int n) {
  int tid = blockIdx.x * blockDim.x + threadIdx.x;
  int i = tid >> 5, f = tid & 31;
  if (i >= n) return;
  g[(size_t)i * 32 + f] =
      (x[i * 2 + 0] * W1[f * 2 + 0] + x[i * 2 + 1] * W1[f * 2 + 1]) * dinv[i];
}

// Mid transform: g = (h @ W^T) * dinv. NPB nodes x OUT feats per block.
template <int IN, int OUT, int NPB>
__global__ void transform_mid_kernel(const float* __restrict__ h, const float* __restrict__ W,
                                     const float* __restrict__ dinv, float* __restrict__ g, int n) {
  __shared__ float Wl[IN * OUT];  // transposed: Wl[j*OUT+f]
  __shared__ float al[NPB][IN];
  int t = threadIdx.x;
  for (int idx = t; idx < IN * OUT; idx += TPB) {
    int f = idx / IN, j = idx % IN;
    Wl[j * OUT + f] = W[idx];
  }
  int base = blockIdx.x * NPB;
  for (int idx = t; idx < NPB * IN; idx += TPB) {
    int nl = idx / IN, j = idx % IN;
    int node = base + nl;
    al[nl][j] = (node < n) ? h[(size_t)node * IN + j] : 0.f;
  }
  __syncthreads();
  int nl = t / OUT, f = t % OUT;
  int node = base + nl;
  if (node >= n) return;
  float s = 0.f;
#pragma unroll
  for (int j = 0; j < IN; ++j) s += al[nl][j] * Wl[j * OUT + f];
  g[(size_t)node * OUT + f] = dinv[node] * s;
}

// Gather + epilogue: h[i] = relu(dinv[i]*(g[i] + sum g[src]) + b). Q = F/4 float4 lanes/node.
template <int LOGQ>
__global__ void gather_kernel(const float4* __restrict__ g4, const int* __restrict__ rowptr,
                              const int* __restrict__ esrc, const float* __restrict__ dinv,
                              const float* __restrict__ b, float4* __restrict__ h4, int n) {
  constexpr int Q = 1 << LOGQ;
  int tid = blockIdx.x * blockDim.x + threadIdx.x;
  int i = tid >> LOGQ, q = tid & (Q - 1);
  if (i >= n) return;
  int r0 = rowptr[i], r1 = rowptr[i + 1];
  float4 acc = g4[(size_t)i * Q + q];  // self-loop
  for (int e = r0; e < r1; ++e) {
    int s = esrc[e];
    float4 v = g4[(size_t)s * Q + q];
    acc.x += v.x; acc.y += v.y; acc.z += v.z; acc.w += v.w;
  }
  float di = dinv[i];
  const float4 bv = ((const float4*)b)[q];
  float4 o;
  o.x = fmaxf(di * acc.x + bv.x, 0.f);
  o.y = fmaxf(di * acc.y + bv.y, 0.f);
  o.z = fmaxf(di * acc.z + bv.z, 0.f);
  o.w = fmaxf(di * acc.w + bv.w, 0.f);
  h4[(size_t)i * Q + q] = o;
}

// Block per graph: mean-pool h3 over the graph's node range, then FC. No atomics.
__global__ void poolfc_kernel(const float* __restrict__ h3, const int* __restrict__ gstart,
                              const float* __restrict__ Wfc, const float* __restrict__ bfc,
                              float* __restrict__ out) {
  int gi = blockIdx.x;
  int s = gstart[gi], e = gstart[gi + 1];
  int t = threadIdx.x;
  int nl = t >> 5, f = t & 31;
  float acc = 0.f;
  for (int i = s + nl; i < e; i += 8) acc += h3[(size_t)i * 32 + f];
  __shared__ float red[256];
  red[t] = acc;
  __syncthreads();
  for (int st = 128; st >= 32; st >>= 1) {
    if (t < st) red[t] += red[t + st];
    __syncthreads();
  }
  if (t < 32) {
    float cnt = (float)(e - s);
    float v = (red[t] / fmaxf(cnt, 1.f)) * Wfc[t];
    for (int o = 16; o; o >>= 1) v += __shfl_down(v, o, 32);
    if (t == 0) out[gi] = v + bfc[0];
  }
}

extern "C" void kernel_launch(void* const* d_in, const int* in_sizes, int n_in,
                              void* d_out, int out_size, void* d_ws, size_t ws_size,
                              hipStream_t stream) {
  const float* x     = (const float*)d_in[0];
  const int*   ei    = (const int*)d_in[1];  // int32 on device
  const int*   batch = (const int*)d_in[2];
  const float* W1    = (const float*)d_in[3];
  const float* b1    = (const float*)d_in[4];
  const float* W2    = (const float*)d_in[5];
  const float* b2    = (const float*)d_in[6];
  const float* W3    = (const float*)d_in[7];
  const float* b3    = (const float*)d_in[8];
  const float* Wfc   = (const float*)d_in[9];
  const float* bfc   = (const float*)d_in[10];
  float* out = (float*)d_out;

  const int N = in_sizes[0] / 2;
  const int E = in_sizes[1] / 2;
  const int G = out_size;  // 512
  const int* src = ei;
  const int* dst = ei + E;

  // Bucket geometry: span = 1<<shift node-ids per bucket, B <= 1024 buckets,
  // span <= 256 (p2 LDS arrays). Holds for N <= 262144.
  int shift = 7;
  while ((((N + (1 << shift) - 1) >> shift)) > 1024) ++shift;
  const int B = (N + (1 << shift) - 1) >> shift;
  const int chunkE = (E + NB1 - 1) / NB1;
  const int M = B * NB1;
  const int segM = (M + NB_SCAN - 1) / NB_SCAN;

  char* ws = (char*)d_ws;
  size_t off = 0;
  auto alloc = [&](size_t bytes) -> char* {
    char* p = ws + off;
    off += (bytes + 255) & ~(size_t)255;
    return p;
  };
  float* dinv   = (float*)alloc((size_t)N * 4);
  int*   rowptr = (int*)alloc((size_t)(N + 1) * 4);
  int*   esrc   = (int*)alloc((size_t)E * 4);
  int*   gstart = (int*)alloc((size_t)(G + 1) * 4);
  int*   hist   = (int*)alloc((size_t)M * 4);
  int*   bsum   = (int*)alloc((size_t)NB_SCAN * 4);
  float* g      = (float*)alloc((size_t)N * 64 * 4);  // transform out; epair aliases this
  float* hA     = (float*)alloc((size_t)N * 32 * 4);  // h1, then h3
  float* hB     = (float*)alloc((size_t)N * 64 * 4);  // h2
  int2*  epair  = (int2*)g;  // 12.8 MB <= 25.6 MB; dead before transform1 writes g

  // --- structure build: bucketed counting sort (no global atomics) ---
  p1_hist_kernel<<<NB1, TPB, 0, stream>>>(dst, hist, E, chunkE, shift, B);
  scan_partial_kernel<<<NB_SCAN, TPB, 0, stream>>>(hist, bsum, M, segM);
  scan_blocks_kernel<<<1, NB_SCAN, 0, stream>>>(bsum);
  scan_emit_kernel<<<NB_SCAN, TPB, 0, stream>>>(hist, bsum, M, segM);
  p1_scatter_kernel<<<NB1, TPB, 0, stream>>>(src, dst, hist, epair, E, chunkE, shift, B);
  p2_sort_kernel<<<B, TPB, 0, stream>>>(epair, hist, rowptr, dinv, esrc, N, E, shift, B);
  gptr_kernel<<<(N + TPB - 1) / TPB, TPB, 0, stream>>>(batch, gstart, N, G);

  // --- layer 1: 2 -> 32 ---
  transform1_kernel<<<((size_t)N * 32 + TPB - 1) / TPB, TPB, 0, stream>>>(x, W1, dinv, g, N);
  gather_kernel<3><<<((size_t)N * 8 + TPB - 1) / TPB, TPB, 0, stream>>>(
      (const float4*)g, rowptr, esrc, dinv, b1, (float4*)hA, N);

  // --- layer 2: 32 -> 64 ---
  transform_mid_kernel<32, 64, 4><<<(N + 3) / 4, TPB, 0, stream>>>(hA, W2, dinv, g, N);
  gather_kernel<4><<<((size_t)N * 16 + TPB - 1) / TPB, TPB, 0, stream>>>(
      (const float4*)g, rowptr, esrc, dinv, b2, (float4*)hB, N);

  // --- layer 3: 64 -> 32 ---
  transform_mid_kernel<64, 32, 8><<<(N + 7) / 8, TPB, 0, stream>>>(hB, W3, dinv, g, N);
  gather_kernel<3><<<((size_t)N * 8 + TPB - 1) / TPB, TPB, 0, stream>>>(
      (const float4*)g, rowptr, esrc, dinv, b3, (float4*)hA, N);

  // --- pool + fc ---
  poolfc_kernel<<<G, 256, 0, stream>>>(hA, gstart, Wfc, bfc, out);
}

// Round 6
// 358.904 us; speedup vs baseline: 8.7926x; 1.3142x over previous
//
#include <hip/hip_runtime.h>

// GCN: 3x GCNConv(relu) + global_mean_pool + FC, fp32.
// R6: pad Wl LDS stride to OUT+1. R5 counters: transform_mid = 108us with
// SQ_LDS_BANK_CONFLICT = 4.96e7 — the transposed W staging (stride-OUT
// writes) was 32/64-way bank conflicted; 32 staging instrs x ~60 cyc x 25000
// blocks / 256 CUs ~= 81us = the whole kernel. +1 padding makes writes hit
// all 32 banks (2 lanes/bank = free) and keeps reads 2-way (free).
// Everything else unchanged from R5.
// NOTE: integer inputs are int32 on device (NOT int64).

static constexpr int TPB = 256;
static constexpr int NB1 = 256;      // phase-1 blocks
static constexpr int NB_SCAN = 256;  // scan blocks
static constexpr int P2CAP = 6144;   // per-bucket LDS staging (ints)

// ---------- phase 1a: per-(bucket,block) histogram ----------
__global__ void p1_hist_kernel(const int* __restrict__ dst, int* __restrict__ hist,
                               int E, int chunk, int shift, int B) {
  __shared__ int h[1024];  // B <= 1024 by construction
  int b = blockIdx.x, t = threadIdx.x;
  for (int i = t; i < B; i += TPB) h[i] = 0;
  __syncthreads();
  int lo = b * chunk, hi = min(lo + chunk, E);
  for (int e = lo + t; e < hi; e += TPB) atomicAdd(&h[dst[e] >> shift], 1);
  __syncthreads();
  for (int i = t; i < B; i += TPB) hist[i * NB1 + b] = h[i];
}

// ---------- generic two-level exclusive scan (in place) ----------
__global__ void scan_partial_kernel(const int* __restrict__ a, int* __restrict__ bsum,
                                    int n, int seg) {
  int b = blockIdx.x, t = threadIdx.x;
  int lo = b * seg, hi = min(lo + seg, n);
  int acc = 0;
  for (int i = lo + t; i < hi; i += TPB) acc += a[i];
  __shared__ int red[TPB];
  red[t] = acc;
  __syncthreads();
  for (int st = TPB / 2; st > 0; st >>= 1) {
    if (t < st) red[t] += red[t + st];
    __syncthreads();
  }
  if (t == 0) bsum[b] = red[0];
}

__global__ void scan_blocks_kernel(int* __restrict__ bsum) {
  __shared__ int cs[NB_SCAN];
  int t = threadIdx.x;
  int v = bsum[t];
  cs[t] = v;
  __syncthreads();
  for (int off = 1; off < NB_SCAN; off <<= 1) {
    int u = (t >= off) ? cs[t - off] : 0;
    __syncthreads();
    cs[t] += u;
    __syncthreads();
  }
  bsum[t] = cs[t] - v;  // exclusive
}

__global__ void scan_emit_kernel(int* __restrict__ a, const int* __restrict__ bsum,
                                 int n, int seg) {
  int b = blockIdx.x, t = threadIdx.x;
  int lo = b * seg, hi = min(lo + seg, n);
  __shared__ int cs[TPB];
  __shared__ int s_run;
  if (t == 0) s_run = bsum[b];
  __syncthreads();
  for (int base = lo; base < hi; base += TPB) {
    int i = base + t;
    int v = (i < hi) ? a[i] : 0;
    cs[t] = v;
    __syncthreads();
    for (int off = 1; off < TPB; off <<= 1) {
      int u = (t >= off) ? cs[t - off] : 0;
      __syncthreads();
      cs[t] += u;
      __syncthreads();
    }
    if (i < hi) a[i] = s_run + cs[t] - v;  // exclusive
    __syncthreads();
    if (t == 0) s_run += cs[TPB - 1];
    __syncthreads();
  }
}

// ---------- phase 1b: scatter edges into bucket-contiguous epair ----------
__global__ void p1_scatter_kernel(const int* __restrict__ src, const int* __restrict__ dst,
                                  const int* __restrict__ hist, int2* __restrict__ epair,
                                  int E, int chunk, int shift, int B) {
  __shared__ int cur[1024];
  int b = blockIdx.x, t = threadIdx.x;
  for (int i = t; i < B; i += TPB) cur[i] = hist[i * NB1 + b];
  __syncthreads();
  int lo = b * chunk, hi = min(lo + chunk, E);
  for (int e = lo + t; e < hi; e += TPB) {
    int d = dst[e];
    int pos = atomicAdd(&cur[d >> shift], 1);
    epair[pos] = make_int2(src[e], d);
  }
}

// ---------- phase 2: per-bucket counting sort + rowptr/dinv emit ----------
__global__ __launch_bounds__(TPB) void p2_sort_kernel(
    const int2* __restrict__ epair, const int* __restrict__ hist,
    int* __restrict__ rowptr, float* __restrict__ dinv, int* __restrict__ esrc,
    int N, int E, int shift, int B) {
  int bkt = blockIdx.x, t = threadIdx.x;
  int span = 1 << shift;  // <= 256
  int nb = bkt << shift;
  int bstart = hist[bkt * NB1];
  int bend = (bkt + 1 < B) ? hist[(bkt + 1) * NB1] : E;
  int bsize = bend - bstart;
  __shared__ int cnt[256];
  __shared__ int ex[256];
  __shared__ int lsrc[P2CAP];
  if (t < span) cnt[t] = 0;
  __syncthreads();
  for (int e = bstart + t; e < bend; e += TPB) atomicAdd(&cnt[epair[e].y - nb], 1);
  __syncthreads();
  int v = (t < span) ? cnt[t] : 0;
  ex[t] = v;
  __syncthreads();
  for (int off = 1; off < 256; off <<= 1) {  // Hillis-Steele inclusive
    int u = (t >= off) ? ex[t - off] : 0;
    __syncthreads();
    ex[t] += u;
    __syncthreads();
  }
  int excl = ex[t] - v;  // exclusive scan value
  int node = nb + t;
  if (t < span && node < N) {
    rowptr[node] = bstart + excl;
    dinv[node] = rsqrtf((float)v + 1.0f);  // +1 self-loop
  }
  if (bkt == 0 && t == 0) rowptr[N] = E;
  __syncthreads();
  bool stage = (bsize <= P2CAP);  // fallback keeps any input correct
  if (t < span) cnt[t] = stage ? excl : bstart + excl;  // reuse cnt as cursor
  __syncthreads();
  for (int e = bstart + t; e < bend; e += TPB) {
    int2 p = epair[e];
    int pos = atomicAdd(&cnt[p.y - nb], 1);
    if (stage) lsrc[pos] = p.x;
    else esrc[pos] = p.x;
  }
  __syncthreads();
  if (stage)
    for (int i = t; i < bsize; i += TPB) esrc[bstart + i] = lsrc[i];  // coalesced
}

// Graph ranges from sorted batch: gstart[g] = first i with batch[i] >= g.
__global__ void gptr_kernel(const int* __restrict__ batch, int* __restrict__ gstart, int n, int G) {
  int i = blockIdx.x * blockDim.x + threadIdx.x;
  if (i >= n) return;
  int b = batch[i];
  int bp = (i == 0) ? -1 : batch[i - 1];
  for (int g = bp + 1; g <= b; ++g) gstart[g] = i;
  if (i == n - 1)
    for (int g = b + 1; g <= G; ++g) gstart[g] = n;
}

// Layer 1 transform: in=2, out=32. One thread per (node, f).
__global__ void transform1_kernel(const float* __restrict__ x, const float* __restrict__ W1,
                                  const float* __restrict__ dinv, float* __restrict__ g, int n) {
  int tid = blockIdx.x * blockDim.x + threadIdx.x;
  int i = tid >> 5, f = tid & 31;
  if (i >= n) return;
  g[(size_t)i * 32 + f] =
      (x[i * 2 + 0] * W1[f * 2 + 0] + x[i * 2 + 1] * W1[f * 2 + 1]) * dinv[i];
}

// Mid transform: g = (h @ W^T) * dinv. NPB nodes x OUT feats per block.
// Wl stride padded to OUT+1: staging writes land on distinct banks
// (2 lanes/bank = free), reads stay 2-way (free).
template <int IN, int OUT, int NPB>
__global__ void transform_mid_kernel(const float* __restrict__ h, const float* __restrict__ W,
                                     const float* __restrict__ dinv, float* __restrict__ g, int n) {
  __shared__ float Wl[IN * (OUT + 1)];  // transposed+padded: Wl[j*(OUT+1)+f]
  __shared__ float al[NPB][IN];
  int t = threadIdx.x;
  for (int idx = t; idx < IN * OUT; idx += TPB) {
    int f = idx / IN, j = idx % IN;
    Wl[j * (OUT + 1) + f] = W[idx];
  }
  int base = blockIdx.x * NPB;
  for (int idx = t; idx < NPB * IN; idx += TPB) {
    int nl = idx / IN, j = idx % IN;
    int node = base + nl;
    al[nl][j] = (node < n) ? h[(size_t)node * IN + j] : 0.f;
  }
  __syncthreads();
  int nl = t / OUT, f = t % OUT;
  int node = base + nl;
  if (node >= n) return;
  float s = 0.f;
#pragma unroll
  for (int j = 0; j < IN; ++j) s += al[nl][j] * Wl[j * (OUT + 1) + f];
  g[(size_t)node * OUT + f] = dinv[node] * s;
}

// Gather + epilogue: h[i] = relu(dinv[i]*(g[i] + sum g[src]) + b). Q = F/4 float4 lanes/node.
template <int LOGQ>
__global__ void gather_kernel(const float4* __restrict__ g4, const int* __restrict__ rowptr,
                              const int* __restrict__ esrc, const float* __restrict__ dinv,
                              const float* __restrict__ b, float4* __restrict__ h4, int n) {
  constexpr int Q = 1 << LOGQ;
  int tid = blockIdx.x * blockDim.x + threadIdx.x;
  int i = tid >> LOGQ, q = tid & (Q - 1);
  if (i >= n) return;
  int r0 = rowptr[i], r1 = rowptr[i + 1];
  float4 acc = g4[(size_t)i * Q + q];  // self-loop
  for (int e = r0; e < r1; ++e) {
    int s = esrc[e];
    float4 v = g4[(size_t)s * Q + q];
    acc.x += v.x; acc.y += v.y; acc.z += v.z; acc.w += v.w;
  }
  float di = dinv[i];
  const float4 bv = ((const float4*)b)[q];
  float4 o;
  o.x = fmaxf(di * acc.x + bv.x, 0.f);
  o.y = fmaxf(di * acc.y + bv.y, 0.f);
  o.z = fmaxf(di * acc.z + bv.z, 0.f);
  o.w = fmaxf(di * acc.w + bv.w, 0.f);
  h4[(size_t)i * Q + q] = o;
}

// Block per graph: mean-pool h3 over the graph's node range, then FC. No atomics.
__global__ void poolfc_kernel(const float* __restrict__ h3, const int* __restrict__ gstart,
                              const float* __restrict__ Wfc, const float* __restrict__ bfc,
                              float* __restrict__ out) {
  int gi = blockIdx.x;
  int s = gstart[gi], e = gstart[gi + 1];
  int t = threadIdx.x;
  int nl = t >> 5, f = t & 31;
  float acc = 0.f;
  for (int i = s + nl; i < e; i += 8) acc += h3[(size_t)i * 32 + f];
  __shared__ float red[256];
  red[t] = acc;
  __syncthreads();
  for (int st = 128; st >= 32; st >>= 1) {
    if (t < st) red[t] += red[t + st];
    __syncthreads();
  }
  if (t < 32) {
    float cnt = (float)(e - s);
    float v = (red[t] / fmaxf(cnt, 1.f)) * Wfc[t];
    for (int o = 16; o; o >>= 1) v += __shfl_down(v, o, 32);
    if (t == 0) out[gi] = v + bfc[0];
  }
}

extern "C" void kernel_launch(void* const* d_in, const int* in_sizes, int n_in,
                              void* d_out, int out_size, void* d_ws, size_t ws_size,
                              hipStream_t stream) {
  const float* x     = (const float*)d_in[0];
  const int*   ei    = (const int*)d_in[1];  // int32 on device
  const int*   batch = (const int*)d_in[2];
  const float* W1    = (const float*)d_in[3];
  const float* b1    = (const float*)d_in[4];
  const float* W2    = (const float*)d_in[5];
  const float* b2    = (const float*)d_in[6];
  const float* W3    = (const float*)d_in[7];
  const float* b3    = (const float*)d_in[8];
  const float* Wfc   = (const float*)d_in[9];
  const float* bfc   = (const float*)d_in[10];
  float* out = (float*)d_out;

  const int N = in_sizes[0] / 2;
  const int E = in_sizes[1] / 2;
  const int G = out_size;  // 512
  const int* src = ei;
  const int* dst = ei + E;

  // Bucket geometry: span = 1<<shift node-ids per bucket, B <= 1024 buckets,
  // span <= 256 (p2 LDS arrays). Holds for N <= 262144.
  int shift = 7;
  while ((((N + (1 << shift) - 1) >> shift)) > 1024) ++shift;
  const int B = (N + (1 << shift) - 1) >> shift;
  const int chunkE = (E + NB1 - 1) / NB1;
  const int M = B * NB1;
  const int segM = (M + NB_SCAN - 1) / NB_SCAN;

  char* ws = (char*)d_ws;
  size_t off = 0;
  auto alloc = [&](size_t bytes) -> char* {
    char* p = ws + off;
    off += (bytes + 255) & ~(size_t)255;
    return p;
  };
  float* dinv   = (float*)alloc((size_t)N * 4);
  int*   rowptr = (int*)alloc((size_t)(N + 1) * 4);
  int*   esrc   = (int*)alloc((size_t)E * 4);
  int*   gstart = (int*)alloc((size_t)(G + 1) * 4);
  int*   hist   = (int*)alloc((size_t)M * 4);
  int*   bsum   = (int*)alloc((size_t)NB_SCAN * 4);
  float* g      = (float*)alloc((size_t)N * 64 * 4);  // transform out; epair aliases this
  float* hA     = (float*)alloc((size_t)N * 32 * 4);  // h1, then h3
  float* hB     = (float*)alloc((size_t)N * 64 * 4);  // h2
  int2*  epair  = (int2*)g;  // 12.8 MB <= 25.6 MB; dead before transform1 writes g

  // --- structure build: bucketed counting sort (no global atomics) ---
  p1_hist_kernel<<<NB1, TPB, 0, stream>>>(dst, hist, E, chunkE, shift, B);
  scan_partial_kernel<<<NB_SCAN, TPB, 0, stream>>>(hist, bsum, M, segM);
  scan_blocks_kernel<<<1, NB_SCAN, 0, stream>>>(bsum);
  scan_emit_kernel<<<NB_SCAN, TPB, 0, stream>>>(hist, bsum, M, segM);
  p1_scatter_kernel<<<NB1, TPB, 0, stream>>>(src, dst, hist, epair, E, chunkE, shift, B);
  p2_sort_kernel<<<B, TPB, 0, stream>>>(epair, hist, rowptr, dinv, esrc, N, E, shift, B);
  gptr_kernel<<<(N + TPB - 1) / TPB, TPB, 0, stream>>>(batch, gstart, N, G);

  // --- layer 1: 2 -> 32 ---
  transform1_kernel<<<((size_t)N * 32 + TPB - 1) / TPB, TPB, 0, stream>>>(x, W1, dinv, g, N);
  gather_kernel<3><<<((size_t)N * 8 + TPB - 1) / TPB, TPB, 0, stream>>>(
      (const float4*)g, rowptr, esrc, dinv, b1, (float4*)hA, N);

  // --- layer 2: 32 -> 64 ---
  transform_mid_kernel<32, 64, 4><<<(N + 3) / 4, TPB, 0, stream>>>(hA, W2, dinv, g, N);
  gather_kernel<4><<<((size_t)N * 16 + TPB - 1) / TPB, TPB, 0, stream>>>(
      (const float4*)g, rowptr, esrc, dinv, b2, (float4*)hB, N);

  // --- layer 3: 64 -> 32 ---
  transform_mid_kernel<64, 32, 8><<<(N + 7) / 8, TPB, 0, stream>>>(hB, W3, dinv, g, N);
  gather_kernel<3><<<((size_t)N * 8 + TPB - 1) / TPB, TPB, 0, stream>>>(
      (const float4*)g, rowptr, esrc, dinv, b3, (float4*)hA, N);

  // --- pool + fc ---
  poolfc_kernel<<<G, 256, 0, stream>>>(hA, gstart, Wfc, bfc, out);
}

// Round 7
// 317.626 us; speedup vs baseline: 9.9353x; 1.1300x over previous
//
#include <hip/hip_runtime.h>
#include <hip/hip_fp16.h>

// GCN: 3x GCNConv(relu) + global_mean_pool + FC, fp32 compute.
// R7: fp16 neighbor messages. R6 counters: layer-2 gather FETCH=188MB ~= 8
// XCDs x 25.6MB g array — every XCD's L2 pulls the whole array once (XCD
// replication bound for random gather; per-XCD L2s not shared). Only lever
// left is bytes/element: transforms now write g in fp32 AND fp16; gathers
// read neighbors from fp16 (16B/lane = 8 halfs), self-loop stays fp32.
// Accumulation + epilogue remain fp32. Everything else unchanged from R6.
// NOTE: integer inputs are int32 on device (NOT int64).

static constexpr int TPB = 256;
static constexpr int NB1 = 256;      // phase-1 blocks
static constexpr int NB_SCAN = 256;  // scan blocks
static constexpr int P2CAP = 6144;   // per-bucket LDS staging (ints)

// ---------- phase 1a: per-(bucket,block) histogram ----------
__global__ void p1_hist_kernel(const int* __restrict__ dst, int* __restrict__ hist,
                               int E, int chunk, int shift, int B) {
  __shared__ int h[1024];  // B <= 1024 by construction
  int b = blockIdx.x, t = threadIdx.x;
  for (int i = t; i < B; i += TPB) h[i] = 0;
  __syncthreads();
  int lo = b * chunk, hi = min(lo + chunk, E);
  for (int e = lo + t; e < hi; e += TPB) atomicAdd(&h[dst[e] >> shift], 1);
  __syncthreads();
  for (int i = t; i < B; i += TPB) hist[i * NB1 + b] = h[i];
}

// ---------- generic two-level exclusive scan (in place) ----------
__global__ void scan_partial_kernel(const int* __restrict__ a, int* __restrict__ bsum,
                                    int n, int seg) {
  int b = blockIdx.x, t = threadIdx.x;
  int lo = b * seg, hi = min(lo + seg, n);
  int acc = 0;
  for (int i = lo + t; i < hi; i += TPB) acc += a[i];
  __shared__ int red[TPB];
  red[t] = acc;
  __syncthreads();
  for (int st = TPB / 2; st > 0; st >>= 1) {
    if (t < st) red[t] += red[t + st];
    __syncthreads();
  }
  if (t == 0) bsum[b] = red[0];
}

__global__ void scan_blocks_kernel(int* __restrict__ bsum) {
  __shared__ int cs[NB_SCAN];
  int t = threadIdx.x;
  int v = bsum[t];
  cs[t] = v;
  __syncthreads();
  for (int off = 1; off < NB_SCAN; off <<= 1) {
    int u = (t >= off) ? cs[t - off] : 0;
    __syncthreads();
    cs[t] += u;
    __syncthreads();
  }
  bsum[t] = cs[t] - v;  // exclusive
}

__global__ void scan_emit_kernel(int* __restrict__ a, const int* __restrict__ bsum,
                                 int n, int seg) {
  int b = blockIdx.x, t = threadIdx.x;
  int lo = b * seg, hi = min(lo + seg, n);
  __shared__ int cs[TPB];
  __shared__ int s_run;
  if (t == 0) s_run = bsum[b];
  __syncthreads();
  for (int base = lo; base < hi; base += TPB) {
    int i = base + t;
    int v = (i < hi) ? a[i] : 0;
    cs[t] = v;
    __syncthreads();
    for (int off = 1; off < TPB; off <<= 1) {
      int u = (t >= off) ? cs[t - off] : 0;
      __syncthreads();
      cs[t] += u;
      __syncthreads();
    }
    if (i < hi) a[i] = s_run + cs[t] - v;  // exclusive
    __syncthreads();
    if (t == 0) s_run += cs[TPB - 1];
    __syncthreads();
  }
}

// ---------- phase 1b: scatter edges into bucket-contiguous epair ----------
__global__ void p1_scatter_kernel(const int* __restrict__ src, const int* __restrict__ dst,
                                  const int* __restrict__ hist, int2* __restrict__ epair,
                                  int E, int chunk, int shift, int B) {
  __shared__ int cur[1024];
  int b = blockIdx.x, t = threadIdx.x;
  for (int i = t; i < B; i += TPB) cur[i] = hist[i * NB1 + b];
  __syncthreads();
  int lo = b * chunk, hi = min(lo + chunk, E);
  for (int e = lo + t; e < hi; e += TPB) {
    int d = dst[e];
    int pos = atomicAdd(&cur[d >> shift], 1);
    epair[pos] = make_int2(src[e], d);
  }
}

// ---------- phase 2: per-bucket counting sort + rowptr/dinv emit ----------
__global__ __launch_bounds__(TPB) void p2_sort_kernel(
    const int2* __restrict__ epair, const int* __restrict__ hist,
    int* __restrict__ rowptr, float* __restrict__ dinv, int* __restrict__ esrc,
    int N, int E, int shift, int B) {
  int bkt = blockIdx.x, t = threadIdx.x;
  int span = 1 << shift;  // <= 256
  int nb = bkt << shift;
  int bstart = hist[bkt * NB1];
  int bend = (bkt + 1 < B) ? hist[(bkt + 1) * NB1] : E;
  int bsize = bend - bstart;
  __shared__ int cnt[256];
  __shared__ int ex[256];
  __shared__ int lsrc[P2CAP];
  if (t < span) cnt[t] = 0;
  __syncthreads();
  for (int e = bstart + t; e < bend; e += TPB) atomicAdd(&cnt[epair[e].y - nb], 1);
  __syncthreads();
  int v = (t < span) ? cnt[t] : 0;
  ex[t] = v;
  __syncthreads();
  for (int off = 1; off < 256; off <<= 1) {  // Hillis-Steele inclusive
    int u = (t >= off) ? ex[t - off] : 0;
    __syncthreads();
    ex[t] += u;
    __syncthreads();
  }
  int excl = ex[t] - v;  // exclusive scan value
  int node = nb + t;
  if (t < span && node < N) {
    rowptr[node] = bstart + excl;
    dinv[node] = rsqrtf((float)v + 1.0f);  // +1 self-loop
  }
  if (bkt == 0 && t == 0) rowptr[N] = E;
  __syncthreads();
  bool stage = (bsize <= P2CAP);  // fallback keeps any input correct
  if (t < span) cnt[t] = stage ? excl : bstart + excl;  // reuse cnt as cursor
  __syncthreads();
  for (int e = bstart + t; e < bend; e += TPB) {
    int2 p = epair[e];
    int pos = atomicAdd(&cnt[p.y - nb], 1);
    if (stage) lsrc[pos] = p.x;
    else esrc[pos] = p.x;
  }
  __syncthreads();
  if (stage)
    for (int i = t; i < bsize; i += TPB) esrc[bstart + i] = lsrc[i];  // coalesced
}

// Graph ranges from sorted batch: gstart[g] = first i with batch[i] >= g.
__global__ void gptr_kernel(const int* __restrict__ batch, int* __restrict__ gstart, int n, int G) {
  int i = blockIdx.x * blockDim.x + threadIdx.x;
  if (i >= n) return;
  int b = batch[i];
  int bp = (i == 0) ? -1 : batch[i - 1];
  for (int g = bp + 1; g <= b; ++g) gstart[g] = i;
  if (i == n - 1)
    for (int g = b + 1; g <= G; ++g) gstart[g] = n;
}

// Layer 1 transform: in=2, out=32. One thread per (node, f). Writes g32 + g16.
__global__ void transform1_kernel(const float* __restrict__ x, const float* __restrict__ W1,
                                  const float* __restrict__ dinv, float* __restrict__ g32,
                                  __half* __restrict__ g16, int n) {
  int tid = blockIdx.x * blockDim.x + threadIdx.x;
  int i = tid >> 5, f = tid & 31;
  if (i >= n) return;
  float gv = (x[i * 2 + 0] * W1[f * 2 + 0] + x[i * 2 + 1] * W1[f * 2 + 1]) * dinv[i];
  g32[(size_t)i * 32 + f] = gv;
  g16[(size_t)i * 32 + f] = __float2half(gv);
}

// Mid transform: g = (h @ W^T) * dinv, written fp32 + fp16. Wl stride padded (+1).
template <int IN, int OUT, int NPB>
__global__ void transform_mid_kernel(const float* __restrict__ h, const float* __restrict__ W,
                                     const float* __restrict__ dinv, float* __restrict__ g32,
                                     __half* __restrict__ g16, int n) {
  __shared__ float Wl[IN * (OUT + 1)];  // transposed+padded: Wl[j*(OUT+1)+f]
  __shared__ float al[NPB][IN];
  int t = threadIdx.x;
  for (int idx = t; idx < IN * OUT; idx += TPB) {
    int f = idx / IN, j = idx % IN;
    Wl[j * (OUT + 1) + f] = W[idx];
  }
  int base = blockIdx.x * NPB;
  for (int idx = t; idx < NPB * IN; idx += TPB) {
    int nl = idx / IN, j = idx % IN;
    int node = base + nl;
    al[nl][j] = (node < n) ? h[(size_t)node * IN + j] : 0.f;
  }
  __syncthreads();
  int nl = t / OUT, f = t % OUT;
  int node = base + nl;
  if (node >= n) return;
  float s = 0.f;
#pragma unroll
  for (int j = 0; j < IN; ++j) s += al[nl][j] * Wl[j * (OUT + 1) + f];
  float gv = dinv[node] * s;
  g32[(size_t)node * OUT + f] = gv;
  g16[(size_t)node * OUT + f] = __float2half(gv);
}

// Gather + epilogue. Node row = F floats; Q = F/8 lanes/node, 8 feats/lane.
// Self-loop from fp32 g32; neighbors from fp16 g16 (16 B/lane loads).
template <int LOGQ>  // Q = 1<<LOGQ, F = 8*Q
__global__ void gather_kernel(const float4* __restrict__ g32, const float4* __restrict__ g16p,
                              const int* __restrict__ rowptr, const int* __restrict__ esrc,
                              const float* __restrict__ dinv, const float* __restrict__ b,
                              float4* __restrict__ h4, int n) {
  constexpr int Q = 1 << LOGQ;
  int tid = blockIdx.x * blockDim.x + threadIdx.x;
  int i = tid >> LOGQ, q = tid & (Q - 1);
  if (i >= n) return;
  float acc[8];
  float4 s0 = g32[(size_t)i * 2 * Q + 2 * q];
  float4 s1 = g32[(size_t)i * 2 * Q + 2 * q + 1];
  acc[0] = s0.x; acc[1] = s0.y; acc[2] = s0.z; acc[3] = s0.w;
  acc[4] = s1.x; acc[5] = s1.y; acc[6] = s1.z; acc[7] = s1.w;
  int r0 = rowptr[i], r1 = rowptr[i + 1];
  for (int e = r0; e < r1; ++e) {
    int s = esrc[e];
    union { float4 f4; __half2 h2[4]; } u;
    u.f4 = g16p[(size_t)s * Q + q];
    float2 a0 = __half22float2(u.h2[0]);
    float2 a1 = __half22float2(u.h2[1]);
    float2 a2 = __half22float2(u.h2[2]);
    float2 a3 = __half22float2(u.h2[3]);
    acc[0] += a0.x; acc[1] += a0.y; acc[2] += a1.x; acc[3] += a1.y;
    acc[4] += a2.x; acc[5] += a2.y; acc[6] += a3.x; acc[7] += a3.y;
  }
  float di = dinv[i];
  const float4 bv0 = ((const float4*)b)[2 * q];
  const float4 bv1 = ((const float4*)b)[2 * q + 1];
  float4 o0, o1;
  o0.x = fmaxf(di * acc[0] + bv0.x, 0.f);
  o0.y = fmaxf(di * acc[1] + bv0.y, 0.f);
  o0.z = fmaxf(di * acc[2] + bv0.z, 0.f);
  o0.w = fmaxf(di * acc[3] + bv0.w, 0.f);
  o1.x = fmaxf(di * acc[4] + bv1.x, 0.f);
  o1.y = fmaxf(di * acc[5] + bv1.y, 0.f);
  o1.z = fmaxf(di * acc[6] + bv1.z, 0.f);
  o1.w = fmaxf(di * acc[7] + bv1.w, 0.f);
  h4[(size_t)i * 2 * Q + 2 * q] = o0;
  h4[(size_t)i * 2 * Q + 2 * q + 1] = o1;
}

// Block per graph: mean-pool h3 over the graph's node range, then FC. No atomics.
__global__ void poolfc_kernel(const float* __restrict__ h3, const int* __restrict__ gstart,
                              const float* __restrict__ Wfc, const float* __restrict__ bfc,
                              float* __restrict__ out) {
  int gi = blockIdx.x;
  int s = gstart[gi], e = gstart[gi + 1];
  int t = threadIdx.x;
  int nl = t >> 5, f = t & 31;
  float acc = 0.f;
  for (int i = s + nl; i < e; i += 8) acc += h3[(size_t)i * 32 + f];
  __shared__ float red[256];
  red[t] = acc;
  __syncthreads();
  for (int st = 128; st >= 32; st >>= 1) {
    if (t < st) red[t] += red[t + st];
    __syncthreads();
  }
  if (t < 32) {
    float cnt = (float)(e - s);
    float v = (red[t] / fmaxf(cnt, 1.f)) * Wfc[t];
    for (int o = 16; o; o >>= 1) v += __shfl_down(v, o, 32);
    if (t == 0) out[gi] = v + bfc[0];
  }
}

extern "C" void kernel_launch(void* const* d_in, const int* in_sizes, int n_in,
                              void* d_out, int out_size, void* d_ws, size_t ws_size,
                              hipStream_t stream) {
  const float* x     = (const float*)d_in[0];
  const int*   ei    = (const int*)d_in[1];  // int32 on device
  const int*   batch = (const int*)d_in[2];
  const float* W1    = (const float*)d_in[3];
  const float* b1    = (const float*)d_in[4];
  const float* W2    = (const float*)d_in[5];
  const float* b2    = (const float*)d_in[6];
  const float* W3    = (const float*)d_in[7];
  const float* b3    = (const float*)d_in[8];
  const float* Wfc   = (const float*)d_in[9];
  const float* bfc   = (const float*)d_in[10];
  float* out = (float*)d_out;

  const int N = in_sizes[0] / 2;
  const int E = in_sizes[1] / 2;
  const int G = out_size;  // 512
  const int* src = ei;
  const int* dst = ei + E;

  // Bucket geometry: span = 1<<shift node-ids per bucket, B <= 1024 buckets,
  // span <= 256 (p2 LDS arrays). Holds for N <= 262144.
  int shift = 7;
  while ((((N + (1 << shift) - 1) >> shift)) > 1024) ++shift;
  const int B = (N + (1 << shift) - 1) >> shift;
  const int chunkE = (E + NB1 - 1) / NB1;
  const int M = B * NB1;
  const int segM = (M + NB_SCAN - 1) / NB_SCAN;

  char* ws = (char*)d_ws;
  size_t off = 0;
  auto alloc = [&](size_t bytes) -> char* {
    char* p = ws + off;
    off += (bytes + 255) & ~(size_t)255;
    return p;
  };
  float*  dinv   = (float*)alloc((size_t)N * 4);
  int*    rowptr = (int*)alloc((size_t)(N + 1) * 4);
  int*    esrc   = (int*)alloc((size_t)E * 4);
  int*    gstart = (int*)alloc((size_t)(G + 1) * 4);
  int*    hist   = (int*)alloc((size_t)M * 4);
  int*    bsum   = (int*)alloc((size_t)NB_SCAN * 4);
  float*  g32    = (float*)alloc((size_t)N * 64 * 4);  // fp32 messages; epair aliases
  __half* g16    = (__half*)alloc((size_t)N * 64 * 2); // fp16 messages
  float*  hA     = (float*)alloc((size_t)N * 32 * 4);  // h1, then h3
  float*  hB     = (float*)alloc((size_t)N * 64 * 4);  // h2
  int2*   epair  = (int2*)g32;  // 12.8 MB <= 25.6 MB; dead before transform1

  // --- structure build: bucketed counting sort (no global atomics) ---
  p1_hist_kernel<<<NB1, TPB, 0, stream>>>(dst, hist, E, chunkE, shift, B);
  scan_partial_kernel<<<NB_SCAN, TPB, 0, stream>>>(hist, bsum, M, segM);
  scan_blocks_kernel<<<1, NB_SCAN, 0, stream>>>(bsum);
  scan_emit_kernel<<<NB_SCAN, TPB, 0, stream>>>(hist, bsum, M, segM);
  p1_scatter_kernel<<<NB1, TPB, 0, stream>>>(src, dst, hist, epair, E, chunkE, shift, B);
  p2_sort_kernel<<<B, TPB, 0, stream>>>(epair, hist, rowptr, dinv, esrc, N, E, shift, B);
  gptr_kernel<<<(N + TPB - 1) / TPB, TPB, 0, stream>>>(batch, gstart, N, G);

  // --- layer 1: 2 -> 32 ---
  transform1_kernel<<<((size_t)N * 32 + TPB - 1) / TPB, TPB, 0, stream>>>(x, W1, dinv, g32, g16, N);
  gather_kernel<2><<<((size_t)N * 4 + TPB - 1) / TPB, TPB, 0, stream>>>(
      (const float4*)g32, (const float4*)g16, rowptr, esrc, dinv, b1, (float4*)hA, N);

  // --- layer 2: 32 -> 64 ---
  transform_mid_kernel<32, 64, 4><<<(N + 3) / 4, TPB, 0, stream>>>(hA, W2, dinv, g32, g16, N);
  gather_kernel<3><<<((size_t)N * 8 + TPB - 1) / TPB, TPB, 0, stream>>>(
      (const float4*)g32, (const float4*)g16, rowptr, esrc, dinv, b2, (float4*)hB, N);

  // --- layer 3: 64 -> 32 ---
  transform_mid_kernel<64, 32, 8><<<(N + 7) / 8, TPB, 0, stream>>>(hB, W3, dinv, g32, g16, N);
  gather_kernel<2><<<((size_t)N * 4 + TPB - 1) / TPB, TPB, 0, stream>>>(
      (const float4*)g32, (const float4*)g16, rowptr, esrc, dinv, b3, (float4*)hA, N);

  // --- pool + fc ---
  poolfc_kernel<<<G, 256, 0, stream>>>(hA, gstart, Wfc, bfc, out);
}

// Round 8
// 291.780 us; speedup vs baseline: 10.8153x; 1.0886x over previous
//
#include <hip/hip_runtime.h>
#include <hip/hip_fp16.h>

// GCN: 3x GCNConv(relu) + global_mean_pool + FC, fp32 compute.
// R8: gather in min(IN,OUT) feature space (norm+linear commute):
//   L1: gather u0=dinv*x at dim 2 fp32 (0.8 MB - L2-resident per XCD, exact)
//       then transform -> u1 = dinv*relu(dinv*(W1@U0)+b1)  [fp32+fp16]
//   L2: gather u1 at dim 32 fp16 (6.4 MB vs 12.8 -> halves XCD-replication
//       fetch), then FUSED transform U1 -> h2=relu(dinv*W2@U1+b2) ->
//       g3=dinv*(W3@h2) (kills the 25.6 MB h2 round-trip)
//   L3: gather g3 at dim 32 fp16 + relu epilogue (as R7).
// Also: epair packed into one int (local_dst<<srcbits | src; valid whenever
// span<=256 constraint holds) -> halves p1_scatter writes / p2_sort reads.
// NOTE: integer inputs are int32 on device (NOT int64).

static constexpr int TPB = 256;
static constexpr int NB1 = 256;      // phase-1 blocks
static constexpr int NB_SCAN = 256;  // scan blocks
static constexpr int P2CAP = 6144;   // per-bucket LDS staging (ints)

// ---------- phase 1a: per-(bucket,block) histogram ----------
__global__ void p1_hist_kernel(const int* __restrict__ dst, int* __restrict__ hist,
                               int E, int chunk, int shift, int B) {
  __shared__ int h[1024];  // B <= 1024 by construction
  int b = blockIdx.x, t = threadIdx.x;
  for (int i = t; i < B; i += TPB) h[i] = 0;
  __syncthreads();
  int lo = b * chunk, hi = min(lo + chunk, E);
  for (int e = lo + t; e < hi; e += TPB) atomicAdd(&h[dst[e] >> shift], 1);
  __syncthreads();
  for (int i = t; i < B; i += TPB) hist[i * NB1 + b] = h[i];
}

// ---------- generic two-level exclusive scan (in place) ----------
__global__ void scan_partial_kernel(const int* __restrict__ a, int* __restrict__ bsum,
                                    int n, int seg) {
  int b = blockIdx.x, t = threadIdx.x;
  int lo = b * seg, hi = min(lo + seg, n);
  int acc = 0;
  for (int i = lo + t; i < hi; i += TPB) acc += a[i];
  __shared__ int red[TPB];
  red[t] = acc;
  __syncthreads();
  for (int st = TPB / 2; st > 0; st >>= 1) {
    if (t < st) red[t] += red[t + st];
    __syncthreads();
  }
  if (t == 0) bsum[b] = red[0];
}

__global__ void scan_blocks_kernel(int* __restrict__ bsum) {
  __shared__ int cs[NB_SCAN];
  int t = threadIdx.x;
  int v = bsum[t];
  cs[t] = v;
  __syncthreads();
  for (int off = 1; off < NB_SCAN; off <<= 1) {
    int u = (t >= off) ? cs[t - off] : 0;
    __syncthreads();
    cs[t] += u;
    __syncthreads();
  }
  bsum[t] = cs[t] - v;  // exclusive
}

__global__ void scan_emit_kernel(int* __restrict__ a, const int* __restrict__ bsum,
                                 int n, int seg) {
  int b = blockIdx.x, t = threadIdx.x;
  int lo = b * seg, hi = min(lo + seg, n);
  __shared__ int cs[TPB];
  __shared__ int s_run;
  if (t == 0) s_run = bsum[b];
  __syncthreads();
  for (int base = lo; base < hi; base += TPB) {
    int i = base + t;
    int v = (i < hi) ? a[i] : 0;
    cs[t] = v;
    __syncthreads();
    for (int off = 1; off < TPB; off <<= 1) {
      int u = (t >= off) ? cs[t - off] : 0;
      __syncthreads();
      cs[t] += u;
      __syncthreads();
    }
    if (i < hi) a[i] = s_run + cs[t] - v;  // exclusive
    __syncthreads();
    if (t == 0) s_run += cs[TPB - 1];
    __syncthreads();
  }
}

// ---------- phase 1b: scatter packed edges into bucket-contiguous epk ----------
__global__ void p1_scatter_kernel(const int* __restrict__ src, const int* __restrict__ dst,
                                  const int* __restrict__ hist, unsigned int* __restrict__ epk,
                                  int E, int chunk, int shift, int srcbits, int B) {
  __shared__ int cur[1024];
  int b = blockIdx.x, t = threadIdx.x;
  for (int i = t; i < B; i += TPB) cur[i] = hist[i * NB1 + b];
  __syncthreads();
  int lo = b * chunk, hi = min(lo + chunk, E);
  int span1 = (1 << shift) - 1;
  for (int e = lo + t; e < hi; e += TPB) {
    int d = dst[e];
    int pos = atomicAdd(&cur[d >> shift], 1);
    epk[pos] = ((unsigned int)(d & span1) << srcbits) | (unsigned int)src[e];
  }
}

// ---------- phase 2: per-bucket counting sort + rowptr/dinv emit ----------
__global__ __launch_bounds__(TPB) void p2_sort_kernel(
    const unsigned int* __restrict__ epk, const int* __restrict__ hist,
    int* __restrict__ rowptr, float* __restrict__ dinv, int* __restrict__ esrc,
    int N, int E, int shift, int srcbits, int B) {
  int bkt = blockIdx.x, t = threadIdx.x;
  int span = 1 << shift;  // <= 256
  unsigned int smask = (1u << srcbits) - 1u;
  int nb = bkt << shift;
  int bstart = hist[bkt * NB1];
  int bend = (bkt + 1 < B) ? hist[(bkt + 1) * NB1] : E;
  int bsize = bend - bstart;
  __shared__ int cnt[256];
  __shared__ int ex[256];
  __shared__ int lsrc[P2CAP];
  if (t < span) cnt[t] = 0;
  __syncthreads();
  for (int e = bstart + t; e < bend; e += TPB) atomicAdd(&cnt[epk[e] >> srcbits], 1);
  __syncthreads();
  int v = (t < span) ? cnt[t] : 0;
  ex[t] = v;
  __syncthreads();
  for (int off = 1; off < 256; off <<= 1) {  // Hillis-Steele inclusive
    int u = (t >= off) ? ex[t - off] : 0;
    __syncthreads();
    ex[t] += u;
    __syncthreads();
  }
  int excl = ex[t] - v;  // exclusive scan value
  int node = nb + t;
  if (t < span && node < N) {
    rowptr[node] = bstart + excl;
    dinv[node] = rsqrtf((float)v + 1.0f);  // +1 self-loop
  }
  if (bkt == 0 && t == 0) rowptr[N] = E;
  __syncthreads();
  bool stage = (bsize <= P2CAP);  // fallback keeps any input correct
  if (t < span) cnt[t] = stage ? excl : bstart + excl;  // reuse cnt as cursor
  __syncthreads();
  for (int e = bstart + t; e < bend; e += TPB) {
    unsigned int p = epk[e];
    int pos = atomicAdd(&cnt[p >> srcbits], 1);
    if (stage) lsrc[pos] = (int)(p & smask);
    else esrc[pos] = (int)(p & smask);
  }
  __syncthreads();
  if (stage)
    for (int i = t; i < bsize; i += TPB) esrc[bstart + i] = lsrc[i];  // coalesced
}

// Graph ranges from sorted batch: gstart[g] = first i with batch[i] >= g.
__global__ void gptr_kernel(const int* __restrict__ batch, int* __restrict__ gstart, int n, int G) {
  int i = blockIdx.x * blockDim.x + threadIdx.x;
  if (i >= n) return;
  int b = batch[i];
  int bp = (i == 0) ? -1 : batch[i - 1];
  for (int g = bp + 1; g <= b; ++g) gstart[g] = i;
  if (i == n - 1)
    for (int g = b + 1; g <= G; ++g) gstart[g] = n;
}

// u0 = dinv * x  (dim 2, fp32). One thread per node.
__global__ void u0_kernel(const float2* __restrict__ x2, const float* __restrict__ dinv,
                          float2* __restrict__ u0, int n) {
  int i = blockIdx.x * blockDim.x + threadIdx.x;
  if (i >= n) return;
  float2 v = x2[i];
  float d = dinv[i];
  u0[i] = make_float2(v.x * d, v.y * d);
}

// Layer-1 gather at dim 2, fp32 (exact; u0 is 0.8 MB -> L2-resident per XCD).
__global__ void gather2_kernel(const float2* __restrict__ u0, const int* __restrict__ rowptr,
                               const int* __restrict__ esrc, float2* __restrict__ U0, int n) {
  int i = blockIdx.x * blockDim.x + threadIdx.x;
  if (i >= n) return;
  float2 acc = u0[i];  // self-loop
  int r0 = rowptr[i], r1 = rowptr[i + 1];
  for (int e = r0; e < r1; ++e) {
    float2 v = u0[esrc[e]];
    acc.x += v.x;
    acc.y += v.y;
  }
  U0[i] = acc;
}

// Layer-1 transform: u1 = dinv * relu(dinv*(W1@U0) + b1). One thread per (node,f).
__global__ void transform1b_kernel(const float2* __restrict__ U0, const float* __restrict__ W1,
                                   const float* __restrict__ b1, const float* __restrict__ dinv,
                                   float* __restrict__ u1_32, __half* __restrict__ u1_16, int n) {
  int tid = blockIdx.x * blockDim.x + threadIdx.x;
  int i = tid >> 5, f = tid & 31;
  if (i >= n) return;
  float2 U = U0[i];
  float di = dinv[i];
  float h = fmaxf(di * (W1[f * 2 + 0] * U.x + W1[f * 2 + 1] * U.y) + b1[f], 0.f);
  float uv = di * h;
  u1_32[(size_t)i * 32 + f] = uv;
  u1_16[(size_t)i * 32 + f] = __float2half(uv);
}

// Dim-32 gather: Q=4 lanes/node, 8 feats/lane. Self from fp32, neighbors fp16.
// EPI: apply relu(di*acc+b) (layer 3); else write raw sum (layer 2's U1).
template <bool EPI>
__global__ void gather32_kernel(const float4* __restrict__ a32, const float4* __restrict__ a16,
                                const int* __restrict__ rowptr, const int* __restrict__ esrc,
                                const float* __restrict__ dinv, const float* __restrict__ b,
                                float4* __restrict__ out4, int n) {
  int tid = blockIdx.x * blockDim.x + threadIdx.x;
  int i = tid >> 2, q = tid & 3;
  if (i >= n) return;
  float acc[8];
  float4 s0 = a32[(size_t)i * 8 + 2 * q];
  float4 s1 = a32[(size_t)i * 8 + 2 * q + 1];
  acc[0] = s0.x; acc[1] = s0.y; acc[2] = s0.z; acc[3] = s0.w;
  acc[4] = s1.x; acc[5] = s1.y; acc[6] = s1.z; acc[7] = s1.w;
  int r0 = rowptr[i], r1 = rowptr[i + 1];
  for (int e = r0; e < r1; ++e) {
    int s = esrc[e];
    union { float4 f4; __half2 h2[4]; } u;
    u.f4 = a16[(size_t)s * 4 + q];
    float2 a0 = __half22float2(u.h2[0]);
    float2 a1 = __half22float2(u.h2[1]);
    float2 a2 = __half22float2(u.h2[2]);
    float2 a3 = __half22float2(u.h2[3]);
    acc[0] += a0.x; acc[1] += a0.y; acc[2] += a1.x; acc[3] += a1.y;
    acc[4] += a2.x; acc[5] += a2.y; acc[6] += a3.x; acc[7] += a3.y;
  }
  float4 o0, o1;
  if (EPI) {
    float di = dinv[i];
    const float4 bv0 = ((const float4*)b)[2 * q];
    const float4 bv1 = ((const float4*)b)[2 * q + 1];
    o0.x = fmaxf(di * acc[0] + bv0.x, 0.f);
    o0.y = fmaxf(di * acc[1] + bv0.y, 0.f);
    o0.z = fmaxf(di * acc[2] + bv0.z, 0.f);
    o0.w = fmaxf(di * acc[3] + bv0.w, 0.f);
    o1.x = fmaxf(di * acc[4] + bv1.x, 0.f);
    o1.y = fmaxf(di * acc[5] + bv1.y, 0.f);
    o1.z = fmaxf(di * acc[6] + bv1.z, 0.f);
    o1.w = fmaxf(di * acc[7] + bv1.w, 0.f);
  } else {
    o0 = make_float4(acc[0], acc[1], acc[2], acc[3]);
    o1 = make_float4(acc[4], acc[5], acc[6], acc[7]);
  }
  out4[(size_t)i * 8 + 2 * q] = o0;
  out4[(size_t)i * 8 + 2 * q + 1] = o1;
}

// Fused layer-2+3 transform: U1 -> h2 = relu(dinv*(W2@U1)+b2) -> g3 = dinv*(W3@h2).
// 4 nodes/block, 256 threads. W stages padded to kill bank conflicts.
__global__ __launch_bounds__(TPB) void t2t3_kernel(
    const float* __restrict__ U1, const float* __restrict__ W2, const float* __restrict__ b2,
    const float* __restrict__ W3, const float* __restrict__ dinv,
    float* __restrict__ g3_32, __half* __restrict__ g3_16, int n) {
  __shared__ float W2l[32 * 65];  // [j2][f2], stride 65
  __shared__ float W3l[64 * 33];  // [j3][f3], stride 33
  __shared__ float U1l[4][32];
  __shared__ float h2l[4][64];
  int t = threadIdx.x;
  for (int idx = t; idx < 2048; idx += TPB) {
    int f2 = idx >> 5, j2 = idx & 31;
    W2l[j2 * 65 + f2] = W2[idx];  // W2 is [64][32] row-major
  }
  for (int idx = t; idx < 2048; idx += TPB) {
    int f3 = idx >> 6, j3 = idx & 63;
    W3l[j3 * 33 + f3] = W3[idx];  // W3 is [32][64] row-major
  }
  int base = blockIdx.x * 4;
  if (t < 128) {
    int nl = t >> 5, j = t & 31;
    int node = base + nl;
    U1l[nl][j] = (node < n) ? U1[(size_t)node * 32 + j] : 0.f;
  }
  __syncthreads();
  int nl = t >> 6, k = t & 63;
  int node = base + nl;
  float di = (node < n) ? dinv[node] : 0.f;
  {  // phase 1: h2[nl][k]
    float s = 0.f;
#pragma unroll
    for (int j = 0; j < 32; ++j) s += U1l[nl][j] * W2l[j * 65 + k];
    h2l[nl][k] = fmaxf(di * s + b2[k], 0.f);
  }
  __syncthreads();
  if (k < 32 && node < n) {  // phase 2: g3[nl][k]
    float s = 0.f;
#pragma unroll
    for (int j = 0; j < 64; ++j) s += h2l[nl][j] * W3l[j * 33 + k];
    float gv = di * s;
    g3_32[(size_t)node * 32 + k] = gv;
    g3_16[(size_t)node * 32 + k] = __float2half(gv);
  }
}

// Block per graph: mean-pool h3 over the graph's node range, then FC. No atomics.
__global__ void poolfc_kernel(const float* __restrict__ h3, const int* __restrict__ gstart,
                              const float* __restrict__ Wfc, const float* __restrict__ bfc,
                              float* __restrict__ out) {
  int gi = blockIdx.x;
  int s = gstart[gi], e = gstart[gi + 1];
  int t = threadIdx.x;
  int nl = t >> 5, f = t & 31;
  float acc = 0.f;
  for (int i = s + nl; i < e; i += 8) acc += h3[(size_t)i * 32 + f];
  __shared__ float red[256];
  red[t] = acc;
  __syncthreads();
  for (int st = 128; st >= 32; st >>= 1) {
    if (t < st) red[t] += red[t + st];
    __syncthreads();
  }
  if (t < 32) {
    float cnt = (float)(e - s);
    float v = (red[t] / fmaxf(cnt, 1.f)) * Wfc[t];
    for (int o = 16; o; o >>= 1) v += __shfl_down(v, o, 32);
    if (t == 0) out[gi] = v + bfc[0];
  }
}

extern "C" void kernel_launch(void* const* d_in, const int* in_sizes, int n_in,
                              void* d_out, int out_size, void* d_ws, size_t ws_size,
                              hipStream_t stream) {
  const float* x     = (const float*)d_in[0];
  const int*   ei    = (const int*)d_in[1];  // int32 on device
  const int*   batch = (const int*)d_in[2];
  const float* W1    = (const float*)d_in[3];
  const float* b1    = (const float*)d_in[4];
  const float* W2    = (const float*)d_in[5];
  const float* b2    = (const float*)d_in[6];
  const float* W3    = (const float*)d_in[7];
  const float* b3    = (const float*)d_in[8];
  const float* Wfc   = (const float*)d_in[9];
  const float* bfc   = (const float*)d_in[10];
  float* out = (float*)d_out;

  const int N = in_sizes[0] / 2;
  const int E = in_sizes[1] / 2;
  const int G = out_size;  // 512
  const int* src = ei;
  const int* dst = ei + E;

  // Bucket geometry: span = 1<<shift <= 256, B <= 1024. Holds for N <= 262144;
  // within that, packing (span-local dst << srcbits | src) always fits 32 bits.
  int shift = 7;
  while ((((N + (1 << shift) - 1) >> shift)) > 1024) ++shift;
  const int B = (N + (1 << shift) - 1) >> shift;
  const int srcbits = 32 - shift;
  const int chunkE = (E + NB1 - 1) / NB1;
  const int M = B * NB1;
  const int segM = (M + NB_SCAN - 1) / NB_SCAN;

  char* ws = (char*)d_ws;
  size_t off = 0;
  auto alloc = [&](size_t bytes) -> char* {
    char* p = ws + off;
    off += (bytes + 255) & ~(size_t)255;
    return p;
  };
  float*        dinv   = (float*)alloc((size_t)N * 4);
  int*          rowptr = (int*)alloc((size_t)(N + 1) * 4);
  int*          esrc   = (int*)alloc((size_t)E * 4);
  int*          gstart = (int*)alloc((size_t)(G + 1) * 4);
  int*          hist   = (int*)alloc((size_t)M * 4);
  int*          bsum   = (int*)alloc((size_t)NB_SCAN * 4);
  unsigned int* epk    = (unsigned int*)alloc((size_t)E * 4);
  float2*       u0     = (float2*)alloc((size_t)N * 8);
  float2*       U0     = (float2*)alloc((size_t)N * 8);
  float*        u1_32  = (float*)alloc((size_t)N * 32 * 4);
  __half*       u1_16  = (__half*)alloc((size_t)N * 32 * 2);
  float*        U1     = (float*)alloc((size_t)N * 32 * 4);
  float*        g3_32  = (float*)alloc((size_t)N * 32 * 4);
  __half*       g3_16  = (__half*)alloc((size_t)N * 32 * 2);
  float*        hA     = (float*)alloc((size_t)N * 32 * 4);  // h3

  // --- structure build: bucketed counting sort (no global atomics) ---
  p1_hist_kernel<<<NB1, TPB, 0, stream>>>(dst, hist, E, chunkE, shift, B);
  scan_partial_kernel<<<NB_SCAN, TPB, 0, stream>>>(hist, bsum, M, segM);
  scan_blocks_kernel<<<1, NB_SCAN, 0, stream>>>(bsum);
  scan_emit_kernel<<<NB_SCAN, TPB, 0, stream>>>(hist, bsum, M, segM);
  p1_scatter_kernel<<<NB1, TPB, 0, stream>>>(src, dst, hist, epk, E, chunkE, shift, srcbits, B);
  p2_sort_kernel<<<B, TPB, 0, stream>>>(epk, hist, rowptr, dinv, esrc, N, E, shift, srcbits, B);
  gptr_kernel<<<(N + TPB - 1) / TPB, TPB, 0, stream>>>(batch, gstart, N, G);

  // --- layer 1: gather at dim 2 (fp32, exact), then transform ---
  u0_kernel<<<(N + TPB - 1) / TPB, TPB, 0, stream>>>((const float2*)x, dinv, u0, N);
  gather2_kernel<<<(N + TPB - 1) / TPB, TPB, 0, stream>>>(u0, rowptr, esrc, U0, N);
  transform1b_kernel<<<((size_t)N * 32 + TPB - 1) / TPB, TPB, 0, stream>>>(
      U0, W1, b1, dinv, u1_32, u1_16, N);

  // --- layer 2: gather u1 at dim 32 (fp16 neighbors), fused transform 2+3 ---
  gather32_kernel<false><<<((size_t)N * 4 + TPB - 1) / TPB, TPB, 0, stream>>>(
      (const float4*)u1_32, (const float4*)u1_16, rowptr, esrc, dinv, b2, (float4*)U1, N);
  t2t3_kernel<<<(N + 3) / 4, TPB, 0, stream>>>(U1, W2, b2, W3, dinv, g3_32, g3_16, N);

  // --- layer 3: gather g3 at dim 32 with relu epilogue ---
  gather32_kernel<true><<<((size_t)N * 4 + TPB - 1) / TPB, TPB, 0, stream>>>(
      (const float4*)g3_32, (const float4*)g3_16, rowptr, esrc, dinv, b3, (float4*)hA, N);

  // --- pool + fc ---
  poolfc_kernel<<<G, 256, 0, stream>>>(hA, gstart, Wfc, bfc, out);
}

// Round 9
// 256.388 us; speedup vs baseline: 12.3083x; 1.1380x over previous
//
#include <hip/hip_runtime.h>
#include <hip/hip_fp16.h>

// GCN: 3x GCNConv(relu) + global_mean_pool + FC, fp32 compute.
// R9: register-tiled t2t3. R8's t2t3 (73us, VALUBusy 52%, HBM 5%) staged
// 4096 W elems per 4 nodes and did ~2 LDS reads per FMA. Now: 128 nodes per
// block (W staged once per 128 nodes), LDS operands transposed (U1l[j][n],
// h2l[k][n]) so node- and k-fragments are float4 reads, 8n x 4k register
// tile (32 FMA per 3 ds_read_b128). LDS-traffic model: ~7us floor.
// Everything else unchanged from R8.
// NOTE: integer inputs are int32 on device (NOT int64).

static constexpr int TPB = 256;
static constexpr int NB1 = 256;      // phase-1 blocks
static constexpr int NB_SCAN = 256;  // scan blocks
static constexpr int P2CAP = 6144;   // per-bucket LDS staging (ints)

// ---------- phase 1a: per-(bucket,block) histogram ----------
__global__ void p1_hist_kernel(const int* __restrict__ dst, int* __restrict__ hist,
                               int E, int chunk, int shift, int B) {
  __shared__ int h[1024];  // B <= 1024 by construction
  int b = blockIdx.x, t = threadIdx.x;
  for (int i = t; i < B; i += TPB) h[i] = 0;
  __syncthreads();
  int lo = b * chunk, hi = min(lo + chunk, E);
  for (int e = lo + t; e < hi; e += TPB) atomicAdd(&h[dst[e] >> shift], 1);
  __syncthreads();
  for (int i = t; i < B; i += TPB) hist[i * NB1 + b] = h[i];
}

// ---------- generic two-level exclusive scan (in place) ----------
__global__ void scan_partial_kernel(const int* __restrict__ a, int* __restrict__ bsum,
                                    int n, int seg) {
  int b = blockIdx.x, t = threadIdx.x;
  int lo = b * seg, hi = min(lo + seg, n);
  int acc = 0;
  for (int i = lo + t; i < hi; i += TPB) acc += a[i];
  __shared__ int red[TPB];
  red[t] = acc;
  __syncthreads();
  for (int st = TPB / 2; st > 0; st >>= 1) {
    if (t < st) red[t] += red[t + st];
    __syncthreads();
  }
  if (t == 0) bsum[b] = red[0];
}

__global__ void scan_blocks_kernel(int* __restrict__ bsum) {
  __shared__ int cs[NB_SCAN];
  int t = threadIdx.x;
  int v = bsum[t];
  cs[t] = v;
  __syncthreads();
  for (int off = 1; off < NB_SCAN; off <<= 1) {
    int u = (t >= off) ? cs[t - off] : 0;
    __syncthreads();
    cs[t] += u;
    __syncthreads();
  }
  bsum[t] = cs[t] - v;  // exclusive
}

__global__ void scan_emit_kernel(int* __restrict__ a, const int* __restrict__ bsum,
                                 int n, int seg) {
  int b = blockIdx.x, t = threadIdx.x;
  int lo = b * seg, hi = min(lo + seg, n);
  __shared__ int cs[TPB];
  __shared__ int s_run;
  if (t == 0) s_run = bsum[b];
  __syncthreads();
  for (int base = lo; base < hi; base += TPB) {
    int i = base + t;
    int v = (i < hi) ? a[i] : 0;
    cs[t] = v;
    __syncthreads();
    for (int off = 1; off < TPB; off <<= 1) {
      int u = (t >= off) ? cs[t - off] : 0;
      __syncthreads();
      cs[t] += u;
      __syncthreads();
    }
    if (i < hi) a[i] = s_run + cs[t] - v;  // exclusive
    __syncthreads();
    if (t == 0) s_run += cs[TPB - 1];
    __syncthreads();
  }
}

// ---------- phase 1b: scatter packed edges into bucket-contiguous epk ----------
__global__ void p1_scatter_kernel(const int* __restrict__ src, const int* __restrict__ dst,
                                  const int* __restrict__ hist, unsigned int* __restrict__ epk,
                                  int E, int chunk, int shift, int srcbits, int B) {
  __shared__ int cur[1024];
  int b = blockIdx.x, t = threadIdx.x;
  for (int i = t; i < B; i += TPB) cur[i] = hist[i * NB1 + b];
  __syncthreads();
  int lo = b * chunk, hi = min(lo + chunk, E);
  int span1 = (1 << shift) - 1;
  for (int e = lo + t; e < hi; e += TPB) {
    int d = dst[e];
    int pos = atomicAdd(&cur[d >> shift], 1);
    epk[pos] = ((unsigned int)(d & span1) << srcbits) | (unsigned int)src[e];
  }
}

// ---------- phase 2: per-bucket counting sort + rowptr/dinv emit ----------
__global__ __launch_bounds__(TPB) void p2_sort_kernel(
    const unsigned int* __restrict__ epk, const int* __restrict__ hist,
    int* __restrict__ rowptr, float* __restrict__ dinv, int* __restrict__ esrc,
    int N, int E, int shift, int srcbits, int B) {
  int bkt = blockIdx.x, t = threadIdx.x;
  int span = 1 << shift;  // <= 256
  unsigned int smask = (1u << srcbits) - 1u;
  int nb = bkt << shift;
  int bstart = hist[bkt * NB1];
  int bend = (bkt + 1 < B) ? hist[(bkt + 1) * NB1] : E;
  int bsize = bend - bstart;
  __shared__ int cnt[256];
  __shared__ int ex[256];
  __shared__ int lsrc[P2CAP];
  if (t < span) cnt[t] = 0;
  __syncthreads();
  for (int e = bstart + t; e < bend; e += TPB) atomicAdd(&cnt[epk[e] >> srcbits], 1);
  __syncthreads();
  int v = (t < span) ? cnt[t] : 0;
  ex[t] = v;
  __syncthreads();
  for (int off = 1; off < 256; off <<= 1) {  // Hillis-Steele inclusive
    int u = (t >= off) ? ex[t - off] : 0;
    __syncthreads();
    ex[t] += u;
    __syncthreads();
  }
  int excl = ex[t] - v;  // exclusive scan value
  int node = nb + t;
  if (t < span && node < N) {
    rowptr[node] = bstart + excl;
    dinv[node] = rsqrtf((float)v + 1.0f);  // +1 self-loop
  }
  if (bkt == 0 && t == 0) rowptr[N] = E;
  __syncthreads();
  bool stage = (bsize <= P2CAP);  // fallback keeps any input correct
  if (t < span) cnt[t] = stage ? excl : bstart + excl;  // reuse cnt as cursor
  __syncthreads();
  for (int e = bstart + t; e < bend; e += TPB) {
    unsigned int p = epk[e];
    int pos = atomicAdd(&cnt[p >> srcbits], 1);
    if (stage) lsrc[pos] = (int)(p & smask);
    else esrc[pos] = (int)(p & smask);
  }
  __syncthreads();
  if (stage)
    for (int i = t; i < bsize; i += TPB) esrc[bstart + i] = lsrc[i];  // coalesced
}

// Graph ranges from sorted batch: gstart[g] = first i with batch[i] >= g.
__global__ void gptr_kernel(const int* __restrict__ batch, int* __restrict__ gstart, int n, int G) {
  int i = blockIdx.x * blockDim.x + threadIdx.x;
  if (i >= n) return;
  int b = batch[i];
  int bp = (i == 0) ? -1 : batch[i - 1];
  for (int g = bp + 1; g <= b; ++g) gstart[g] = i;
  if (i == n - 1)
    for (int g = b + 1; g <= G; ++g) gstart[g] = n;
}

// u0 = dinv * x  (dim 2, fp32). One thread per node.
__global__ void u0_kernel(const float2* __restrict__ x2, const float* __restrict__ dinv,
                          float2* __restrict__ u0, int n) {
  int i = blockIdx.x * blockDim.x + threadIdx.x;
  if (i >= n) return;
  float2 v = x2[i];
  float d = dinv[i];
  u0[i] = make_float2(v.x * d, v.y * d);
}

// Layer-1 gather at dim 2, fp32 (exact; u0 is 0.8 MB -> L2-resident per XCD).
__global__ void gather2_kernel(const float2* __restrict__ u0, const int* __restrict__ rowptr,
                               const int* __restrict__ esrc, float2* __restrict__ U0, int n) {
  int i = blockIdx.x * blockDim.x + threadIdx.x;
  if (i >= n) return;
  float2 acc = u0[i];  // self-loop
  int r0 = rowptr[i], r1 = rowptr[i + 1];
  for (int e = r0; e < r1; ++e) {
    float2 v = u0[esrc[e]];
    acc.x += v.x;
    acc.y += v.y;
  }
  U0[i] = acc;
}

// Layer-1 transform: u1 = dinv * relu(dinv*(W1@U0) + b1). One thread per (node,f).
__global__ void transform1b_kernel(const float2* __restrict__ U0, const float* __restrict__ W1,
                                   const float* __restrict__ b1, const float* __restrict__ dinv,
                                   float* __restrict__ u1_32, __half* __restrict__ u1_16, int n) {
  int tid = blockIdx.x * blockDim.x + threadIdx.x;
  int i = tid >> 5, f = tid & 31;
  if (i >= n) return;
  float2 U = U0[i];
  float di = dinv[i];
  float h = fmaxf(di * (W1[f * 2 + 0] * U.x + W1[f * 2 + 1] * U.y) + b1[f], 0.f);
  float uv = di * h;
  u1_32[(size_t)i * 32 + f] = uv;
  u1_16[(size_t)i * 32 + f] = __float2half(uv);
}

// Dim-32 gather: Q=4 lanes/node, 8 feats/lane. Self from fp32, neighbors fp16.
// EPI: apply relu(di*acc+b) (layer 3); else write raw sum (layer 2's U1).
template <bool EPI>
__global__ void gather32_kernel(const float4* __restrict__ a32, const float4* __restrict__ a16,
                                const int* __restrict__ rowptr, const int* __restrict__ esrc,
                                const float* __restrict__ dinv, const float* __restrict__ b,
                                float4* __restrict__ out4, int n) {
  int tid = blockIdx.x * blockDim.x + threadIdx.x;
  int i = tid >> 2, q = tid & 3;
  if (i >= n) return;
  float acc[8];
  float4 s0 = a32[(size_t)i * 8 + 2 * q];
  float4 s1 = a32[(size_t)i * 8 + 2 * q + 1];
  acc[0] = s0.x; acc[1] = s0.y; acc[2] = s0.z; acc[3] = s0.w;
  acc[4] = s1.x; acc[5] = s1.y; acc[6] = s1.z; acc[7] = s1.w;
  int r0 = rowptr[i], r1 = rowptr[i + 1];
  for (int e = r0; e < r1; ++e) {
    int s = esrc[e];
    union { float4 f4; __half2 h2[4]; } u;
    u.f4 = a16[(size_t)s * 4 + q];
    float2 a0 = __half22float2(u.h2[0]);
    float2 a1 = __half22float2(u.h2[1]);
    float2 a2 = __half22float2(u.h2[2]);
    float2 a3 = __half22float2(u.h2[3]);
    acc[0] += a0.x; acc[1] += a0.y; acc[2] += a1.x; acc[3] += a1.y;
    acc[4] += a2.x; acc[5] += a2.y; acc[6] += a3.x; acc[7] += a3.y;
  }
  float4 o0, o1;
  if (EPI) {
    float di = dinv[i];
    const float4 bv0 = ((const float4*)b)[2 * q];
    const float4 bv1 = ((const float4*)b)[2 * q + 1];
    o0.x = fmaxf(di * acc[0] + bv0.x, 0.f);
    o0.y = fmaxf(di * acc[1] + bv0.y, 0.f);
    o0.z = fmaxf(di * acc[2] + bv0.z, 0.f);
    o0.w = fmaxf(di * acc[3] + bv0.w, 0.f);
    o1.x = fmaxf(di * acc[4] + bv1.x, 0.f);
    o1.y = fmaxf(di * acc[5] + bv1.y, 0.f);
    o1.z = fmaxf(di * acc[6] + bv1.z, 0.f);
    o1.w = fmaxf(di * acc[7] + bv1.w, 0.f);
  } else {
    o0 = make_float4(acc[0], acc[1], acc[2], acc[3]);
    o1 = make_float4(acc[4], acc[5], acc[6], acc[7]);
  }
  out4[(size_t)i * 8 + 2 * q] = o0;
  out4[(size_t)i * 8 + 2 * q + 1] = o1;
}

// Fused layer-2+3 transform, register-tiled.
// U1 -> h2 = relu(dinv*(W2@U1)+b2) -> g3 = dinv*(W3@h2).
// 128 nodes/block. LDS transposed: U1l[j][node], h2l[k][node].
// Phase 1: thread = 8n x 4k; phase 2: thread = 8n x 2k.
__global__ __launch_bounds__(TPB) void t2t3_kernel(
    const float* __restrict__ U1, const float* __restrict__ W2, const float* __restrict__ b2,
    const float* __restrict__ W3, const float* __restrict__ dinv,
    float* __restrict__ g3_32, __half* __restrict__ g3_16, int n) {
  constexpr int SN = 136;               // node-dim stride (16B-aligned fragments)
  __shared__ float U1l[32 * SN];        // [j][node]
  __shared__ float h2l[64 * SN];        // [k][node]
  __shared__ float W2l[32 * 68];        // [j][k], stride 68
  __shared__ float W3l[64 * 36];        // [j][k], stride 36
  __shared__ float dil[128];
  int t = threadIdx.x;
  int base = blockIdx.x * 128;
  // stage W2: global [64][32] row-major -> W2l[j*68+k]
  for (int idx = t; idx < 2048; idx += TPB) {
    int k = idx >> 5, j = idx & 31;
    W2l[j * 68 + k] = W2[idx];
  }
  // stage W3: global [32][64] row-major -> W3l[j*36+k]
  for (int idx = t; idx < 2048; idx += TPB) {
    int k = idx >> 6, j = idx & 63;
    W3l[j * 36 + k] = W3[idx];
  }
  if (t < 128) dil[t] = (base + t < n) ? dinv[base + t] : 0.f;
  // stage U1 transposed: U1[node][j] (float4 reads) -> U1l[j*SN + node]
  for (int it = 0; it < 4; ++it) {
    int idx = it * 256 + t;  // float4 index in 128x32 tile
    int nl = idx >> 3, j0 = (idx & 7) * 4;
    int node = base + nl;
    float4 v = (node < n) ? ((const float4*)U1)[(size_t)node * 8 + (idx & 7)]
                          : make_float4(0.f, 0.f, 0.f, 0.f);
    U1l[(j0 + 0) * SN + nl] = v.x;
    U1l[(j0 + 1) * SN + nl] = v.y;
    U1l[(j0 + 2) * SN + nl] = v.z;
    U1l[(j0 + 3) * SN + nl] = v.w;
  }
  __syncthreads();
  // ---- phase 1: h2l[k][n] over 128n x 64k; thread 8n x 4k ----
  {
    int a = t & 15, bb = t >> 4;
    int n0 = a * 8, k0 = bb * 4;
    float acc[4][8];
#pragma unroll
    for (int kk = 0; kk < 4; ++kk)
#pragma unroll
      for (int nn = 0; nn < 8; ++nn) acc[kk][nn] = 0.f;
#pragma unroll 8
    for (int j = 0; j < 32; ++j) {
      float4 ua = *(const float4*)&U1l[j * SN + n0];
      float4 ub = *(const float4*)&U1l[j * SN + n0 + 4];
      float4 w = *(const float4*)&W2l[j * 68 + k0];
      float un[8] = {ua.x, ua.y, ua.z, ua.w, ub.x, ub.y, ub.z, ub.w};
      float wk[4] = {w.x, w.y, w.z, w.w};
#pragma unroll
      for (int kk = 0; kk < 4; ++kk)
#pragma unroll
        for (int nn = 0; nn < 8; ++nn) acc[kk][nn] += un[nn] * wk[kk];
    }
    float4 bv = ((const float4*)b2)[bb];
    float bk[4] = {bv.x, bv.y, bv.z, bv.w};
#pragma unroll
    for (int kk = 0; kk < 4; ++kk) {
      float o[8];
#pragma unroll
      for (int nn = 0; nn < 8; ++nn)
        o[nn] = fmaxf(dil[n0 + nn] * acc[kk][nn] + bk[kk], 0.f);
      *(float4*)&h2l[(k0 + kk) * SN + n0] = make_float4(o[0], o[1], o[2], o[3]);
      *(float4*)&h2l[(k0 + kk) * SN + n0 + 4] = make_float4(o[4], o[5], o[6], o[7]);
    }
  }
  __syncthreads();
  // ---- phase 2: g3[n][k] over 128n x 32k; thread 8n x 2k ----
  {
    int a = t & 15, bb = t >> 4;
    int n0 = a * 8, k0 = bb * 2;
    float acc[2][8];
#pragma unroll
    for (int kk = 0; kk < 2; ++kk)
#pragma unroll
      for (int nn = 0; nn < 8; ++nn) acc[kk][nn] = 0.f;
#pragma unroll 8
    for (int j = 0; j < 64; ++j) {
      float4 ua = *(const float4*)&h2l[j * SN + n0];
      float4 ub = *(const float4*)&h2l[j * SN + n0 + 4];
      float w0 = W3l[j * 36 + k0];
      float w1 = W3l[j * 36 + k0 + 1];
      float un[8] = {ua.x, ua.y, ua.z, ua.w, ub.x, ub.y, ub.z, ub.w};
#pragma unroll
      for (int nn = 0; nn < 8; ++nn) {
        acc[0][nn] += un[nn] * w0;
        acc[1][nn] += un[nn] * w1;
      }
    }
#pragma unroll
    for (int nn = 0; nn < 8; ++nn) {
      int node = base + n0 + nn;
      if (node < n) {
        float di = dil[n0 + nn];
#pragma unroll
        for (int kk = 0; kk < 2; ++kk) {
          float gv = di * acc[kk][nn];
          g3_32[(size_t)node * 32 + k0 + kk] = gv;
          g3_16[(size_t)node * 32 + k0 + kk] = __float2half(gv);
        }
      }
    }
  }
}

// Block per graph: mean-pool h3 over the graph's node range, then FC. No atomics.
__global__ void poolfc_kernel(const float* __restrict__ h3, const int* __restrict__ gstart,
                              const float* __restrict__ Wfc, const float* __restrict__ bfc,
                              float* __restrict__ out) {
  int gi = blockIdx.x;
  int s = gstart[gi], e = gstart[gi + 1];
  int t = threadIdx.x;
  int nl = t >> 5, f = t & 31;
  float acc = 0.f;
  for (int i = s + nl; i < e; i += 8) acc += h3[(size_t)i * 32 + f];
  __shared__ float red[256];
  red[t] = acc;
  __syncthreads();
  for (int st = 128; st >= 32; st >>= 1) {
    if (t < st) red[t] += red[t + st];
    __syncthreads();
  }
  if (t < 32) {
    float cnt = (float)(e - s);
    float v = (red[t] / fmaxf(cnt, 1.f)) * Wfc[t];
    for (int o = 16; o; o >>= 1) v += __shfl_down(v, o, 32);
    if (t == 0) out[gi] = v + bfc[0];
  }
}

extern "C" void kernel_launch(void* const* d_in, const int* in_sizes, int n_in,
                              void* d_out, int out_size, void* d_ws, size_t ws_size,
                              hipStream_t stream) {
  const float* x     = (const float*)d_in[0];
  const int*   ei    = (const int*)d_in[1];  // int32 on device
  const int*   batch = (const int*)d_in[2];
  const float* W1    = (const float*)d_in[3];
  const float* b1    = (const float*)d_in[4];
  const float* W2    = (const float*)d_in[5];
  const float* b2    = (const float*)d_in[6];
  const float* W3    = (const float*)d_in[7];
  const float* b3    = (const float*)d_in[8];
  const float* Wfc   = (const float*)d_in[9];
  const float* bfc   = (const float*)d_in[10];
  float* out = (float*)d_out;

  const int N = in_sizes[0] / 2;
  const int E = in_sizes[1] / 2;
  const int G = out_size;  // 512
  const int* src = ei;
  const int* dst = ei + E;

  // Bucket geometry: span = 1<<shift <= 256, B <= 1024. Holds for N <= 262144;
  // within that, packing (span-local dst << srcbits | src) always fits 32 bits.
  int shift = 7;
  while ((((N + (1 << shift) - 1) >> shift)) > 1024) ++shift;
  const int B = (N + (1 << shift) - 1) >> shift;
  const int srcbits = 32 - shift;
  const int chunkE = (E + NB1 - 1) / NB1;
  const int M = B * NB1;
  const int segM = (M + NB_SCAN - 1) / NB_SCAN;

  char* ws = (char*)d_ws;
  size_t off = 0;
  auto alloc = [&](size_t bytes) -> char* {
    char* p = ws + off;
    off += (bytes + 255) & ~(size_t)255;
    return p;
  };
  float*        dinv   = (float*)alloc((size_t)N * 4);
  int*          rowptr = (int*)alloc((size_t)(N + 1) * 4);
  int*          esrc   = (int*)alloc((size_t)E * 4);
  int*          gstart = (int*)alloc((size_t)(G + 1) * 4);
  int*          hist   = (int*)alloc((size_t)M * 4);
  int*          bsum   = (int*)alloc((size_t)NB_SCAN * 4);
  unsigned int* epk    = (unsigned int*)alloc((size_t)E * 4);
  float2*       u0     = (float2*)alloc((size_t)N * 8);
  float2*       U0     = (float2*)alloc((size_t)N * 8);
  float*        u1_32  = (float*)alloc((size_t)N * 32 * 4);
  __half*       u1_16  = (__half*)alloc((size_t)N * 32 * 2);
  float*        U1     = (float*)alloc((size_t)N * 32 * 4);
  float*        g3_32  = (float*)alloc((size_t)N * 32 * 4);
  __half*       g3_16  = (__half*)alloc((size_t)N * 32 * 2);
  float*        hA     = (float*)alloc((size_t)N * 32 * 4);  // h3

  // --- structure build: bucketed counting sort (no global atomics) ---
  p1_hist_kernel<<<NB1, TPB, 0, stream>>>(dst, hist, E, chunkE, shift, B);
  scan_partial_kernel<<<NB_SCAN, TPB, 0, stream>>>(hist, bsum, M, segM);
  scan_blocks_kernel<<<1, NB_SCAN, 0, stream>>>(bsum);
  scan_emit_kernel<<<NB_SCAN, TPB, 0, stream>>>(hist, bsum, M, segM);
  p1_scatter_kernel<<<NB1, TPB, 0, stream>>>(src, dst, hist, epk, E, chunkE, shift, srcbits, B);
  p2_sort_kernel<<<B, TPB, 0, stream>>>(epk, hist, rowptr, dinv, esrc, N, E, shift, srcbits, B);
  gptr_kernel<<<(N + TPB - 1) / TPB, TPB, 0, stream>>>(batch, gstart, N, G);

  // --- layer 1: gather at dim 2 (fp32, exact), then transform ---
  u0_kernel<<<(N + TPB - 1) / TPB, TPB, 0, stream>>>((const float2*)x, dinv, u0, N);
  gather2_kernel<<<(N + TPB - 1) / TPB, TPB, 0, stream>>>(u0, rowptr, esrc, U0, N);
  transform1b_kernel<<<((size_t)N * 32 + TPB - 1) / TPB, TPB, 0, stream>>>(
      U0, W1, b1, dinv, u1_32, u1_16, N);

  // --- layer 2: gather u1 at dim 32 (fp16 neighbors), fused transform 2+3 ---
  gather32_kernel<false><<<((size_t)N * 4 + TPB - 1) / TPB, TPB, 0, stream>>>(
      (const float4*)u1_32, (const float4*)u1_16, rowptr, esrc, dinv, b2, (float4*)U1, N);
  t2t3_kernel<<<(N + 127) / 128, TPB, 0, stream>>>(U1, W2, b2, W3, dinv, g3_32, g3_16, N);

  // --- layer 3: gather g3 at dim 32 with relu epilogue ---
  gather32_kernel<true><<<((size_t)N * 4 + TPB - 1) / TPB, TPB, 0, stream>>>(
      (const float4*)g3_32, (const float4*)g3_16, rowptr, esrc, dinv, b3, (float4*)hA, N);

  // --- pool + fc ---
  poolfc_kernel<<<G, 256, 0, stream>>>(hA, gstart, Wfc, bfc, out);
}

// Round 10
// 248.129 us; speedup vs baseline: 12.7180x; 1.0333x over previous
//
#include <hip/hip_runtime.h>
#include <hip/hip_fp16.h>

// GCN: 3x GCNConv(relu) + global_mean_pool + FC, fp32 compute.
// R10: memory-level parallelism for the latency-bound gathers + kernel fusion.
//  - gather32: 16 lanes/node = 4 edge-splits x 4 feature-lanes; splits walk
//    interleaved edges (4x outstanding loads, less degree-divergence waste),
//    combined via __shfl_xor(4|8). Bytes unchanged (already at XCD-replication
//    bound); this attacks latency, which R9 showed (51 MB at only 2 TB/s).
//  - layer-1 fused: gather at dim-2 with 4-way edge split + W1 transform in
//    one kernel (U0 round-trip + 2 launches gone).
//  - u0 = dinv*x computed inside p2_sort (already per-node there).
// Top-5 fill dispatches = harness d_ws re-poison (268 MB @6.2TB/s = 44 us),
// fixed overhead outside our control.
// NOTE: integer inputs are int32 on device (NOT int64).

static constexpr int TPB = 256;
static constexpr int NB1 = 256;      // phase-1 blocks
static constexpr int NB_SCAN = 256;  // scan blocks
static constexpr int P2CAP = 6144;   // per-bucket LDS staging (ints)

// ---------- phase 1a: per-(bucket,block) histogram ----------
__global__ void p1_hist_kernel(const int* __restrict__ dst, int* __restrict__ hist,
                               int E, int chunk, int shift, int B) {
  __shared__ int h[1024];  // B <= 1024 by construction
  int b = blockIdx.x, t = threadIdx.x;
  for (int i = t; i < B; i += TPB) h[i] = 0;
  __syncthreads();
  int lo = b * chunk, hi = min(lo + chunk, E);
  for (int e = lo + t; e < hi; e += TPB) atomicAdd(&h[dst[e] >> shift], 1);
  __syncthreads();
  for (int i = t; i < B; i += TPB) hist[i * NB1 + b] = h[i];
}

// ---------- generic two-level exclusive scan (in place) ----------
__global__ void scan_partial_kernel(const int* __restrict__ a, int* __restrict__ bsum,
                                    int n, int seg) {
  int b = blockIdx.x, t = threadIdx.x;
  int lo = b * seg, hi = min(lo + seg, n);
  int acc = 0;
  for (int i = lo + t; i < hi; i += TPB) acc += a[i];
  __shared__ int red[TPB];
  red[t] = acc;
  __syncthreads();
  for (int st = TPB / 2; st > 0; st >>= 1) {
    if (t < st) red[t] += red[t + st];
    __syncthreads();
  }
  if (t == 0) bsum[b] = red[0];
}

__global__ void scan_blocks_kernel(int* __restrict__ bsum) {
  __shared__ int cs[NB_SCAN];
  int t = threadIdx.x;
  int v = bsum[t];
  cs[t] = v;
  __syncthreads();
  for (int off = 1; off < NB_SCAN; off <<= 1) {
    int u = (t >= off) ? cs[t - off] : 0;
    __syncthreads();
    cs[t] += u;
    __syncthreads();
  }
  bsum[t] = cs[t] - v;  // exclusive
}

__global__ void scan_emit_kernel(int* __restrict__ a, const int* __restrict__ bsum,
                                 int n, int seg) {
  int b = blockIdx.x, t = threadIdx.x;
  int lo = b * seg, hi = min(lo + seg, n);
  __shared__ int cs[TPB];
  __shared__ int s_run;
  if (t == 0) s_run = bsum[b];
  __syncthreads();
  for (int base = lo; base < hi; base += TPB) {
    int i = base + t;
    int v = (i < hi) ? a[i] : 0;
    cs[t] = v;
    __syncthreads();
    for (int off = 1; off < TPB; off <<= 1) {
      int u = (t >= off) ? cs[t - off] : 0;
      __syncthreads();
      cs[t] += u;
      __syncthreads();
    }
    if (i < hi) a[i] = s_run + cs[t] - v;  // exclusive
    __syncthreads();
    if (t == 0) s_run += cs[TPB - 1];
    __syncthreads();
  }
}

// ---------- phase 1b: scatter packed edges into bucket-contiguous epk ----------
__global__ void p1_scatter_kernel(const int* __restrict__ src, const int* __restrict__ dst,
                                  const int* __restrict__ hist, unsigned int* __restrict__ epk,
                                  int E, int chunk, int shift, int srcbits, int B) {
  __shared__ int cur[1024];
  int b = blockIdx.x, t = threadIdx.x;
  for (int i = t; i < B; i += TPB) cur[i] = hist[i * NB1 + b];
  __syncthreads();
  int lo = b * chunk, hi = min(lo + chunk, E);
  int span1 = (1 << shift) - 1;
  for (int e = lo + t; e < hi; e += TPB) {
    int d = dst[e];
    int pos = atomicAdd(&cur[d >> shift], 1);
    epk[pos] = ((unsigned int)(d & span1) << srcbits) | (unsigned int)src[e];
  }
}

// ---------- phase 2: per-bucket counting sort + rowptr/dinv/u0 emit ----------
__global__ __launch_bounds__(TPB) void p2_sort_kernel(
    const unsigned int* __restrict__ epk, const int* __restrict__ hist,
    const float2* __restrict__ x2,
    int* __restrict__ rowptr, float* __restrict__ dinv, float2* __restrict__ u0,
    int* __restrict__ esrc, int N, int E, int shift, int srcbits, int B) {
  int bkt = blockIdx.x, t = threadIdx.x;
  int span = 1 << shift;  // <= 256
  unsigned int smask = (1u << srcbits) - 1u;
  int nb = bkt << shift;
  int bstart = hist[bkt * NB1];
  int bend = (bkt + 1 < B) ? hist[(bkt + 1) * NB1] : E;
  int bsize = bend - bstart;
  __shared__ int cnt[256];
  __shared__ int ex[256];
  __shared__ int lsrc[P2CAP];
  if (t < span) cnt[t] = 0;
  __syncthreads();
  for (int e = bstart + t; e < bend; e += TPB) atomicAdd(&cnt[epk[e] >> srcbits], 1);
  __syncthreads();
  int v = (t < span) ? cnt[t] : 0;
  ex[t] = v;
  __syncthreads();
  for (int off = 1; off < 256; off <<= 1) {  // Hillis-Steele inclusive
    int u = (t >= off) ? ex[t - off] : 0;
    __syncthreads();
    ex[t] += u;
    __syncthreads();
  }
  int excl = ex[t] - v;  // exclusive scan value
  int node = nb + t;
  if (t < span && node < N) {
    rowptr[node] = bstart + excl;
    float dv = rsqrtf((float)v + 1.0f);  // +1 self-loop
    dinv[node] = dv;
    float2 xv = x2[node];
    u0[node] = make_float2(xv.x * dv, xv.y * dv);
  }
  if (bkt == 0 && t == 0) rowptr[N] = E;
  __syncthreads();
  bool stage = (bsize <= P2CAP);  // fallback keeps any input correct
  if (t < span) cnt[t] = stage ? excl : bstart + excl;  // reuse cnt as cursor
  __syncthreads();
  for (int e = bstart + t; e < bend; e += TPB) {
    unsigned int p = epk[e];
    int pos = atomicAdd(&cnt[p >> srcbits], 1);
    if (stage) lsrc[pos] = (int)(p & smask);
    else esrc[pos] = (int)(p & smask);
  }
  __syncthreads();
  if (stage)
    for (int i = t; i < bsize; i += TPB) esrc[bstart + i] = lsrc[i];  // coalesced
}

// Graph ranges from sorted batch: gstart[g] = first i with batch[i] >= g.
__global__ void gptr_kernel(const int* __restrict__ batch, int* __restrict__ gstart, int n, int G) {
  int i = blockIdx.x * blockDim.x + threadIdx.x;
  if (i >= n) return;
  int b = batch[i];
  int bp = (i == 0) ? -1 : batch[i - 1];
  for (int g = bp + 1; g <= b; ++g) gstart[g] = i;
  if (i == n - 1)
    for (int g = b + 1; g <= G; ++g) gstart[g] = n;
}

// Fused layer 1: gather u0 (dim 2, fp32, exact) with 4-way edge split,
// shuffle-combine, then each split computes 8 of 32 output features:
// u1 = dinv * relu(dinv*(W1@U0) + b1), written fp32 + fp16.
__global__ void layer1_kernel(const float2* __restrict__ u0, const int* __restrict__ rowptr,
                              const int* __restrict__ esrc, const float* __restrict__ W1,
                              const float* __restrict__ b1, const float* __restrict__ dinv,
                              float* __restrict__ u1_32, __half* __restrict__ u1_16, int n) {
  int tid = blockIdx.x * blockDim.x + threadIdx.x;
  int i = tid >> 2, split = tid & 3;
  if (i >= n) return;
  float ax = 0.f, ay = 0.f;
  if (split == 0) {  // self-loop
    float2 s = u0[i];
    ax = s.x; ay = s.y;
  }
  int r0 = rowptr[i], r1 = rowptr[i + 1];
  for (int e = r0 + split; e < r1; e += 4) {
    float2 v = u0[esrc[e]];
    ax += v.x; ay += v.y;
  }
  ax += __shfl_xor(ax, 1, 64); ay += __shfl_xor(ay, 1, 64);
  ax += __shfl_xor(ax, 2, 64); ay += __shfl_xor(ay, 2, 64);
  float di = dinv[i];
  int f0 = split * 8;
  float o[8];
  union { float4 f4[1]; __half h[8]; } oh;
#pragma unroll
  for (int k = 0; k < 8; ++k) {
    int f = f0 + k;
    float hv = fmaxf(di * (W1[f * 2 + 0] * ax + W1[f * 2 + 1] * ay) + b1[f], 0.f);
    float uv = di * hv;
    o[k] = uv;
    oh.h[k] = __float2half(uv);
  }
  *(float4*)&u1_32[(size_t)i * 32 + f0] = make_float4(o[0], o[1], o[2], o[3]);
  *(float4*)&u1_32[(size_t)i * 32 + f0 + 4] = make_float4(o[4], o[5], o[6], o[7]);
  *(float4*)&u1_16[(size_t)i * 32 + f0] = oh.f4[0];  // byte off (i*32+f0)*2, 16B-aligned
}

// Dim-32 gather, 16 lanes/node: split = edge stripe (4), q = feature quad (4).
// Self from fp32, neighbors fp16; splits combined via shfl_xor(4|8).
// EPI: relu(di*acc+b) epilogue (layer 3); else raw sum (layer 2's U1).
template <bool EPI>
__global__ void gather32_kernel(const float4* __restrict__ a32, const float4* __restrict__ a16,
                                const int* __restrict__ rowptr, const int* __restrict__ esrc,
                                const float* __restrict__ dinv, const float* __restrict__ b,
                                float4* __restrict__ out4, int n) {
  int tid = blockIdx.x * blockDim.x + threadIdx.x;
  int i = tid >> 4;
  int sub = tid & 15;
  int split = sub >> 2, q = sub & 3;
  if (i >= n) return;
  float acc[8] = {0.f, 0.f, 0.f, 0.f, 0.f, 0.f, 0.f, 0.f};
  if (split == 0) {  // self-loop (fp32)
    float4 s0 = a32[(size_t)i * 8 + 2 * q];
    float4 s1 = a32[(size_t)i * 8 + 2 * q + 1];
    acc[0] = s0.x; acc[1] = s0.y; acc[2] = s0.z; acc[3] = s0.w;
    acc[4] = s1.x; acc[5] = s1.y; acc[6] = s1.z; acc[7] = s1.w;
  }
  int r0 = rowptr[i], r1 = rowptr[i + 1];
  for (int e = r0 + split; e < r1; e += 4) {
    int s = esrc[e];
    union { float4 f4; __half2 h2[4]; } u;
    u.f4 = a16[(size_t)s * 4 + q];
    float2 a0 = __half22float2(u.h2[0]);
    float2 a1 = __half22float2(u.h2[1]);
    float2 a2 = __half22float2(u.h2[2]);
    float2 a3 = __half22float2(u.h2[3]);
    acc[0] += a0.x; acc[1] += a0.y; acc[2] += a1.x; acc[3] += a1.y;
    acc[4] += a2.x; acc[5] += a2.y; acc[6] += a3.x; acc[7] += a3.y;
  }
#pragma unroll
  for (int k = 0; k < 8; ++k) acc[k] += __shfl_xor(acc[k], 4, 64);
#pragma unroll
  for (int k = 0; k < 8; ++k) acc[k] += __shfl_xor(acc[k], 8, 64);
  if (split != 0) return;
  float4 o0, o1;
  if (EPI) {
    float di = dinv[i];
    const float4 bv0 = ((const float4*)b)[2 * q];
    const float4 bv1 = ((const float4*)b)[2 * q + 1];
    o0.x = fmaxf(di * acc[0] + bv0.x, 0.f);
    o0.y = fmaxf(di * acc[1] + bv0.y, 0.f);
    o0.z = fmaxf(di * acc[2] + bv0.z, 0.f);
    o0.w = fmaxf(di * acc[3] + bv0.w, 0.f);
    o1.x = fmaxf(di * acc[4] + bv1.x, 0.f);
    o1.y = fmaxf(di * acc[5] + bv1.y, 0.f);
    o1.z = fmaxf(di * acc[6] + bv1.z, 0.f);
    o1.w = fmaxf(di * acc[7] + bv1.w, 0.f);
  } else {
    o0 = make_float4(acc[0], acc[1], acc[2], acc[3]);
    o1 = make_float4(acc[4], acc[5], acc[6], acc[7]);
  }
  out4[(size_t)i * 8 + 2 * q] = o0;
  out4[(size_t)i * 8 + 2 * q + 1] = o1;
}

// Fused layer-2+3 transform, register-tiled (unchanged from R9).
__global__ __launch_bounds__(TPB) void t2t3_kernel(
    const float* __restrict__ U1, const float* __restrict__ W2, const float* __restrict__ b2,
    const float* __restrict__ W3, const float* __restrict__ dinv,
    float* __restrict__ g3_32, __half* __restrict__ g3_16, int n) {
  constexpr int SN = 136;               // node-dim stride (16B-aligned fragments)
  __shared__ float U1l[32 * SN];        // [j][node]
  __shared__ float h2l[64 * SN];        // [k][node]
  __shared__ float W2l[32 * 68];        // [j][k], stride 68
  __shared__ float W3l[64 * 36];        // [j][k], stride 36
  __shared__ float dil[128];
  int t = threadIdx.x;
  int base = blockIdx.x * 128;
  for (int idx = t; idx < 2048; idx += TPB) {
    int k = idx >> 5, j = idx & 31;
    W2l[j * 68 + k] = W2[idx];
  }
  for (int idx = t; idx < 2048; idx += TPB) {
    int k = idx >> 6, j = idx & 63;
    W3l[j * 36 + k] = W3[idx];
  }
  if (t < 128) dil[t] = (base + t < n) ? dinv[base + t] : 0.f;
  for (int it = 0; it < 4; ++it) {
    int idx = it * 256 + t;  // float4 index in 128x32 tile
    int nl = idx >> 3, j0 = (idx & 7) * 4;
    int node = base + nl;
    float4 v = (node < n) ? ((const float4*)U1)[(size_t)node * 8 + (idx & 7)]
                          : make_float4(0.f, 0.f, 0.f, 0.f);
    U1l[(j0 + 0) * SN + nl] = v.x;
    U1l[(j0 + 1) * SN + nl] = v.y;
    U1l[(j0 + 2) * SN + nl] = v.z;
    U1l[(j0 + 3) * SN + nl] = v.w;
  }
  __syncthreads();
  {  // phase 1: h2l[k][n] over 128n x 64k; thread 8n x 4k
    int a = t & 15, bb = t >> 4;
    int n0 = a * 8, k0 = bb * 4;
    float acc[4][8];
#pragma unroll
    for (int kk = 0; kk < 4; ++kk)
#pragma unroll
      for (int nn = 0; nn < 8; ++nn) acc[kk][nn] = 0.f;
#pragma unroll 8
    for (int j = 0; j < 32; ++j) {
      float4 ua = *(const float4*)&U1l[j * SN + n0];
      float4 ub = *(const float4*)&U1l[j * SN + n0 + 4];
      float4 w = *(const float4*)&W2l[j * 68 + k0];
      float un[8] = {ua.x, ua.y, ua.z, ua.w, ub.x, ub.y, ub.z, ub.w};
      float wk[4] = {w.x, w.y, w.z, w.w};
#pragma unroll
      for (int kk = 0; kk < 4; ++kk)
#pragma unroll
        for (int nn = 0; nn < 8; ++nn) acc[kk][nn] += un[nn] * wk[kk];
    }
    float4 bv = ((const float4*)b2)[bb];
    float bk[4] = {bv.x, bv.y, bv.z, bv.w};
#pragma unroll
    for (int kk = 0; kk < 4; ++kk) {
      float o[8];
#pragma unroll
      for (int nn = 0; nn < 8; ++nn)
        o[nn] = fmaxf(dil[n0 + nn] * acc[kk][nn] + bk[kk], 0.f);
      *(float4*)&h2l[(k0 + kk) * SN + n0] = make_float4(o[0], o[1], o[2], o[3]);
      *(float4*)&h2l[(k0 + kk) * SN + n0 + 4] = make_float4(o[4], o[5], o[6], o[7]);
    }
  }
  __syncthreads();
  {  // phase 2: g3[n][k] over 128n x 32k; thread 8n x 2k
    int a = t & 15, bb = t >> 4;
    int n0 = a * 8, k0 = bb * 2;
    float acc[2][8];
#pragma unroll
    for (int kk = 0; kk < 2; ++kk)
#pragma unroll
      for (int nn = 0; nn < 8; ++nn) acc[kk][nn] = 0.f;
#pragma unroll 8
    for (int j = 0; j < 64; ++j) {
      float4 ua = *(const float4*)&h2l[j * SN + n0];
      float4 ub = *(const float4*)&h2l[j * SN + n0 + 4];
      float w0 = W3l[j * 36 + k0];
      float w1 = W3l[j * 36 + k0 + 1];
      float un[8] = {ua.x, ua.y, ua.z, ua.w, ub.x, ub.y, ub.z, ub.w};
#pragma unroll
      for (int nn = 0; nn < 8; ++nn) {
        acc[0][nn] += un[nn] * w0;
        acc[1][nn] += un[nn] * w1;
      }
    }
#pragma unroll
    for (int nn = 0; nn < 8; ++nn) {
      int node = base + n0 + nn;
      if (node < n) {
        float di = dil[n0 + nn];
#pragma unroll
        for (int kk = 0; kk < 2; ++kk) {
          float gv = di * acc[kk][nn];
          g3_32[(size_t)node * 32 + k0 + kk] = gv;
          g3_16[(size_t)node * 32 + k0 + kk] = __float2half(gv);
        }
      }
    }
  }
}

// Block per graph: mean-pool h3 over the graph's node range, then FC. No atomics.
__global__ void poolfc_kernel(const float* __restrict__ h3, const int* __restrict__ gstart,
                              const float* __restrict__ Wfc, const float* __restrict__ bfc,
                              float* __restrict__ out) {
  int gi = blockIdx.x;
  int s = gstart[gi], e = gstart[gi + 1];
  int t = threadIdx.x;
  int nl = t >> 5, f = t & 31;
  float acc = 0.f;
  for (int i = s + nl; i < e; i += 8) acc += h3[(size_t)i * 32 + f];
  __shared__ float red[256];
  red[t] = acc;
  __syncthreads();
  for (int st = 128; st >= 32; st >>= 1) {
    if (t < st) red[t] += red[t + st];
    __syncthreads();
  }
  if (t < 32) {
    float cnt = (float)(e - s);
    float v = (red[t] / fmaxf(cnt, 1.f)) * Wfc[t];
    for (int o = 16; o; o >>= 1) v += __shfl_down(v, o, 32);
    if (t == 0) out[gi] = v + bfc[0];
  }
}

extern "C" void kernel_launch(void* const* d_in, const int* in_sizes, int n_in,
                              void* d_out, int out_size, void* d_ws, size_t ws_size,
                              hipStream_t stream) {
  const float* x     = (const float*)d_in[0];
  const int*   ei    = (const int*)d_in[1];  // int32 on device
  const int*   batch = (const int*)d_in[2];
  const float* W1    = (const float*)d_in[3];
  const float* b1    = (const float*)d_in[4];
  const float* W2    = (const float*)d_in[5];
  const float* b2    = (const float*)d_in[6];
  const float* W3    = (const float*)d_in[7];
  const float* b3    = (const float*)d_in[8];
  const float* Wfc   = (const float*)d_in[9];
  const float* bfc   = (const float*)d_in[10];
  float* out = (float*)d_out;

  const int N = in_sizes[0] / 2;
  const int E = in_sizes[1] / 2;
  const int G = out_size;  // 512
  const int* src = ei;
  const int* dst = ei + E;

  // Bucket geometry: span = 1<<shift <= 256, B <= 1024. Holds for N <= 262144;
  // within that, packing (span-local dst << srcbits | src) always fits 32 bits.
  int shift = 7;
  while ((((N + (1 << shift) - 1) >> shift)) > 1024) ++shift;
  const int B = (N + (1 << shift) - 1) >> shift;
  const int srcbits = 32 - shift;
  const int chunkE = (E + NB1 - 1) / NB1;
  const int M = B * NB1;
  const int segM = (M + NB_SCAN - 1) / NB_SCAN;

  char* ws = (char*)d_ws;
  size_t off = 0;
  auto alloc = [&](size_t bytes) -> char* {
    char* p = ws + off;
    off += (bytes + 255) & ~(size_t)255;
    return p;
  };
  float*        dinv   = (float*)alloc((size_t)N * 4);
  int*          rowptr = (int*)alloc((size_t)(N + 1) * 4);
  int*          esrc   = (int*)alloc((size_t)E * 4);
  int*          gstart = (int*)alloc((size_t)(G + 1) * 4);
  int*          hist   = (int*)alloc((size_t)M * 4);
  int*          bsum   = (int*)alloc((size_t)NB_SCAN * 4);
  unsigned int* epk    = (unsigned int*)alloc((size_t)E * 4);
  float2*       u0     = (float2*)alloc((size_t)N * 8);
  float*        u1_32  = (float*)alloc((size_t)N * 32 * 4);
  __half*       u1_16  = (__half*)alloc((size_t)N * 32 * 2);
  float*        U1     = (float*)alloc((size_t)N * 32 * 4);
  float*        g3_32  = (float*)alloc((size_t)N * 32 * 4);
  __half*       g3_16  = (__half*)alloc((size_t)N * 32 * 2);
  float*        hA     = (float*)alloc((size_t)N * 32 * 4);  // h3

  // --- structure build: bucketed counting sort (no global atomics) ---
  p1_hist_kernel<<<NB1, TPB, 0, stream>>>(dst, hist, E, chunkE, shift, B);
  scan_partial_kernel<<<NB_SCAN, TPB, 0, stream>>>(hist, bsum, M, segM);
  scan_blocks_kernel<<<1, NB_SCAN, 0, stream>>>(bsum);
  scan_emit_kernel<<<NB_SCAN, TPB, 0, stream>>>(hist, bsum, M, segM);
  p1_scatter_kernel<<<NB1, TPB, 0, stream>>>(src, dst, hist, epk, E, chunkE, shift, srcbits, B);
  p2_sort_kernel<<<B, TPB, 0, stream>>>(epk, hist, (const float2*)x, rowptr, dinv, u0, esrc,
                                        N, E, shift, srcbits, B);
  gptr_kernel<<<(N + TPB - 1) / TPB, TPB, 0, stream>>>(batch, gstart, N, G);

  // --- layer 1: fused dim-2 gather (4-way split) + transform ---
  layer1_kernel<<<((size_t)N * 4 + TPB - 1) / TPB, TPB, 0, stream>>>(
      u0, rowptr, esrc, W1, b1, dinv, u1_32, u1_16, N);

  // --- layer 2: dim-32 gather (16 lanes/node), fused transform 2+3 ---
  gather32_kernel<false><<<((size_t)N * 16 + TPB - 1) / TPB, TPB, 0, stream>>>(
      (const float4*)u1_32, (const float4*)u1_16, rowptr, esrc, dinv, b2, (float4*)U1, N);
  t2t3_kernel<<<(N + 127) / 128, TPB, 0, stream>>>(U1, W2, b2, W3, dinv, g3_32, g3_16, N);

  // --- layer 3: dim-32 gather with relu epilogue ---
  gather32_kernel<true><<<((size_t)N * 16 + TPB - 1) / TPB, TPB, 0, stream>>>(
      (const float4*)g3_32, (const float4*)g3_16, rowptr, esrc, dinv, b3, (float4*)hA, N);

  // --- pool + fc ---
  poolfc_kernel<<<G, 256, 0, stream>>>(hA, gstart, Wfc, bfc, out);
}

// Round 11
// 228.690 us; speedup vs baseline: 13.7990x; 1.0850x over previous
//
#include <hip/hip_runtime.h>
#include <hip/hip_fp16.h>

// GCN: 3x GCNConv(relu) + global_mean_pool + FC, fp32 compute.
// R11: trim residuals.
//  - Self-loop reads fp16 like neighbors -> u1/g3 fp32 mirrors deleted
//    (25.6 MB writes gone; error grows 1 of-17-terms, ~1e-4 vs 3.2e-4 thr).
//  - Gather edge loops software-pipelined: prefetch esrc[e+4] so the index
//    load overlaps the dependent row load (gathers sit near the ~2.6 TB/s
//    random-fill fabric bound; this shaves the remaining latency component).
//  - scan_blocks folded into scan_emit (11 dispatches total).
// Top-5 profile = harness 0xAA ws re-poison (268 MB @6.2 TB/s ~= 44 us/iter,
// fixed). NOTE: integer inputs are int32 on device (NOT int64).

static constexpr int TPB = 256;
static constexpr int NB1 = 256;      // phase-1 blocks
static constexpr int NB_SCAN = 256;  // scan blocks
static constexpr int P2CAP = 6144;   // per-bucket LDS staging (ints)

// ---------- phase 1a: per-(bucket,block) histogram ----------
__global__ void p1_hist_kernel(const int* __restrict__ dst, int* __restrict__ hist,
                               int E, int chunk, int shift, int B) {
  __shared__ int h[1024];  // B <= 1024 by construction
  int b = blockIdx.x, t = threadIdx.x;
  for (int i = t; i < B; i += TPB) h[i] = 0;
  __syncthreads();
  int lo = b * chunk, hi = min(lo + chunk, E);
  for (int e = lo + t; e < hi; e += TPB) atomicAdd(&h[dst[e] >> shift], 1);
  __syncthreads();
  for (int i = t; i < B; i += TPB) hist[i * NB1 + b] = h[i];
}

// ---------- two-level exclusive scan (partial sums, then emit w/ own prefix) ----------
__global__ void scan_partial_kernel(const int* __restrict__ a, int* __restrict__ bsum,
                                    int n, int seg) {
  int b = blockIdx.x, t = threadIdx.x;
  int lo = b * seg, hi = min(lo + seg, n);
  int acc = 0;
  for (int i = lo + t; i < hi; i += TPB) acc += a[i];
  __shared__ int red[TPB];
  red[t] = acc;
  __syncthreads();
  for (int st = TPB / 2; st > 0; st >>= 1) {
    if (t < st) red[t] += red[t + st];
    __syncthreads();
  }
  if (t == 0) bsum[b] = red[0];
}

// emit: block b computes sum(bsum[0..b)) itself (256 adds), then scans its segment.
__global__ void scan_emit_kernel(int* __restrict__ a, const int* __restrict__ bsum,
                                 int n, int seg) {
  int b = blockIdx.x, t = threadIdx.x;
  int lo = b * seg, hi = min(lo + seg, n);
  __shared__ int cs[TPB];
  __shared__ int s_run;
  cs[t] = (t < b) ? bsum[t] : 0;  // only blocks before me
  __syncthreads();
  for (int st = TPB / 2; st > 0; st >>= 1) {
    if (t < st) cs[t] += cs[t + st];
    __syncthreads();
  }
  if (t == 0) s_run = cs[0];
  __syncthreads();
  for (int base = lo; base < hi; base += TPB) {
    int i = base + t;
    int v = (i < hi) ? a[i] : 0;
    cs[t] = v;
    __syncthreads();
    for (int off = 1; off < TPB; off <<= 1) {
      int u = (t >= off) ? cs[t - off] : 0;
      __syncthreads();
      cs[t] += u;
      __syncthreads();
    }
    if (i < hi) a[i] = s_run + cs[t] - v;  // exclusive
    __syncthreads();
    if (t == 0) s_run += cs[TPB - 1];
    __syncthreads();
  }
}

// ---------- phase 1b: scatter packed edges into bucket-contiguous epk ----------
__global__ void p1_scatter_kernel(const int* __restrict__ src, const int* __restrict__ dst,
                                  const int* __restrict__ hist, unsigned int* __restrict__ epk,
                                  int E, int chunk, int shift, int srcbits, int B) {
  __shared__ int cur[1024];
  int b = blockIdx.x, t = threadIdx.x;
  for (int i = t; i < B; i += TPB) cur[i] = hist[i * NB1 + b];
  __syncthreads();
  int lo = b * chunk, hi = min(lo + chunk, E);
  int span1 = (1 << shift) - 1;
  for (int e = lo + t; e < hi; e += TPB) {
    int d = dst[e];
    int pos = atomicAdd(&cur[d >> shift], 1);
    epk[pos] = ((unsigned int)(d & span1) << srcbits) | (unsigned int)src[e];
  }
}

// ---------- phase 2: per-bucket counting sort + rowptr/dinv/u0 emit ----------
__global__ __launch_bounds__(TPB) void p2_sort_kernel(
    const unsigned int* __restrict__ epk, const int* __restrict__ hist,
    const float2* __restrict__ x2,
    int* __restrict__ rowptr, float* __restrict__ dinv, float2* __restrict__ u0,
    int* __restrict__ esrc, int N, int E, int shift, int srcbits, int B) {
  int bkt = blockIdx.x, t = threadIdx.x;
  int span = 1 << shift;  // <= 256
  unsigned int smask = (1u << srcbits) - 1u;
  int nb = bkt << shift;
  int bstart = hist[bkt * NB1];
  int bend = (bkt + 1 < B) ? hist[(bkt + 1) * NB1] : E;
  int bsize = bend - bstart;
  __shared__ int cnt[256];
  __shared__ int ex[256];
  __shared__ int lsrc[P2CAP];
  if (t < span) cnt[t] = 0;
  __syncthreads();
  for (int e = bstart + t; e < bend; e += TPB) atomicAdd(&cnt[epk[e] >> srcbits], 1);
  __syncthreads();
  int v = (t < span) ? cnt[t] : 0;
  ex[t] = v;
  __syncthreads();
  for (int off = 1; off < 256; off <<= 1) {  // Hillis-Steele inclusive
    int u = (t >= off) ? ex[t - off] : 0;
    __syncthreads();
    ex[t] += u;
    __syncthreads();
  }
  int excl = ex[t] - v;  // exclusive scan value
  int node = nb + t;
  if (t < span && node < N) {
    rowptr[node] = bstart + excl;
    float dv = rsqrtf((float)v + 1.0f);  // +1 self-loop
    dinv[node] = dv;
    float2 xv = x2[node];
    u0[node] = make_float2(xv.x * dv, xv.y * dv);
  }
  if (bkt == 0 && t == 0) rowptr[N] = E;
  __syncthreads();
  bool stage = (bsize <= P2CAP);  // fallback keeps any input correct
  if (t < span) cnt[t] = stage ? excl : bstart + excl;  // reuse cnt as cursor
  __syncthreads();
  for (int e = bstart + t; e < bend; e += TPB) {
    unsigned int p = epk[e];
    int pos = atomicAdd(&cnt[p >> srcbits], 1);
    if (stage) lsrc[pos] = (int)(p & smask);
    else esrc[pos] = (int)(p & smask);
  }
  __syncthreads();
  if (stage)
    for (int i = t; i < bsize; i += TPB) esrc[bstart + i] = lsrc[i];  // coalesced
}

// Graph ranges from sorted batch: gstart[g] = first i with batch[i] >= g.
__global__ void gptr_kernel(const int* __restrict__ batch, int* __restrict__ gstart, int n, int G) {
  int i = blockIdx.x * blockDim.x + threadIdx.x;
  if (i >= n) return;
  int b = batch[i];
  int bp = (i == 0) ? -1 : batch[i - 1];
  for (int g = bp + 1; g <= b; ++g) gstart[g] = i;
  if (i == n - 1)
    for (int g = b + 1; g <= G; ++g) gstart[g] = n;
}

// Fused layer 1: dim-2 fp32 gather (4-way edge split, prefetched), shuffle-
// combine, then each split computes 8 of 32 features of
// u1 = dinv * relu(dinv*(W1@U0) + b1), written fp16 only.
__global__ void layer1_kernel(const float2* __restrict__ u0, const int* __restrict__ rowptr,
                              const int* __restrict__ esrc, const float* __restrict__ W1,
                              const float* __restrict__ b1, const float* __restrict__ dinv,
                              __half* __restrict__ u1_16, int n) {
  int tid = blockIdx.x * blockDim.x + threadIdx.x;
  int i = tid >> 2, split = tid & 3;
  if (i >= n) return;
  float ax = 0.f, ay = 0.f;
  if (split == 0) {  // self-loop
    float2 s = u0[i];
    ax = s.x; ay = s.y;
  }
  int r0 = rowptr[i], r1 = rowptr[i + 1];
  int e = r0 + split;
  if (e < r1) {  // software-pipelined: index load runs ahead of row load
    int snext = esrc[e];
    for (e += 4; e < r1; e += 4) {
      int scur = snext;
      snext = esrc[e];
      float2 v = u0[scur];
      ax += v.x; ay += v.y;
    }
    float2 v = u0[snext];
    ax += v.x; ay += v.y;
  }
  ax += __shfl_xor(ax, 1, 64); ay += __shfl_xor(ay, 1, 64);
  ax += __shfl_xor(ax, 2, 64); ay += __shfl_xor(ay, 2, 64);
  float di = dinv[i];
  int f0 = split * 8;
  union { float4 f4[1]; __half h[8]; } oh;
#pragma unroll
  for (int k = 0; k < 8; ++k) {
    int f = f0 + k;
    float hv = fmaxf(di * (W1[f * 2 + 0] * ax + W1[f * 2 + 1] * ay) + b1[f], 0.f);
    oh.h[k] = __float2half(di * hv);
  }
  *(float4*)&u1_16[(size_t)i * 32 + f0] = oh.f4[0];  // byte off 64i+16*split, aligned
}

// Dim-32 fp16 gather, 16 lanes/node: split = edge stripe (4), q = feature quad.
// Self + neighbors both fp16; prefetched edge loop; shfl_xor(4|8) combine.
// EPI: relu(di*acc+b) epilogue (layer 3); else raw fp32 sum (layer 2's U1).
template <bool EPI>
__global__ void gather32_kernel(const float4* __restrict__ a16,
                                const int* __restrict__ rowptr, const int* __restrict__ esrc,
                                const float* __restrict__ dinv, const float* __restrict__ b,
                                float4* __restrict__ out4, int n) {
  int tid = blockIdx.x * blockDim.x + threadIdx.x;
  int i = tid >> 4;
  int sub = tid & 15;
  int split = sub >> 2, q = sub & 3;
  if (i >= n) return;
  float acc[8] = {0.f, 0.f, 0.f, 0.f, 0.f, 0.f, 0.f, 0.f};
  auto addrow = [&](int s) {
    union { float4 f4; __half2 h2[4]; } u;
    u.f4 = a16[(size_t)s * 4 + q];
    float2 a0 = __half22float2(u.h2[0]);
    float2 a1 = __half22float2(u.h2[1]);
    float2 a2 = __half22float2(u.h2[2]);
    float2 a3 = __half22float2(u.h2[3]);
    acc[0] += a0.x; acc[1] += a0.y; acc[2] += a1.x; acc[3] += a1.y;
    acc[4] += a2.x; acc[5] += a2.y; acc[6] += a3.x; acc[7] += a3.y;
  };
  if (split == 0) addrow(i);  // self-loop (fp16, same as neighbors)
  int r0 = rowptr[i], r1 = rowptr[i + 1];
  int e = r0 + split;
  if (e < r1) {  // software-pipelined
    int snext = esrc[e];
    for (e += 4; e < r1; e += 4) {
      int scur = snext;
      snext = esrc[e];
      addrow(scur);
    }
    addrow(snext);
  }
#pragma unroll
  for (int k = 0; k < 8; ++k) acc[k] += __shfl_xor(acc[k], 4, 64);
#pragma unroll
  for (int k = 0; k < 8; ++k) acc[k] += __shfl_xor(acc[k], 8, 64);
  if (split != 0) return;
  float4 o0, o1;
  if (EPI) {
    float di = dinv[i];
    const float4 bv0 = ((const float4*)b)[2 * q];
    const float4 bv1 = ((const float4*)b)[2 * q + 1];
    o0.x = fmaxf(di * acc[0] + bv0.x, 0.f);
    o0.y = fmaxf(di * acc[1] + bv0.y, 0.f);
    o0.z = fmaxf(di * acc[2] + bv0.z, 0.f);
    o0.w = fmaxf(di * acc[3] + bv0.w, 0.f);
    o1.x = fmaxf(di * acc[4] + bv1.x, 0.f);
    o1.y = fmaxf(di * acc[5] + bv1.y, 0.f);
    o1.z = fmaxf(di * acc[6] + bv1.z, 0.f);
    o1.w = fmaxf(di * acc[7] + bv1.w, 0.f);
  } else {
    o0 = make_float4(acc[0], acc[1], acc[2], acc[3]);
    o1 = make_float4(acc[4], acc[5], acc[6], acc[7]);
  }
  out4[(size_t)i * 8 + 2 * q] = o0;
  out4[(size_t)i * 8 + 2 * q + 1] = o1;
}

// Fused layer-2+3 transform, register-tiled; writes g3 fp16 only.
__global__ __launch_bounds__(TPB) void t2t3_kernel(
    const float* __restrict__ U1, const float* __restrict__ W2, const float* __restrict__ b2,
    const float* __restrict__ W3, const float* __restrict__ dinv,
    __half* __restrict__ g3_16, int n) {
  constexpr int SN = 136;               // node-dim stride (16B-aligned fragments)
  __shared__ float U1l[32 * SN];        // [j][node]
  __shared__ float h2l[64 * SN];        // [k][node]
  __shared__ float W2l[32 * 68];        // [j][k], stride 68
  __shared__ float W3l[64 * 36];        // [j][k], stride 36
  __shared__ float dil[128];
  int t = threadIdx.x;
  int base = blockIdx.x * 128;
  for (int idx = t; idx < 2048; idx += TPB) {
    int k = idx >> 5, j = idx & 31;
    W2l[j * 68 + k] = W2[idx];
  }
  for (int idx = t; idx < 2048; idx += TPB) {
    int k = idx >> 6, j = idx & 63;
    W3l[j * 36 + k] = W3[idx];
  }
  if (t < 128) dil[t] = (base + t < n) ? dinv[base + t] : 0.f;
  for (int it = 0; it < 4; ++it) {
    int idx = it * 256 + t;  // float4 index in 128x32 tile
    int nl = idx >> 3, j0 = (idx & 7) * 4;
    int node = base + nl;
    float4 v = (node < n) ? ((const float4*)U1)[(size_t)node * 8 + (idx & 7)]
                          : make_float4(0.f, 0.f, 0.f, 0.f);
    U1l[(j0 + 0) * SN + nl] = v.x;
    U1l[(j0 + 1) * SN + nl] = v.y;
    U1l[(j0 + 2) * SN + nl] = v.z;
    U1l[(j0 + 3) * SN + nl] = v.w;
  }
  __syncthreads();
  {  // phase 1: h2l[k][n] over 128n x 64k; thread 8n x 4k
    int a = t & 15, bb = t >> 4;
    int n0 = a * 8, k0 = bb * 4;
    float acc[4][8];
#pragma unroll
    for (int kk = 0; kk < 4; ++kk)
#pragma unroll
      for (int nn = 0; nn < 8; ++nn) acc[kk][nn] = 0.f;
#pragma unroll 8
    for (int j = 0; j < 32; ++j) {
      float4 ua = *(const float4*)&U1l[j * SN + n0];
      float4 ub = *(const float4*)&U1l[j * SN + n0 + 4];
      float4 w = *(const float4*)&W2l[j * 68 + k0];
      float un[8] = {ua.x, ua.y, ua.z, ua.w, ub.x, ub.y, ub.z, ub.w};
      float wk[4] = {w.x, w.y, w.z, w.w};
#pragma unroll
      for (int kk = 0; kk < 4; ++kk)
#pragma unroll
        for (int nn = 0; nn < 8; ++nn) acc[kk][nn] += un[nn] * wk[kk];
    }
    float4 bv = ((const float4*)b2)[bb];
    float bk[4] = {bv.x, bv.y, bv.z, bv.w};
#pragma unroll
    for (int kk = 0; kk < 4; ++kk) {
      float o[8];
#pragma unroll
      for (int nn = 0; nn < 8; ++nn)
        o[nn] = fmaxf(dil[n0 + nn] * acc[kk][nn] + bk[kk], 0.f);
      *(float4*)&h2l[(k0 + kk) * SN + n0] = make_float4(o[0], o[1], o[2], o[3]);
      *(float4*)&h2l[(k0 + kk) * SN + n0 + 4] = make_float4(o[4], o[5], o[6], o[7]);
    }
  }
  __syncthreads();
  {  // phase 2: g3[n][k] over 128n x 32k; thread 8n x 2k
    int a = t & 15, bb = t >> 4;
    int n0 = a * 8, k0 = bb * 2;
    float acc[2][8];
#pragma unroll
    for (int kk = 0; kk < 2; ++kk)
#pragma unroll
      for (int nn = 0; nn < 8; ++nn) acc[kk][nn] = 0.f;
#pragma unroll 8
    for (int j = 0; j < 64; ++j) {
      float4 ua = *(const float4*)&h2l[j * SN + n0];
      float4 ub = *(const float4*)&h2l[j * SN + n0 + 4];
      float w0 = W3l[j * 36 + k0];
      float w1 = W3l[j * 36 + k0 + 1];
      float un[8] = {ua.x, ua.y, ua.z, ua.w, ub.x, ub.y, ub.z, ub.w};
#pragma unroll
      for (int nn = 0; nn < 8; ++nn) {
        acc[0][nn] += un[nn] * w0;
        acc[1][nn] += un[nn] * w1;
      }
    }
#pragma unroll
    for (int nn = 0; nn < 8; ++nn) {
      int node = base + n0 + nn;
      if (node < n) {
        float di = dil[n0 + nn];
#pragma unroll
        for (int kk = 0; kk < 2; ++kk)
          g3_16[(size_t)node * 32 + k0 + kk] = __float2half(di * acc[kk][nn]);
      }
    }
  }
}

// Block per graph: mean-pool h3 over the graph's node range, then FC. No atomics.
__global__ void poolfc_kernel(const float* __restrict__ h3, const int* __restrict__ gstart,
                              const float* __restrict__ Wfc, const float* __restrict__ bfc,
                              float* __restrict__ out) {
  int gi = blockIdx.x;
  int s = gstart[gi], e = gstart[gi + 1];
  int t = threadIdx.x;
  int nl = t >> 5, f = t & 31;
  float acc = 0.f;
  for (int i = s + nl; i < e; i += 8) acc += h3[(size_t)i * 32 + f];
  __shared__ float red[256];
  red[t] = acc;
  __syncthreads();
  for (int st = 128; st >= 32; st >>= 1) {
    if (t < st) red[t] += red[t + st];
    __syncthreads();
  }
  if (t < 32) {
    float cnt = (float)(e - s);
    float v = (red[t] / fmaxf(cnt, 1.f)) * Wfc[t];
    for (int o = 16; o; o >>= 1) v += __shfl_down(v, o, 32);
    if (t == 0) out[gi] = v + bfc[0];
  }
}

extern "C" void kernel_launch(void* const* d_in, const int* in_sizes, int n_in,
                              void* d_out, int out_size, void* d_ws, size_t ws_size,
                              hipStream_t stream) {
  const float* x     = (const float*)d_in[0];
  const int*   ei    = (const int*)d_in[1];  // int32 on device
  const int*   batch = (const int*)d_in[2];
  const float* W1    = (const float*)d_in[3];
  const float* b1    = (const float*)d_in[4];
  const float* W2    = (const float*)d_in[5];
  const float* b2    = (const float*)d_in[6];
  const float* W3    = (const float*)d_in[7];
  const float* b3    = (const float*)d_in[8];
  const float* Wfc   = (const float*)d_in[9];
  const float* bfc   = (const float*)d_in[10];
  float* out = (float*)d_out;

  const int N = in_sizes[0] / 2;
  const int E = in_sizes[1] / 2;
  const int G = out_size;  // 512
  const int* src = ei;
  const int* dst = ei + E;

  // Bucket geometry: span = 1<<shift <= 256, B <= 1024. Holds for N <= 262144;
  // within that, packing (span-local dst << srcbits | src) always fits 32 bits.
  int shift = 7;
  while ((((N + (1 << shift) - 1) >> shift)) > 1024) ++shift;
  const int B = (N + (1 << shift) - 1) >> shift;
  const int srcbits = 32 - shift;
  const int chunkE = (E + NB1 - 1) / NB1;
  const int M = B * NB1;
  const int segM = (M + NB_SCAN - 1) / NB_SCAN;

  char* ws = (char*)d_ws;
  size_t off = 0;
  auto alloc = [&](size_t bytes) -> char* {
    char* p = ws + off;
    off += (bytes + 255) & ~(size_t)255;
    return p;
  };
  float*        dinv   = (float*)alloc((size_t)N * 4);
  int*          rowptr = (int*)alloc((size_t)(N + 1) * 4);
  int*          esrc   = (int*)alloc((size_t)E * 4);
  int*          gstart = (int*)alloc((size_t)(G + 1) * 4);
  int*          hist   = (int*)alloc((size_t)M * 4);
  int*          bsum   = (int*)alloc((size_t)NB_SCAN * 4);
  unsigned int* epk    = (unsigned int*)alloc((size_t)E * 4);
  float2*       u0     = (float2*)alloc((size_t)N * 8);
  __half*       u1_16  = (__half*)alloc((size_t)N * 32 * 2);
  float*        U1     = (float*)alloc((size_t)N * 32 * 4);
  __half*       g3_16  = (__half*)alloc((size_t)N * 32 * 2);
  float*        hA     = (float*)alloc((size_t)N * 32 * 4);  // h3

  // --- structure build: bucketed counting sort (no global atomics) ---
  p1_hist_kernel<<<NB1, TPB, 0, stream>>>(dst, hist, E, chunkE, shift, B);
  scan_partial_kernel<<<NB_SCAN, TPB, 0, stream>>>(hist, bsum, M, segM);
  scan_emit_kernel<<<NB_SCAN, TPB, 0, stream>>>(hist, bsum, M, segM);
  p1_scatter_kernel<<<NB1, TPB, 0, stream>>>(src, dst, hist, epk, E, chunkE, shift, srcbits, B);
  p2_sort_kernel<<<B, TPB, 0, stream>>>(epk, hist, (const float2*)x, rowptr, dinv, u0, esrc,
                                        N, E, shift, srcbits, B);
  gptr_kernel<<<(N + TPB - 1) / TPB, TPB, 0, stream>>>(batch, gstart, N, G);

  // --- layer 1: fused dim-2 gather + transform (fp16 out) ---
  layer1_kernel<<<((size_t)N * 4 + TPB - 1) / TPB, TPB, 0, stream>>>(
      u0, rowptr, esrc, W1, b1, dinv, u1_16, N);

  // --- layer 2: dim-32 fp16 gather, fused transform 2+3 ---
  gather32_kernel<false><<<((size_t)N * 16 + TPB - 1) / TPB, TPB, 0, stream>>>(
      (const float4*)u1_16, rowptr, esrc, dinv, b2, (float4*)U1, N);
  t2t3_kernel<<<(N + 127) / 128, TPB, 0, stream>>>(U1, W2, b2, W3, dinv, g3_16, N);

  // --- layer 3: dim-32 fp16 gather with relu epilogue ---
  gather32_kernel<true><<<((size_t)N * 16 + TPB - 1) / TPB, TPB, 0, stream>>>(
      (const float4*)g3_16, rowptr, esrc, dinv, b3, (float4*)hA, N);

  // --- pool + fc ---
  poolfc_kernel<<<G, 256, 0, stream>>>(hA, gstart, Wfc, bfc, out);
}

// Round 12
// 219.404 us; speedup vs baseline: 14.3830x; 1.0423x over previous
//
#include <hip/hip_runtime.h>
#include <hip/hip_fp16.h>

// GCN: 3x GCNConv(relu) + global_mean_pool + FC, fp32 compute.
// R12: last traffic trims. Gathers fetch == compulsory 8x-XCD replication
// (R7: 92.6 vs 102 MB) — only bytes/elem remains, so: U1 and h3 now fp16
// (errors average down ~sqrt(195) in mean-pool; measured absmax 0-6e-5 at
// threshold 3.2e-4). gptr folded into p1_hist grid (10 dispatches).
// Fixed per-iter overhead outside our control: harness 0xAA ws re-poison,
// 268 MB @ ~6.2 TB/s ~= 43 us (the entire top-5).
// NOTE: integer inputs are int32 on device (NOT int64).

static constexpr int TPB = 256;
static constexpr int NB1 = 256;      // phase-1 blocks
static constexpr int NB_SCAN = 256;  // scan blocks
static constexpr int P2CAP = 6144;   // per-bucket LDS staging (ints)

// ---------- phase 1a: per-(bucket,block) histogram + (extra blocks) gptr ----------
__global__ void p1_hist_gptr_kernel(const int* __restrict__ dst, int* __restrict__ hist,
                                    int E, int chunk, int shift, int B,
                                    const int* __restrict__ batch, int* __restrict__ gstart,
                                    int n, int G) {
  int b = blockIdx.x, t = threadIdx.x;
  if (b >= NB1) {  // gptr role: gstart[g] = first i with batch[i] >= g (batch sorted)
    int i = (b - NB1) * TPB + t;
    if (i >= n) return;
    int bb = batch[i];
    int bp = (i == 0) ? -1 : batch[i - 1];
    for (int g = bp + 1; g <= bb; ++g) gstart[g] = i;
    if (i == n - 1)
      for (int g = bb + 1; g <= G; ++g) gstart[g] = n;
    return;
  }
  __shared__ int h[1024];  // B <= 1024 by construction
  for (int i = t; i < B; i += TPB) h[i] = 0;
  __syncthreads();
  int lo = b * chunk, hi = min(lo + chunk, E);
  for (int e = lo + t; e < hi; e += TPB) atomicAdd(&h[dst[e] >> shift], 1);
  __syncthreads();
  for (int i = t; i < B; i += TPB) hist[i * NB1 + b] = h[i];
}

// ---------- two-level exclusive scan (partial sums, then emit w/ own prefix) ----------
__global__ void scan_partial_kernel(const int* __restrict__ a, int* __restrict__ bsum,
                                    int n, int seg) {
  int b = blockIdx.x, t = threadIdx.x;
  int lo = b * seg, hi = min(lo + seg, n);
  int acc = 0;
  for (int i = lo + t; i < hi; i += TPB) acc += a[i];
  __shared__ int red[TPB];
  red[t] = acc;
  __syncthreads();
  for (int st = TPB / 2; st > 0; st >>= 1) {
    if (t < st) red[t] += red[t + st];
    __syncthreads();
  }
  if (t == 0) bsum[b] = red[0];
}

// emit: block b computes sum(bsum[0..b)) itself, then scans its segment.
__global__ void scan_emit_kernel(int* __restrict__ a, const int* __restrict__ bsum,
                                 int n, int seg) {
  int b = blockIdx.x, t = threadIdx.x;
  int lo = b * seg, hi = min(lo + seg, n);
  __shared__ int cs[TPB];
  __shared__ int s_run;
  cs[t] = (t < b) ? bsum[t] : 0;  // only blocks before me
  __syncthreads();
  for (int st = TPB / 2; st > 0; st >>= 1) {
    if (t < st) cs[t] += cs[t + st];
    __syncthreads();
  }
  if (t == 0) s_run = cs[0];
  __syncthreads();
  for (int base = lo; base < hi; base += TPB) {
    int i = base + t;
    int v = (i < hi) ? a[i] : 0;
    cs[t] = v;
    __syncthreads();
    for (int off = 1; off < TPB; off <<= 1) {
      int u = (t >= off) ? cs[t - off] : 0;
      __syncthreads();
      cs[t] += u;
      __syncthreads();
    }
    if (i < hi) a[i] = s_run + cs[t] - v;  // exclusive
    __syncthreads();
    if (t == 0) s_run += cs[TPB - 1];
    __syncthreads();
  }
}

// ---------- phase 1b: scatter packed edges into bucket-contiguous epk ----------
__global__ void p1_scatter_kernel(const int* __restrict__ src, const int* __restrict__ dst,
                                  const int* __restrict__ hist, unsigned int* __restrict__ epk,
                                  int E, int chunk, int shift, int srcbits, int B) {
  __shared__ int cur[1024];
  int b = blockIdx.x, t = threadIdx.x;
  for (int i = t; i < B; i += TPB) cur[i] = hist[i * NB1 + b];
  __syncthreads();
  int lo = b * chunk, hi = min(lo + chunk, E);
  int span1 = (1 << shift) - 1;
  for (int e = lo + t; e < hi; e += TPB) {
    int d = dst[e];
    int pos = atomicAdd(&cur[d >> shift], 1);
    epk[pos] = ((unsigned int)(d & span1) << srcbits) | (unsigned int)src[e];
  }
}

// ---------- phase 2: per-bucket counting sort + rowptr/dinv/u0 emit ----------
__global__ __launch_bounds__(TPB) void p2_sort_kernel(
    const unsigned int* __restrict__ epk, const int* __restrict__ hist,
    const float2* __restrict__ x2,
    int* __restrict__ rowptr, float* __restrict__ dinv, float2* __restrict__ u0,
    int* __restrict__ esrc, int N, int E, int shift, int srcbits, int B) {
  int bkt = blockIdx.x, t = threadIdx.x;
  int span = 1 << shift;  // <= 256
  unsigned int smask = (1u << srcbits) - 1u;
  int nb = bkt << shift;
  int bstart = hist[bkt * NB1];
  int bend = (bkt + 1 < B) ? hist[(bkt + 1) * NB1] : E;
  int bsize = bend - bstart;
  __shared__ int cnt[256];
  __shared__ int ex[256];
  __shared__ int lsrc[P2CAP];
  if (t < span) cnt[t] = 0;
  __syncthreads();
  for (int e = bstart + t; e < bend; e += TPB) atomicAdd(&cnt[epk[e] >> srcbits], 1);
  __syncthreads();
  int v = (t < span) ? cnt[t] : 0;
  ex[t] = v;
  __syncthreads();
  for (int off = 1; off < 256; off <<= 1) {  // Hillis-Steele inclusive
    int u = (t >= off) ? ex[t - off] : 0;
    __syncthreads();
    ex[t] += u;
    __syncthreads();
  }
  int excl = ex[t] - v;  // exclusive scan value
  int node = nb + t;
  if (t < span && node < N) {
    rowptr[node] = bstart + excl;
    float dv = rsqrtf((float)v + 1.0f);  // +1 self-loop
    dinv[node] = dv;
    float2 xv = x2[node];
    u0[node] = make_float2(xv.x * dv, xv.y * dv);
  }
  if (bkt == 0 && t == 0) rowptr[N] = E;
  __syncthreads();
  bool stage = (bsize <= P2CAP);  // fallback keeps any input correct
  if (t < span) cnt[t] = stage ? excl : bstart + excl;  // reuse cnt as cursor
  __syncthreads();
  for (int e = bstart + t; e < bend; e += TPB) {
    unsigned int p = epk[e];
    int pos = atomicAdd(&cnt[p >> srcbits], 1);
    if (stage) lsrc[pos] = (int)(p & smask);
    else esrc[pos] = (int)(p & smask);
  }
  __syncthreads();
  if (stage)
    for (int i = t; i < bsize; i += TPB) esrc[bstart + i] = lsrc[i];  // coalesced
}

// Fused layer 1: dim-2 fp32 gather (4-way edge split, prefetched), shuffle-
// combine, then each split computes 8 of 32 features of
// u1 = dinv * relu(dinv*(W1@U0) + b1), written fp16.
__global__ void layer1_kernel(const float2* __restrict__ u0, const int* __restrict__ rowptr,
                              const int* __restrict__ esrc, const float* __restrict__ W1,
                              const float* __restrict__ b1, const float* __restrict__ dinv,
                              __half* __restrict__ u1_16, int n) {
  int tid = blockIdx.x * blockDim.x + threadIdx.x;
  int i = tid >> 2, split = tid & 3;
  if (i >= n) return;
  float ax = 0.f, ay = 0.f;
  if (split == 0) {  // self-loop
    float2 s = u0[i];
    ax = s.x; ay = s.y;
  }
  int r0 = rowptr[i], r1 = rowptr[i + 1];
  int e = r0 + split;
  if (e < r1) {  // software-pipelined: index load runs ahead of row load
    int snext = esrc[e];
    for (e += 4; e < r1; e += 4) {
      int scur = snext;
      snext = esrc[e];
      float2 v = u0[scur];
      ax += v.x; ay += v.y;
    }
    float2 v = u0[snext];
    ax += v.x; ay += v.y;
  }
  ax += __shfl_xor(ax, 1, 64); ay += __shfl_xor(ay, 1, 64);
  ax += __shfl_xor(ax, 2, 64); ay += __shfl_xor(ay, 2, 64);
  float di = dinv[i];
  int f0 = split * 8;
  union { float4 f4[1]; __half h[8]; } oh;
#pragma unroll
  for (int k = 0; k < 8; ++k) {
    int f = f0 + k;
    float hv = fmaxf(di * (W1[f * 2 + 0] * ax + W1[f * 2 + 1] * ay) + b1[f], 0.f);
    oh.h[k] = __float2half(di * hv);
  }
  *(float4*)&u1_16[(size_t)i * 32 + f0] = oh.f4[0];  // 16B-aligned
}

// Dim-32 fp16 gather, 16 lanes/node: split = edge stripe (4), q = feature quad.
// Prefetched edge loop; shfl_xor(4|8) combine. Output fp16 (16 B per q-lane).
// EPI: relu(di*acc+b) epilogue (layer 3); else raw sum (layer 2's U1).
template <bool EPI>
__global__ void gather32_kernel(const float4* __restrict__ a16,
                                const int* __restrict__ rowptr, const int* __restrict__ esrc,
                                const float* __restrict__ dinv, const float* __restrict__ b,
                                float4* __restrict__ out16, int n) {
  int tid = blockIdx.x * blockDim.x + threadIdx.x;
  int i = tid >> 4;
  int sub = tid & 15;
  int split = sub >> 2, q = sub & 3;
  if (i >= n) return;
  float acc[8] = {0.f, 0.f, 0.f, 0.f, 0.f, 0.f, 0.f, 0.f};
  auto addrow = [&](int s) {
    union { float4 f4; __half2 h2[4]; } u;
    u.f4 = a16[(size_t)s * 4 + q];
    float2 a0 = __half22float2(u.h2[0]);
    float2 a1 = __half22float2(u.h2[1]);
    float2 a2 = __half22float2(u.h2[2]);
    float2 a3 = __half22float2(u.h2[3]);
    acc[0] += a0.x; acc[1] += a0.y; acc[2] += a1.x; acc[3] += a1.y;
    acc[4] += a2.x; acc[5] += a2.y; acc[6] += a3.x; acc[7] += a3.y;
  };
  if (split == 0) addrow(i);  // self-loop
  int r0 = rowptr[i], r1 = rowptr[i + 1];
  int e = r0 + split;
  if (e < r1) {  // software-pipelined
    int snext = esrc[e];
    for (e += 4; e < r1; e += 4) {
      int scur = snext;
      snext = esrc[e];
      addrow(scur);
    }
    addrow(snext);
  }
#pragma unroll
  for (int k = 0; k < 8; ++k) acc[k] += __shfl_xor(acc[k], 4, 64);
#pragma unroll
  for (int k = 0; k < 8; ++k) acc[k] += __shfl_xor(acc[k], 8, 64);
  if (split != 0) return;
  if (EPI) {
    float di = dinv[i];
    const float4 bv0 = ((const float4*)b)[2 * q];
    const float4 bv1 = ((const float4*)b)[2 * q + 1];
    acc[0] = fmaxf(di * acc[0] + bv0.x, 0.f);
    acc[1] = fmaxf(di * acc[1] + bv0.y, 0.f);
    acc[2] = fmaxf(di * acc[2] + bv0.z, 0.f);
    acc[3] = fmaxf(di * acc[3] + bv0.w, 0.f);
    acc[4] = fmaxf(di * acc[4] + bv1.x, 0.f);
    acc[5] = fmaxf(di * acc[5] + bv1.y, 0.f);
    acc[6] = fmaxf(di * acc[6] + bv1.z, 0.f);
    acc[7] = fmaxf(di * acc[7] + bv1.w, 0.f);
  }
  union { float4 f4; __half2 h2[4]; } o;
  o.h2[0] = __floats2half2_rn(acc[0], acc[1]);
  o.h2[1] = __floats2half2_rn(acc[2], acc[3]);
  o.h2[2] = __floats2half2_rn(acc[4], acc[5]);
  o.h2[3] = __floats2half2_rn(acc[6], acc[7]);
  out16[(size_t)i * 4 + q] = o.f4;
}

// Fused layer-2+3 transform, register-tiled; U1 in fp16, g3 out fp16.
__global__ __launch_bounds__(TPB) void t2t3_kernel(
    const float4* __restrict__ U1h, const float* __restrict__ W2, const float* __restrict__ b2,
    const float* __restrict__ W3, const float* __restrict__ dinv,
    __half* __restrict__ g3_16, int n) {
  constexpr int SN = 136;               // node-dim stride (16B-aligned fragments)
  __shared__ float U1l[32 * SN];        // [j][node]
  __shared__ float h2l[64 * SN];        // [k][node]
  __shared__ float W2l[32 * 68];        // [j][k], stride 68
  __shared__ float W3l[64 * 36];        // [j][k], stride 36
  __shared__ float dil[128];
  int t = threadIdx.x;
  int base = blockIdx.x * 128;
  for (int idx = t; idx < 2048; idx += TPB) {
    int k = idx >> 5, j = idx & 31;
    W2l[j * 68 + k] = W2[idx];
  }
  for (int idx = t; idx < 2048; idx += TPB) {
    int k = idx >> 6, j = idx & 63;
    W3l[j * 36 + k] = W3[idx];
  }
  if (t < 128) dil[t] = (base + t < n) ? dinv[base + t] : 0.f;
  // stage U1 fp16 -> fp32 transposed: 128 nodes x 32 feats = 512 x (8 halfs)
  for (int it = 0; it < 2; ++it) {
    int idx = it * 256 + t;
    int nl = idx >> 2, j0 = (idx & 3) * 8;
    int node = base + nl;
    union { float4 f4; __half2 h2[4]; } u;
    u.f4 = (node < n) ? U1h[(size_t)node * 4 + (idx & 3)]
                      : make_float4(0.f, 0.f, 0.f, 0.f);
#pragma unroll
    for (int k = 0; k < 4; ++k) {
      float2 p = __half22float2(u.h2[k]);
      U1l[(j0 + 2 * k + 0) * SN + nl] = p.x;
      U1l[(j0 + 2 * k + 1) * SN + nl] = p.y;
    }
  }
  __syncthreads();
  {  // phase 1: h2l[k][n] over 128n x 64k; thread 8n x 4k
    int a = t & 15, bb = t >> 4;
    int n0 = a * 8, k0 = bb * 4;
    float acc[4][8];
#pragma unroll
    for (int kk = 0; kk < 4; ++kk)
#pragma unroll
      for (int nn = 0; nn < 8; ++nn) acc[kk][nn] = 0.f;
#pragma unroll 8
    for (int j = 0; j < 32; ++j) {
      float4 ua = *(const float4*)&U1l[j * SN + n0];
      float4 ub = *(const float4*)&U1l[j * SN + n0 + 4];
      float4 w = *(const float4*)&W2l[j * 68 + k0];
      float un[8] = {ua.x, ua.y, ua.z, ua.w, ub.x, ub.y, ub.z, ub.w};
      float wk[4] = {w.x, w.y, w.z, w.w};
#pragma unroll
      for (int kk = 0; kk < 4; ++kk)
#pragma unroll
        for (int nn = 0; nn < 8; ++nn) acc[kk][nn] += un[nn] * wk[kk];
    }
    float4 bv = ((const float4*)b2)[bb];
    float bk[4] = {bv.x, bv.y, bv.z, bv.w};
#pragma unroll
    for (int kk = 0; kk < 4; ++kk) {
      float o[8];
#pragma unroll
      for (int nn = 0; nn < 8; ++nn)
        o[nn] = fmaxf(dil[n0 + nn] * acc[kk][nn] + bk[kk], 0.f);
      *(float4*)&h2l[(k0 + kk) * SN + n0] = make_float4(o[0], o[1], o[2], o[3]);
      *(float4*)&h2l[(k0 + kk) * SN + n0 + 4] = make_float4(o[4], o[5], o[6], o[7]);
    }
  }
  __syncthreads();
  {  // phase 2: g3[n][k] over 128n x 32k; thread 8n x 2k
    int a = t & 15, bb = t >> 4;
    int n0 = a * 8, k0 = bb * 2;
    float acc[2][8];
#pragma unroll
    for (int kk = 0; kk < 2; ++kk)
#pragma unroll
      for (int nn = 0; nn < 8; ++nn) acc[kk][nn] = 0.f;
#pragma unroll 8
    for (int j = 0; j < 64; ++j) {
      float4 ua = *(const float4*)&h2l[j * SN + n0];
      float4 ub = *(const float4*)&h2l[j * SN + n0 + 4];
      float w0 = W3l[j * 36 + k0];
      float w1 = W3l[j * 36 + k0 + 1];
      float un[8] = {ua.x, ua.y, ua.z, ua.w, ub.x, ub.y, ub.z, ub.w};
#pragma unroll
      for (int nn = 0; nn < 8; ++nn) {
        acc[0][nn] += un[nn] * w0;
        acc[1][nn] += un[nn] * w1;
      }
    }
#pragma unroll
    for (int nn = 0; nn < 8; ++nn) {
      int node = base + n0 + nn;
      if (node < n) {
        float di = dil[n0 + nn];
        __half2 hv = __floats2half2_rn(di * acc[0][nn], di * acc[1][nn]);
        *(__half2*)&g3_16[(size_t)node * 32 + k0] = hv;
      }
    }
  }
}

// Block per graph: mean-pool fp16 h3 over the graph's node range, then FC.
__global__ void poolfc_kernel(const __half* __restrict__ h3, const int* __restrict__ gstart,
                              const float* __restrict__ Wfc, const float* __restrict__ bfc,
                              float* __restrict__ out) {
  int gi = blockIdx.x;
  int s = gstart[gi], e = gstart[gi + 1];
  int t = threadIdx.x;
  int nl = t >> 5, f = t & 31;
  float acc = 0.f;
  for (int i = s + nl; i < e; i += 8) acc += __half2float(h3[(size_t)i * 32 + f]);
  __shared__ float red[256];
  red[t] = acc;
  __syncthreads();
  for (int st = 128; st >= 32; st >>= 1) {
    if (t < st) red[t] += red[t + st];
    __syncthreads();
  }
  if (t < 32) {
    float cnt = (float)(e - s);
    float v = (red[t] / fmaxf(cnt, 1.f)) * Wfc[t];
    for (int o = 16; o; o >>= 1) v += __shfl_down(v, o, 32);
    if (t == 0) out[gi] = v + bfc[0];
  }
}

extern "C" void kernel_launch(void* const* d_in, const int* in_sizes, int n_in,
                              void* d_out, int out_size, void* d_ws, size_t ws_size,
                              hipStream_t stream) {
  const float* x     = (const float*)d_in[0];
  const int*   ei    = (const int*)d_in[1];  // int32 on device
  const int*   batch = (const int*)d_in[2];
  const float* W1    = (const float*)d_in[3];
  const float* b1    = (const float*)d_in[4];
  const float* W2    = (const float*)d_in[5];
  const float* b2    = (const float*)d_in[6];
  const float* W3    = (const float*)d_in[7];
  const float* b3    = (const float*)d_in[8];
  const float* Wfc   = (const float*)d_in[9];
  const float* bfc   = (const float*)d_in[10];
  float* out = (float*)d_out;

  const int N = in_sizes[0] / 2;
  const int E = in_sizes[1] / 2;
  const int G = out_size;  // 512
  const int* src = ei;
  const int* dst = ei + E;

  // Bucket geometry: span = 1<<shift <= 256, B <= 1024. Holds for N <= 262144;
  // within that, packing (span-local dst << srcbits | src) always fits 32 bits.
  int shift = 7;
  while ((((N + (1 << shift) - 1) >> shift)) > 1024) ++shift;
  const int B = (N + (1 << shift) - 1) >> shift;
  const int srcbits = 32 - shift;
  const int chunkE = (E + NB1 - 1) / NB1;
  const int M = B * NB1;
  const int segM = (M + NB_SCAN - 1) / NB_SCAN;

  char* ws = (char*)d_ws;
  size_t off = 0;
  auto alloc = [&](size_t bytes) -> char* {
    char* p = ws + off;
    off += (bytes + 255) & ~(size_t)255;
    return p;
  };
  float*        dinv   = (float*)alloc((size_t)N * 4);
  int*          rowptr = (int*)alloc((size_t)(N + 1) * 4);
  int*          esrc   = (int*)alloc((size_t)E * 4);
  int*          gstart = (int*)alloc((size_t)(G + 1) * 4);
  int*          hist   = (int*)alloc((size_t)M * 4);
  int*          bsum   = (int*)alloc((size_t)NB_SCAN * 4);
  unsigned int* epk    = (unsigned int*)alloc((size_t)E * 4);
  float2*       u0     = (float2*)alloc((size_t)N * 8);
  __half*       u1_16  = (__half*)alloc((size_t)N * 32 * 2);
  __half*       U1h    = (__half*)alloc((size_t)N * 32 * 2);
  __half*       g3_16  = (__half*)alloc((size_t)N * 32 * 2);
  __half*       hA16   = (__half*)alloc((size_t)N * 32 * 2);  // h3

  // --- structure build: bucketed counting sort (no global atomics) ---
  const int gptrBlocks = (N + TPB - 1) / TPB;
  p1_hist_gptr_kernel<<<NB1 + gptrBlocks, TPB, 0, stream>>>(dst, hist, E, chunkE, shift, B,
                                                            batch, gstart, N, G);
  scan_partial_kernel<<<NB_SCAN, TPB, 0, stream>>>(hist, bsum, M, segM);
  scan_emit_kernel<<<NB_SCAN, TPB, 0, stream>>>(hist, bsum, M, segM);
  p1_scatter_kernel<<<NB1, TPB, 0, stream>>>(src, dst, hist, epk, E, chunkE, shift, srcbits, B);
  p2_sort_kernel<<<B, TPB, 0, stream>>>(epk, hist, (const float2*)x, rowptr, dinv, u0, esrc,
                                        N, E, shift, srcbits, B);

  // --- layer 1: fused dim-2 gather + transform (fp16 out) ---
  layer1_kernel<<<((size_t)N * 4 + TPB - 1) / TPB, TPB, 0, stream>>>(
      u0, rowptr, esrc, W1, b1, dinv, u1_16, N);

  // --- layer 2: dim-32 fp16 gather -> fp16 U1, fused transform 2+3 ---
  gather32_kernel<false><<<((size_t)N * 16 + TPB - 1) / TPB, TPB, 0, stream>>>(
      (const float4*)u1_16, rowptr, esrc, dinv, b2, (float4*)U1h, N);
  t2t3_kernel<<<(N + 127) / 128, TPB, 0, stream>>>(
      (const float4*)U1h, W2, b2, W3, dinv, g3_16, N);

  // --- layer 3: dim-32 fp16 gather with relu epilogue -> fp16 h3 ---
  gather32_kernel<true><<<((size_t)N * 16 + TPB - 1) / TPB, TPB, 0, stream>>>(
      (const float4*)g3_16, rowptr, esrc, dinv, b3, (float4*)hA16, N);

  // --- pool + fc ---
  poolfc_kernel<<<G, 256, 0, stream>>>(hA16, gstart, Wfc, bfc, out);
}

// Round 13
// 217.917 us; speedup vs baseline: 14.4812x; 1.0068x over previous
//
#include <hip/hip_runtime.h>
#include <hip/hip_fp16.h>

// GCN: 3x GCNConv(relu) + global_mean_pool + FC, fp32 compute.
// R13: structure-build trims (my kernels are all < the 42us profile cutoff;
// these are model-driven).
//  - shift=8: span 256 (=p2 LDS width), B=391 buckets -> p1_scatter runs are
//    16 edges = 64 B full lines (was 32 B half-lines, 2x write-amp); hist and
//    scan halve (M 200k -> 100k).
//  - p2_sort single-pass: bucket edges staged into LDS once (coalesced),
//    count/scan/scatter all LDS-local; only esrc writeback goes to global.
//    Saves the 6.4 MB second epk pass. Global 2-pass fallback if bucket
//    overflows P2CAP (keeps any input correct).
// Fixed per-iter overhead: harness 0xAA ws re-poison, 268 MB ~= 43 us.
// Gathers fetch == compulsory 8x-XCD replication (R7) at fp16 — no traffic
// lever left there. NOTE: integer inputs are int32 on device (NOT int64).

static constexpr int TPB = 256;
static constexpr int NB1 = 256;      // phase-1 blocks
static constexpr int NB_SCAN = 256;  // scan blocks
static constexpr int P2CAP = 6144;   // per-bucket LDS staging (ints); avg ~4.1k at B=391

// ---------- phase 1a: per-(bucket,block) histogram + (extra blocks) gptr ----------
__global__ void p1_hist_gptr_kernel(const int* __restrict__ dst, int* __restrict__ hist,
                                    int E, int chunk, int shift, int B,
                                    const int* __restrict__ batch, int* __restrict__ gstart,
                                    int n, int G) {
  int b = blockIdx.x, t = threadIdx.x;
  if (b >= NB1) {  // gptr role: gstart[g] = first i with batch[i] >= g (batch sorted)
    int i = (b - NB1) * TPB + t;
    if (i >= n) return;
    int bb = batch[i];
    int bp = (i == 0) ? -1 : batch[i - 1];
    for (int g = bp + 1; g <= bb; ++g) gstart[g] = i;
    if (i == n - 1)
      for (int g = bb + 1; g <= G; ++g) gstart[g] = n;
    return;
  }
  __shared__ int h[1024];  // B <= 1024 by construction
  for (int i = t; i < B; i += TPB) h[i] = 0;
  __syncthreads();
  int lo = b * chunk, hi = min(lo + chunk, E);
  for (int e = lo + t; e < hi; e += TPB) atomicAdd(&h[dst[e] >> shift], 1);
  __syncthreads();
  for (int i = t; i < B; i += TPB) hist[i * NB1 + b] = h[i];
}

// ---------- two-level exclusive scan (partial sums, then emit w/ own prefix) ----------
__global__ void scan_partial_kernel(const int* __restrict__ a, int* __restrict__ bsum,
                                    int n, int seg) {
  int b = blockIdx.x, t = threadIdx.x;
  int lo = b * seg, hi = min(lo + seg, n);
  int acc = 0;
  for (int i = lo + t; i < hi; i += TPB) acc += a[i];
  __shared__ int red[TPB];
  red[t] = acc;
  __syncthreads();
  for (int st = TPB / 2; st > 0; st >>= 1) {
    if (t < st) red[t] += red[t + st];
    __syncthreads();
  }
  if (t == 0) bsum[b] = red[0];
}

// emit: block b computes sum(bsum[0..b)) itself, then scans its segment.
__global__ void scan_emit_kernel(int* __restrict__ a, const int* __restrict__ bsum,
                                 int n, int seg) {
  int b = blockIdx.x, t = threadIdx.x;
  int lo = b * seg, hi = min(lo + seg, n);
  __shared__ int cs[TPB];
  __shared__ int s_run;
  cs[t] = (t < b) ? bsum[t] : 0;  // only blocks before me
  __syncthreads();
  for (int st = TPB / 2; st > 0; st >>= 1) {
    if (t < st) cs[t] += cs[t + st];
    __syncthreads();
  }
  if (t == 0) s_run = cs[0];
  __syncthreads();
  for (int base = lo; base < hi; base += TPB) {
    int i = base + t;
    int v = (i < hi) ? a[i] : 0;
    cs[t] = v;
    __syncthreads();
    for (int off = 1; off < TPB; off <<= 1) {
      int u = (t >= off) ? cs[t - off] : 0;
      __syncthreads();
      cs[t] += u;
      __syncthreads();
    }
    if (i < hi) a[i] = s_run + cs[t] - v;  // exclusive
    __syncthreads();
    if (t == 0) s_run += cs[TPB - 1];
    __syncthreads();
  }
}

// ---------- phase 1b: scatter packed edges into bucket-contiguous epk ----------
__global__ void p1_scatter_kernel(const int* __restrict__ src, const int* __restrict__ dst,
                                  const int* __restrict__ hist, unsigned int* __restrict__ epk,
                                  int E, int chunk, int shift, int srcbits, int B) {
  __shared__ int cur[1024];
  int b = blockIdx.x, t = threadIdx.x;
  for (int i = t; i < B; i += TPB) cur[i] = hist[i * NB1 + b];
  __syncthreads();
  int lo = b * chunk, hi = min(lo + chunk, E);
  int span1 = (1 << shift) - 1;
  for (int e = lo + t; e < hi; e += TPB) {
    int d = dst[e];
    int pos = atomicAdd(&cur[d >> shift], 1);
    epk[pos] = ((unsigned int)(d & span1) << srcbits) | (unsigned int)src[e];
  }
}

// ---------- phase 2: per-bucket counting sort + rowptr/dinv/u0 emit ----------
// Single-pass: bucket edges staged into LDS (coalesced), count/scan/scatter
// LDS-local, coalesced esrc writeback. Fallback to 2-pass global if oversized.
__global__ __launch_bounds__(TPB) void p2_sort_kernel(
    const unsigned int* __restrict__ epk, const int* __restrict__ hist,
    const float2* __restrict__ x2,
    int* __restrict__ rowptr, float* __restrict__ dinv, float2* __restrict__ u0,
    int* __restrict__ esrc, int N, int E, int shift, int srcbits, int B) {
  int bkt = blockIdx.x, t = threadIdx.x;
  int span = 1 << shift;  // == 256 == TPB for N <= 262144
  unsigned int smask = (1u << srcbits) - 1u;
  int nb = bkt << shift;
  int bstart = hist[bkt * NB1];
  int bend = (bkt + 1 < B) ? hist[(bkt + 1) * NB1] : E;
  int bsize = bend - bstart;
  __shared__ int cnt[256];
  __shared__ int ex[256];
  __shared__ int ldata[P2CAP];
  __shared__ int lsrc[P2CAP];
  bool stage = (bsize <= P2CAP);
  if (t < span) cnt[t] = 0;
  __syncthreads();
  if (stage) {
    for (int i = t; i < bsize; i += TPB) ldata[i] = (int)epk[bstart + i];  // coalesced
    __syncthreads();
    for (int i = t; i < bsize; i += TPB)
      atomicAdd(&cnt[((unsigned int)ldata[i]) >> srcbits], 1);
  } else {
    for (int e = bstart + t; e < bend; e += TPB) atomicAdd(&cnt[epk[e] >> srcbits], 1);
  }
  __syncthreads();
  int v = (t < span) ? cnt[t] : 0;
  ex[t] = v;
  __syncthreads();
  for (int off = 1; off < 256; off <<= 1) {  // Hillis-Steele inclusive
    int u = (t >= off) ? ex[t - off] : 0;
    __syncthreads();
    ex[t] += u;
    __syncthreads();
  }
  int excl = ex[t] - v;  // exclusive scan value
  int node = nb + t;
  if (t < span && node < N) {
    rowptr[node] = bstart + excl;
    float dv = rsqrtf((float)v + 1.0f);  // +1 self-loop
    dinv[node] = dv;
    float2 xv = x2[node];
    u0[node] = make_float2(xv.x * dv, xv.y * dv);
  }
  if (bkt == 0 && t == 0) rowptr[N] = E;
  __syncthreads();
  if (t < span) cnt[t] = stage ? excl : bstart + excl;  // reuse cnt as cursor
  __syncthreads();
  if (stage) {
    for (int i = t; i < bsize; i += TPB) {
      unsigned int p = (unsigned int)ldata[i];
      int pos = atomicAdd(&cnt[p >> srcbits], 1);
      lsrc[pos] = (int)(p & smask);
    }
    __syncthreads();
    for (int i = t; i < bsize; i += TPB) esrc[bstart + i] = lsrc[i];  // coalesced
  } else {
    for (int e = bstart + t; e < bend; e += TPB) {
      unsigned int p = epk[e];
      int pos = atomicAdd(&cnt[p >> srcbits], 1);
      esrc[pos] = (int)(p & smask);
    }
  }
}

// Fused layer 1: dim-2 fp32 gather (4-way edge split, prefetched), shuffle-
// combine, then each split computes 8 of 32 features of
// u1 = dinv * relu(dinv*(W1@U0) + b1), written fp16.
__global__ void layer1_kernel(const float2* __restrict__ u0, const int* __restrict__ rowptr,
                              const int* __restrict__ esrc, const float* __restrict__ W1,
                              const float* __restrict__ b1, const float* __restrict__ dinv,
                              __half* __restrict__ u1_16, int n) {
  int tid = blockIdx.x * blockDim.x + threadIdx.x;
  int i = tid >> 2, split = tid & 3;
  if (i >= n) return;
  float ax = 0.f, ay = 0.f;
  if (split == 0) {  // self-loop
    float2 s = u0[i];
    ax = s.x; ay = s.y;
  }
  int r0 = rowptr[i], r1 = rowptr[i + 1];
  int e = r0 + split;
  if (e < r1) {  // software-pipelined: index load runs ahead of row load
    int snext = esrc[e];
    for (e += 4; e < r1; e += 4) {
      int scur = snext;
      snext = esrc[e];
      float2 v = u0[scur];
      ax += v.x; ay += v.y;
    }
    float2 v = u0[snext];
    ax += v.x; ay += v.y;
  }
  ax += __shfl_xor(ax, 1, 64); ay += __shfl_xor(ay, 1, 64);
  ax += __shfl_xor(ax, 2, 64); ay += __shfl_xor(ay, 2, 64);
  float di = dinv[i];
  int f0 = split * 8;
  union { float4 f4[1]; __half h[8]; } oh;
#pragma unroll
  for (int k = 0; k < 8; ++k) {
    int f = f0 + k;
    float hv = fmaxf(di * (W1[f * 2 + 0] * ax + W1[f * 2 + 1] * ay) + b1[f], 0.f);
    oh.h[k] = __float2half(di * hv);
  }
  *(float4*)&u1_16[(size_t)i * 32 + f0] = oh.f4[0];  // 16B-aligned
}

// Dim-32 fp16 gather, 16 lanes/node: split = edge stripe (4), q = feature quad.
// Prefetched edge loop; shfl_xor(4|8) combine. Output fp16 (16 B per q-lane).
// EPI: relu(di*acc+b) epilogue (layer 3); else raw sum (layer 2's U1).
template <bool EPI>
__global__ void gather32_kernel(const float4* __restrict__ a16,
                                const int* __restrict__ rowptr, const int* __restrict__ esrc,
                                const float* __restrict__ dinv, const float* __restrict__ b,
                                float4* __restrict__ out16, int n) {
  int tid = blockIdx.x * blockDim.x + threadIdx.x;
  int i = tid >> 4;
  int sub = tid & 15;
  int split = sub >> 2, q = sub & 3;
  if (i >= n) return;
  float acc[8] = {0.f, 0.f, 0.f, 0.f, 0.f, 0.f, 0.f, 0.f};
  auto addrow = [&](int s) {
    union { float4 f4; __half2 h2[4]; } u;
    u.f4 = a16[(size_t)s * 4 + q];
    float2 a0 = __half22float2(u.h2[0]);
    float2 a1 = __half22float2(u.h2[1]);
    float2 a2 = __half22float2(u.h2[2]);
    float2 a3 = __half22float2(u.h2[3]);
    acc[0] += a0.x; acc[1] += a0.y; acc[2] += a1.x; acc[3] += a1.y;
    acc[4] += a2.x; acc[5] += a2.y; acc[6] += a3.x; acc[7] += a3.y;
  };
  if (split == 0) addrow(i);  // self-loop
  int r0 = rowptr[i], r1 = rowptr[i + 1];
  int e = r0 + split;
  if (e < r1) {  // software-pipelined
    int snext = esrc[e];
    for (e += 4; e < r1; e += 4) {
      int scur = snext;
      snext = esrc[e];
      addrow(scur);
    }
    addrow(snext);
  }
#pragma unroll
  for (int k = 0; k < 8; ++k) acc[k] += __shfl_xor(acc[k], 4, 64);
#pragma unroll
  for (int k = 0; k < 8; ++k) acc[k] += __shfl_xor(acc[k], 8, 64);
  if (split != 0) return;
  if (EPI) {
    float di = dinv[i];
    const float4 bv0 = ((const float4*)b)[2 * q];
    const float4 bv1 = ((const float4*)b)[2 * q + 1];
    acc[0] = fmaxf(di * acc[0] + bv0.x, 0.f);
    acc[1] = fmaxf(di * acc[1] + bv0.y, 0.f);
    acc[2] = fmaxf(di * acc[2] + bv0.z, 0.f);
    acc[3] = fmaxf(di * acc[3] + bv0.w, 0.f);
    acc[4] = fmaxf(di * acc[4] + bv1.x, 0.f);
    acc[5] = fmaxf(di * acc[5] + bv1.y, 0.f);
    acc[6] = fmaxf(di * acc[6] + bv1.z, 0.f);
    acc[7] = fmaxf(di * acc[7] + bv1.w, 0.f);
  }
  union { float4 f4; __half2 h2[4]; } o;
  o.h2[0] = __floats2half2_rn(acc[0], acc[1]);
  o.h2[1] = __floats2half2_rn(acc[2], acc[3]);
  o.h2[2] = __floats2half2_rn(acc[4], acc[5]);
  o.h2[3] = __floats2half2_rn(acc[6], acc[7]);
  out16[(size_t)i * 4 + q] = o.f4;
}

// Fused layer-2+3 transform, register-tiled; U1 in fp16, g3 out fp16.
__global__ __launch_bounds__(TPB) void t2t3_kernel(
    const float4* __restrict__ U1h, const float* __restrict__ W2, const float* __restrict__ b2,
    const float* __restrict__ W3, const float* __restrict__ dinv,
    __half* __restrict__ g3_16, int n) {
  constexpr int SN = 136;               // node-dim stride (16B-aligned fragments)
  __shared__ float U1l[32 * SN];        // [j][node]
  __shared__ float h2l[64 * SN];        // [k][node]
  __shared__ float W2l[32 * 68];        // [j][k], stride 68
  __shared__ float W3l[64 * 36];        // [j][k], stride 36
  __shared__ float dil[128];
  int t = threadIdx.x;
  int base = blockIdx.x * 128;
  for (int idx = t; idx < 2048; idx += TPB) {
    int k = idx >> 5, j = idx & 31;
    W2l[j * 68 + k] = W2[idx];
  }
  for (int idx = t; idx < 2048; idx += TPB) {
    int k = idx >> 6, j = idx & 63;
    W3l[j * 36 + k] = W3[idx];
  }
  if (t < 128) dil[t] = (base + t < n) ? dinv[base + t] : 0.f;
  // stage U1 fp16 -> fp32 transposed: 128 nodes x 32 feats = 512 x (8 halfs)
  for (int it = 0; it < 2; ++it) {
    int idx = it * 256 + t;
    int nl = idx >> 2, j0 = (idx & 3) * 8;
    int node = base + nl;
    union { float4 f4; __half2 h2[4]; } u;
    u.f4 = (node < n) ? U1h[(size_t)node * 4 + (idx & 3)]
                      : make_float4(0.f, 0.f, 0.f, 0.f);
#pragma unroll
    for (int k = 0; k < 4; ++k) {
      float2 p = __half22float2(u.h2[k]);
      U1l[(j0 + 2 * k + 0) * SN + nl] = p.x;
      U1l[(j0 + 2 * k + 1) * SN + nl] = p.y;
    }
  }
  __syncthreads();
  {  // phase 1: h2l[k][n] over 128n x 64k; thread 8n x 4k
    int a = t & 15, bb = t >> 4;
    int n0 = a * 8, k0 = bb * 4;
    float acc[4][8];
#pragma unroll
    for (int kk = 0; kk < 4; ++kk)
#pragma unroll
      for (int nn = 0; nn < 8; ++nn) acc[kk][nn] = 0.f;
#pragma unroll 8
    for (int j = 0; j < 32; ++j) {
      float4 ua = *(const float4*)&U1l[j * SN + n0];
      float4 ub = *(const float4*)&U1l[j * SN + n0 + 4];
      float4 w = *(const float4*)&W2l[j * 68 + k0];
      float un[8] = {ua.x, ua.y, ua.z, ua.w, ub.x, ub.y, ub.z, ub.w};
      float wk[4] = {w.x, w.y, w.z, w.w};
#pragma unroll
      for (int kk = 0; kk < 4; ++kk)
#pragma unroll
        for (int nn = 0; nn < 8; ++nn) acc[kk][nn] += un[nn] * wk[kk];
    }
    float4 bv = ((const float4*)b2)[bb];
    float bk[4] = {bv.x, bv.y, bv.z, bv.w};
#pragma unroll
    for (int kk = 0; kk < 4; ++kk) {
      float o[8];
#pragma unroll
      for (int nn = 0; nn < 8; ++nn)
        o[nn] = fmaxf(dil[n0 + nn] * acc[kk][nn] + bk[kk], 0.f);
      *(float4*)&h2l[(k0 + kk) * SN + n0] = make_float4(o[0], o[1], o[2], o[3]);
      *(float4*)&h2l[(k0 + kk) * SN + n0 + 4] = make_float4(o[4], o[5], o[6], o[7]);
    }
  }
  __syncthreads();
  {  // phase 2: g3[n][k] over 128n x 32k; thread 8n x 2k
    int a = t & 15, bb = t >> 4;
    int n0 = a * 8, k0 = bb * 2;
    float acc[2][8];
#pragma unroll
    for (int kk = 0; kk < 2; ++kk)
#pragma unroll
      for (int nn = 0; nn < 8; ++nn) acc[kk][nn] = 0.f;
#pragma unroll 8
    for (int j = 0; j < 64; ++j) {
      float4 ua = *(const float4*)&h2l[j * SN + n0];
      float4 ub = *(const float4*)&h2l[j * SN + n0 + 4];
      float w0 = W3l[j * 36 + k0];
      float w1 = W3l[j * 36 + k0 + 1];
      float un[8] = {ua.x, ua.y, ua.z, ua.w, ub.x, ub.y, ub.z, ub.w};
#pragma unroll
      for (int nn = 0; nn < 8; ++nn) {
        acc[0][nn] += un[nn] * w0;
        acc[1][nn] += un[nn] * w1;
      }
    }
#pragma unroll
    for (int nn = 0; nn < 8; ++nn) {
      int node = base + n0 + nn;
      if (node < n) {
        float di = dil[n0 + nn];
        __half2 hv = __floats2half2_rn(di * acc[0][nn], di * acc[1][nn]);
        *(__half2*)&g3_16[(size_t)node * 32 + k0] = hv;
      }
    }
  }
}

// Block per graph: mean-pool fp16 h3 over the graph's node range, then FC.
__global__ void poolfc_kernel(const __half* __restrict__ h3, const int* __restrict__ gstart,
                              const float* __restrict__ Wfc, const float* __restrict__ bfc,
                              float* __restrict__ out) {
  int gi = blockIdx.x;
  int s = gstart[gi], e = gstart[gi + 1];
  int t = threadIdx.x;
  int nl = t >> 5, f = t & 31;
  float acc = 0.f;
  for (int i = s + nl; i < e; i += 8) acc += __half2float(h3[(size_t)i * 32 + f]);
  __shared__ float red[256];
  red[t] = acc;
  __syncthreads();
  for (int st = 128; st >= 32; st >>= 1) {
    if (t < st) red[t] += red[t + st];
    __syncthreads();
  }
  if (t < 32) {
    float cnt = (float)(e - s);
    float v = (red[t] / fmaxf(cnt, 1.f)) * Wfc[t];
    for (int o = 16; o; o >>= 1) v += __shfl_down(v, o, 32);
    if (t == 0) out[gi] = v + bfc[0];
  }
}

extern "C" void kernel_launch(void* const* d_in, const int* in_sizes, int n_in,
                              void* d_out, int out_size, void* d_ws, size_t ws_size,
                              hipStream_t stream) {
  const float* x     = (const float*)d_in[0];
  const int*   ei    = (const int*)d_in[1];  // int32 on device
  const int*   batch = (const int*)d_in[2];
  const float* W1    = (const float*)d_in[3];
  const float* b1    = (const float*)d_in[4];
  const float* W2    = (const float*)d_in[5];
  const float* b2    = (const float*)d_in[6];
  const float* W3    = (const float*)d_in[7];
  const float* b3    = (const float*)d_in[8];
  const float* Wfc   = (const float*)d_in[9];
  const float* bfc   = (const float*)d_in[10];
  float* out = (float*)d_out;

  const int N = in_sizes[0] / 2;
  const int E = in_sizes[1] / 2;
  const int G = out_size;  // 512
  const int* src = ei;
  const int* dst = ei + E;

  // Bucket geometry: span = 1<<shift, B <= 1024, span <= 256 (p2 LDS width).
  // shift=8 -> 64 B scatter runs; holds for N <= 262144.
  int shift = 8;
  while ((((N + (1 << shift) - 1) >> shift)) > 1024) ++shift;
  const int B = (N + (1 << shift) - 1) >> shift;
  const int srcbits = 32 - shift;
  const int chunkE = (E + NB1 - 1) / NB1;
  const int M = B * NB1;
  const int segM = (M + NB_SCAN - 1) / NB_SCAN;

  char* ws = (char*)d_ws;
  size_t off = 0;
  auto alloc = [&](size_t bytes) -> char* {
    char* p = ws + off;
    off += (bytes + 255) & ~(size_t)255;
    return p;
  };
  float*        dinv   = (float*)alloc((size_t)N * 4);
  int*          rowptr = (int*)alloc((size_t)(N + 1) * 4);
  int*          esrc   = (int*)alloc((size_t)E * 4);
  int*          gstart = (int*)alloc((size_t)(G + 1) * 4);
  int*          hist   = (int*)alloc((size_t)M * 4);
  int*          bsum   = (int*)alloc((size_t)NB_SCAN * 4);
  unsigned int* epk    = (unsigned int*)alloc((size_t)E * 4);
  float2*       u0     = (float2*)alloc((size_t)N * 8);
  __half*       u1_16  = (__half*)alloc((size_t)N * 32 * 2);
  __half*       U1h    = (__half*)alloc((size_t)N * 32 * 2);
  __half*       g3_16  = (__half*)alloc((size_t)N * 32 * 2);
  __half*       hA16   = (__half*)alloc((size_t)N * 32 * 2);  // h3

  // --- structure build: bucketed counting sort (no global atomics) ---
  const int gptrBlocks = (N + TPB - 1) / TPB;
  p1_hist_gptr_kernel<<<NB1 + gptrBlocks, TPB, 0, stream>>>(dst, hist, E, chunkE, shift, B,
                                                            batch, gstart, N, G);
  scan_partial_kernel<<<NB_SCAN, TPB, 0, stream>>>(hist, bsum, M, segM);
  scan_emit_kernel<<<NB_SCAN, TPB, 0, stream>>>(hist, bsum, M, segM);
  p1_scatter_kernel<<<NB1, TPB, 0, stream>>>(src, dst, hist, epk, E, chunkE, shift, srcbits, B);
  p2_sort_kernel<<<B, TPB, 0, stream>>>(epk, hist, (const float2*)x, rowptr, dinv, u0, esrc,
                                        N, E, shift, srcbits, B);

  // --- layer 1: fused dim-2 gather + transform (fp16 out) ---
  layer1_kernel<<<((size_t)N * 4 + TPB - 1) / TPB, TPB, 0, stream>>>(
      u0, rowptr, esrc, W1, b1, dinv, u1_16, N);

  // --- layer 2: dim-32 fp16 gather -> fp16 U1, fused transform 2+3 ---
  gather32_kernel<false><<<((size_t)N * 16 + TPB - 1) / TPB, TPB, 0, stream>>>(
      (const float4*)u1_16, rowptr, esrc, dinv, b2, (float4*)U1h, N);
  t2t3_kernel<<<(N + 127) / 128, TPB, 0, stream>>>(
      (const float4*)U1h, W2, b2, W3, dinv, g3_16, N);

  // --- layer 3: dim-32 fp16 gather with relu epilogue -> fp16 h3 ---
  gather32_kernel<true><<<((size_t)N * 16 + TPB - 1) / TPB, TPB, 0, stream>>>(
      (const float4*)g3_16, rowptr, esrc, dinv, b3, (float4*)hA16, N);

  // --- pool + fc ---
  poolfc_kernel<<<G, 256, 0, stream>>>(hA16, gstart, Wfc, bfc, out);
}